// Round 3
// baseline (970.994 us; speedup 1.0000x reference)
//
#include <hip/hip_runtime.h>
#include <hip/hip_bf16.h>

// MAMBA_BayesMAGAC: B=32, L=512, D=128, E=64, HS=64, DTR=4, U=32, R=3, K=3, DE=10, NH=4
// Round 3: scan v3 (block owns (b,dir,e-quarter), LDS-staged tiles, reg-prefetch dbuf),
// prep3 (16 rows/block), gate3 (LDS transpose), head_v3 (per-thread l-group reuse).

#define B_ 32
#define L_ 512
#define D_ 128
#define E_ 64
#define HS_ 64

// ---- workspace offsets (floats) ----
#define OFF_X     0u          // 2,097,152  x [b][l][128]
#define OFF_XZF   2097152u    // 2,097,152  xz fwd [b][l][128]
#define OFF_XZB   4194304u
#define OFF_XPF   6291456u    // 1,048,576  xp [b][l][64]
#define OFF_XPB   7340032u
#define OFF_PKF   8388608u    // 2,097,152  (dl,du) [b][l][64][2]
#define OFF_PKB   10485760u
#define OFF_XBCF  12582912u   // 2,097,152  (B,C) [b][l][128]
#define OFF_XBCB  14680064u
#define OFF_YSF   16777216u   // 1,048,576  scan y [b][e][l]
#define OFF_YSB   17825792u   // end 18,874,368 floats = 75.5 MB
// reuse (liveness-checked):
#define OFF_YGF   8388608u    // over PKF (dead after scan)
#define OFF_YGB   9437184u
#define OFF_Y3    16777216u   // over YSF+YSB (dead after gate)
// head phase (only OFF_X live):
#define OFF_V     2097152u    // 8,388,608  V [l][m][n]
#define OFF_WFT   10485760u   // 1,048,576  Wf [h][k][l][n]
#define OFF_STT   11534336u   // 262,144    S^T [h][k][m][n]
#define OFF_AEFF  11796480u   // 65,536
#define OFF_GB    11862016u   // 16,384
#define OFF_QKB   11878400u   // 65,536
#define OFF_QB    11943936u   // 5,120
#define OFF_KB    11949056u   // 5,120
#define OFF_MIX   11954176u   // 4
#define OFF_ALPH  11954180u   // 1
#define OFF_BFT   11954184u   // 128
#define OFF_PART  12582912u   // 2,097,152  partial [512][32][128]

__device__ __forceinline__ float sigf(float x) { return 1.f / (1.f + __expf(-x)); }

// ---------------- in-projection: xz = x @ in_w (both dirs), 32 rows/block ----------------
__global__ __launch_bounds__(256) void gemm_in2_kernel(
    const float* __restrict__ X, const float* __restrict__ WF, const float* __restrict__ WB,
    float* __restrict__ xzF, float* __restrict__ xzB)
{
    __shared__ float sxT[128][36];    // transposed x tile, padded
    __shared__ float sw[2][16][128];
    const int tid = threadIdx.x;
    const int r0 = blockIdx.x * 32;
    for (int q = tid; q < 32 * 128; q += 256) {
        const int r = q >> 7, k = q & 127;
        sxT[k][r] = X[(r0 + r) * 128 + k];
    }
    const int wv = tid >> 6, lane = tid & 63;
    const int d = wv >> 1, ch = wv & 1;
    const int r4 = lane >> 4, c16 = lane & 15;
    float4 acc[8];
#pragma unroll
    for (int j = 0; j < 8; ++j) acc[j] = float4{0.f, 0.f, 0.f, 0.f};
    for (int ko = 0; ko < 128; ko += 16) {
        __syncthreads();
        for (int q = tid; q < 2 * 16 * 128; q += 256) {
            const int dd = q >> 11, kk = (q >> 7) & 15, c = q & 127;
            sw[dd][kk][c] = (dd ? WB : WF)[(ko + kk) * 128 + c];
        }
        __syncthreads();
#pragma unroll
        for (int kk = 0; kk < 16; ++kk) {
            const float4 w4 = *(const float4*)&sw[d][kk][ch * 64 + c16 * 4];
            const float4 xa = *(const float4*)&sxT[ko + kk][r4 * 8];
            const float4 xb = *(const float4*)&sxT[ko + kk][r4 * 8 + 4];
            const float xs[8] = {xa.x, xa.y, xa.z, xa.w, xb.x, xb.y, xb.z, xb.w};
#pragma unroll
            for (int j = 0; j < 8; ++j) {
                acc[j].x = fmaf(xs[j], w4.x, acc[j].x);
                acc[j].y = fmaf(xs[j], w4.y, acc[j].y);
                acc[j].z = fmaf(xs[j], w4.z, acc[j].z);
                acc[j].w = fmaf(xs[j], w4.w, acc[j].w);
            }
        }
    }
    float* xz = d ? xzB : xzF;
#pragma unroll
    for (int j = 0; j < 8; ++j) {
        *(float4*)&xz[(r0 + r4 * 8 + j) * 128 + ch * 64 + c16 * 4] = acc[j];
    }
}

// ------------- conv + silu + xproj + delta, both dirs. grid 2048 (16 rows/block) -------------
__global__ __launch_bounds__(256) void prep3_kernel(
    const float* __restrict__ xzF_, const float* __restrict__ xzB_,
    const float* __restrict__ conv_w, const float* __restrict__ conv_b,
    const float* __restrict__ xproj_w, const float* __restrict__ dt_w,
    const float* __restrict__ dt_b, int layer,
    float* __restrict__ xpF_, float* __restrict__ xpB_,
    float* __restrict__ xbcF_, float* __restrict__ xbcB_,
    float* __restrict__ pkF_, float* __restrict__ pkB_)
{
    __shared__ float sW[64 * 132];
    __shared__ float sxp[4][64];
    __shared__ float sdl[4][4];
    const int tid = threadIdx.x, wv = tid >> 6, lane = tid & 63;
    const int dir = (int)(blockIdx.x >= 1024);        // block-uniform
    const int r0 = (blockIdx.x & 1023) * 16;          // 16 rows, same b
    const int b = r0 >> 9;
    const int m = layer * 2 + dir;
    // stage xproj W once for 16 rows
    const float* Wg = xproj_w + m * 8448;
    for (int q = tid; q < 8448; q += 256) sW[q] = Wg[q];
    const float* xz = dir ? xzB_ : xzF_;
    float* xp  = dir ? xpB_  : xpF_;
    float* xbc = dir ? xbcB_ : xbcF_;
    float* pkx = dir ? pkB_  : pkF_;
    // hoisted per-lane weights
    const float* cw = conv_w + m * 192 + lane * 3;
    const float cw0 = cw[0], cw1 = cw[1], cw2 = cw[2];
    const float cb  = conv_b[m * 64 + lane];
    const float dtb = dt_b[m * 64 + lane];
    const float* dwp = dt_w + m * 256;
    const float dw0 = dwp[lane], dw1 = dwp[64 + lane], dw2 = dwp[128 + lane], dw3 = dwp[192 + lane];
    __syncthreads();
    const int jdt = lane & 3;
    for (int it = 0; it < 4; ++it) {
        const int row = r0 + wv * 4 + it;
        const int l = row & 511;
        const int l1 = dir ? l + 1 : l - 1;
        const int l2 = dir ? l + 2 : l - 2;
        float acc = cb;
        const float x0 = xz[(size_t)row * 128 + lane];
        const float x1 = (l1 >= 0 && l1 < 512) ? xz[(size_t)(b * 512 + l1) * 128 + lane] : 0.f;
        const float x2 = (l2 >= 0 && l2 < 512) ? xz[(size_t)(b * 512 + l2) * 128 + lane] : 0.f;
        acc += cw0 * x2 + cw1 * x1 + cw2 * x0;
        const float u = acc * sigf(acc);   // silu
        xp[row * 64 + lane] = u;
        sxp[wv][lane] = u;
        float aB = 0.f, aC = 0.f, adt = 0.f;
#pragma unroll 8
        for (int k = 0; k < 64; ++k) {
            const float xv = sxp[wv][k];
            aB  = fmaf(xv, sW[k * 132 + 4 + lane], aB);
            aC  = fmaf(xv, sW[k * 132 + 68 + lane], aC);
            adt = fmaf(xv, sW[k * 132 + jdt], adt);
        }
        xbc[row * 128 + lane]      = aB;
        xbc[row * 128 + 64 + lane] = aC;
        if (lane < 4) sdl[wv][lane] = adt;
        float dpre = fmaf(sdl[wv][0], dw0, dtb);
        dpre = fmaf(sdl[wv][1], dw1, dpre);
        dpre = fmaf(sdl[wv][2], dw2, dpre);
        dpre = fmaf(sdl[wv][3], dw3, dpre);
        const float dlt = (dpre > 20.f) ? dpre : log1pf(__expf(dpre));
        ((float2*)pkx)[row * 64 + lane] = float2{dlt, dlt * u};
    }
}

// ------------- selective scan v3. grid 256 (block = (dir,b,e-quarter)), block 256 -------------
// thread t: e = e0 + (t>>4), n = (t&15)*4 .. +3. LDS-staged 16-step tiles, reg-prefetch dbuf.
__global__ __launch_bounds__(256) void scan3_kernel(
    const float* __restrict__ xbcF, const float* __restrict__ xbcB,
    const float* __restrict__ pkF, const float* __restrict__ pkB,
    const float* __restrict__ AlogF, const float* __restrict__ AlogB,
    float* __restrict__ ysF, float* __restrict__ ysB)
{
    __shared__ float sbc[2][16][128];   // 16 KB  (B|C rows)
    __shared__ float spk[2][16][32];    // 4 KB   (dl,du for 16 e)
    __shared__ float ytile[16][17];     // padded
    const int tid = threadIdx.x;
    const int dir = blockIdx.x >> 7;                  // block-uniform
    const int b   = (blockIdx.x >> 2) & 31;
    const int e0  = (blockIdx.x & 3) * 16;
    const float* xbc = dir ? xbcB : xbcF;
    const float* pk  = dir ? pkB  : pkF;
    const float* Aw  = dir ? AlogB : AlogF;
    float* ys = dir ? ysB : ysF;
    const int e_loc = tid >> 4;         // 0..15
    const int sub   = tid & 15;
    const int n0    = sub * 4;
    const int e     = e0 + e_loc;
    const float L2E = 1.4426950408889634f;
    const float a20 = -__expf(Aw[e * 64 + n0 + 0]) * L2E;
    const float a21 = -__expf(Aw[e * 64 + n0 + 1]) * L2E;
    const float a22 = -__expf(Aw[e * 64 + n0 + 2]) * L2E;
    const float a23 = -__expf(Aw[e * 64 + n0 + 3]) * L2E;
    float s0 = 0.f, s1 = 0.f, s2 = 0.f, s3 = 0.f;

    const int prow = tid >> 4, pf = tid & 15;         // pk staging coords
    // prologue: stage tile 0
    {
        const int rs = b * 512 + (dir ? 496 : 0);
        const float4 ba = *(const float4*)(xbc + (size_t)rs * 128 + tid * 8);
        const float4 bb = *(const float4*)(xbc + (size_t)rs * 128 + tid * 8 + 4);
        const float2 pp = *(const float2*)(pk + (size_t)(rs + prow) * 128 + e0 * 2 + pf * 2);
        *(float4*)(&sbc[0][0][0] + tid * 8)     = ba;
        *(float4*)(&sbc[0][0][0] + tid * 8 + 4) = bb;
        *(float2*)(&spk[0][0][0] + tid * 2)     = pp;
    }
    __syncthreads();

    int cur = 0;
    for (int t = 0; t < 32; ++t) {
        // prefetch tile t+1 into regs (flies during compute)
        float4 nba, nbb; float2 npp;
        const bool more = (t + 1) < 32;
        if (more) {
            const int rs = b * 512 + (dir ? (496 - (t + 1) * 16) : ((t + 1) * 16));
            nba = *(const float4*)(xbc + (size_t)rs * 128 + tid * 8);
            nbb = *(const float4*)(xbc + (size_t)rs * 128 + tid * 8 + 4);
            npp = *(const float2*)(pk + (size_t)(rs + prow) * 128 + e0 * 2 + pf * 2);
        }
        const float* bcur = &sbc[cur][0][0];
        const float* pcur = &spk[cur][0][0];
#pragma unroll
        for (int tt = 0; tt < 16; ++tt) {
            const int slot = dir ? (15 - tt) : tt;
            const float2 dd = *(const float2*)(pcur + slot * 32 + e_loc * 2);
            const float4 Bv = *(const float4*)(bcur + slot * 128 + n0);
            const float4 Cv = *(const float4*)(bcur + slot * 128 + 64 + n0);
            const float dl = dd.x, du = dd.y;
            s0 = exp2f(dl * a20) * s0 + du * Bv.x;
            s1 = exp2f(dl * a21) * s1 + du * Bv.y;
            s2 = exp2f(dl * a22) * s2 + du * Bv.z;
            s3 = exp2f(dl * a23) * s3 + du * Bv.w;
            float p = s0 * Cv.x;
            p = fmaf(s1, Cv.y, p);
            p = fmaf(s2, Cv.z, p);
            p = fmaf(s3, Cv.w, p);
            p += __shfl_xor(p, 1);
            p += __shfl_xor(p, 2);
            p += __shfl_xor(p, 4);
            p += __shfl_xor(p, 8);
            if (sub == 0) ytile[tt][e_loc] = p;
        }
        __syncthreads();
        // flush: thread t -> (e_out = t>>4, tt = t&15)
        {
            const int eo = tid >> 4, tt = tid & 15;
            const int l = dir ? (511 - (t * 16 + tt)) : (t * 16 + tt);
            ys[(size_t)(b * 64 + e0 + eo) * 512 + l] = ytile[tt][eo];
        }
        if (more) {
            float* bnx = &sbc[cur ^ 1][0][0];
            float* pnx = &spk[cur ^ 1][0][0];
            *(float4*)(bnx + tid * 8)     = nba;
            *(float4*)(bnx + tid * 8 + 4) = nbb;
            *(float2*)(pnx + tid * 2)     = npp;
        }
        __syncthreads();
        cur ^= 1;
    }
}

// ------------- gate v3: LDS transpose of ys + gate math. grid 512 (dir,b,l-tile), block 256 ----
__global__ __launch_bounds__(256) void gate3_kernel(
    const float* __restrict__ ysF_, const float* __restrict__ ysB_,
    const float* __restrict__ xpF_, const float* __restrict__ xpB_,
    const float* __restrict__ xzF_, const float* __restrict__ xzB_,
    const float* __restrict__ Dp, int layer,
    float* __restrict__ ygF_, float* __restrict__ ygB_)
{
    __shared__ float sy[64][65];
    const int tid = threadIdx.x;
    const int dir = blockIdx.x >> 8;
    const int rem = blockIdx.x & 255;
    const int b = rem >> 3, lt = rem & 7;
    const int l0 = lt * 64;
    const float* ys = dir ? ysB_ : ysF_;
    const float* xp = dir ? xpB_ : xpF_;
    const float* xz = dir ? xzB_ : xzF_;
    float* yg = dir ? ygB_ : ygF_;
    for (int q = tid; q < 4096; q += 256) {
        const int e = q >> 6, l = q & 63;
        sy[e][l] = ys[(size_t)(b * 64 + e) * 512 + l0 + l];
    }
    __syncthreads();
    const int m = layer * 2 + dir;
    for (int q = tid; q < 4096; q += 256) {
        const int l = q >> 6, e = q & 63;
        const int bl = b * 512 + l0 + l;
        const float dv = Dp[m * 64 + e];
        const float u = xp[(size_t)bl * 64 + e];
        const float res = xz[(size_t)bl * 128 + 64 + e];
        yg[(size_t)bl * 64 + e] = (sy[e][l] + u * dv) * sigf(res);
    }
}

// ------------- out-proj (both dirs as K=128 GEMM) + residual + LN1 -> Y3 -------------
__global__ __launch_bounds__(256) void opln_kernel(
    const float* __restrict__ ygF, const float* __restrict__ ygB,
    const float* __restrict__ Xc, const float* __restrict__ out_w, int layer,
    const float* __restrict__ g, const float* __restrict__ bb,
    float* __restrict__ Y3)
{
    __shared__ float sy[16][128];   // [row][ygF|ygB]
    __shared__ float sw[32][128];
    const int tid = threadIdx.x;
    const int r0 = blockIdx.x * 16;
    for (int q = tid; q < 2048; q += 256) {
        const int r = q >> 7, c = q & 127;
        sy[r][c] = (c < 64) ? ygF[(r0 + r) * 64 + c] : ygB[(r0 + r) * 64 + (c - 64)];
    }
    const int wv = tid >> 6, lane = tid & 63;
    const float* WFp = out_w + (layer * 2) * 8192;
    const float* WBp = out_w + (layer * 2 + 1) * 8192;
    float acc[4][2];
#pragma unroll
    for (int r = 0; r < 4; ++r) { acc[r][0] = 0.f; acc[r][1] = 0.f; }
    for (int ko = 0; ko < 128; ko += 32) {
        __syncthreads();
        for (int q = tid; q < 4096; q += 256) {
            const int kk = q >> 7, c = q & 127;
            const int kg = ko + kk;
            sw[kk][c] = (kg < 64) ? WFp[kg * 128 + c] : WBp[(kg - 64) * 128 + c];
        }
        __syncthreads();
#pragma unroll
        for (int kk = 0; kk < 32; ++kk) {
            const float w0 = sw[kk][lane], w1 = sw[kk][lane + 64];
            const int kg = ko + kk;
#pragma unroll
            for (int r = 0; r < 4; ++r) {
                const float yv = sy[wv * 4 + r][kg];
                acc[r][0] = fmaf(yv, w0, acc[r][0]);
                acc[r][1] = fmaf(yv, w1, acc[r][1]);
            }
        }
    }
#pragma unroll
    for (int r = 0; r < 4; ++r) {
        const int row = r0 + wv * 4 + r;
        float v0 = acc[r][0] + Xc[row * 128 + lane];
        float v1 = acc[r][1] + Xc[row * 128 + lane + 64];
        float sum = v0 + v1, sq = v0 * v0 + v1 * v1;
#pragma unroll
        for (int o = 32; o >= 1; o >>= 1) { sum += __shfl_xor(sum, o); sq += __shfl_xor(sq, o); }
        const float mean = sum * (1.f / 128.f);
        const float var = sq * (1.f / 128.f) - mean * mean;
        const float rs = rsqrtf(var + 1e-5f);
        Y3[row * 128 + lane]      = (v0 - mean) * rs * g[lane] + bb[lane];
        Y3[row * 128 + lane + 64] = (v1 - mean) * rs * g[lane + 64] + bb[lane + 64];
    }
}

// ------------- FFN1 + FFN2 + residual + LN2 -> x. grid 1024, block 256 (16 rows) -------------
__global__ __launch_bounds__(256) void ffn_kernel(
    const float* __restrict__ Y3, const float* __restrict__ W1, const float* __restrict__ b1,
    const float* __restrict__ W2, const float* __restrict__ b2,
    const float* __restrict__ g, const float* __restrict__ bb, float* __restrict__ xout)
{
    __shared__ float sx[16][128];
    __shared__ float sw1[128][32];
    __shared__ float sh[16][32];
    __shared__ float sw2[32][128];
    const int tid = threadIdx.x;
    const int r0 = blockIdx.x * 16;
    for (int q = tid; q < 2048; q += 256) sx[q >> 7][q & 127] = Y3[r0 * 128 + q];
    for (int q = tid; q < 4096; q += 256) sw1[q >> 5][q & 31] = W1[q];
    for (int q = tid; q < 4096; q += 256) sw2[q >> 7][q & 127] = W2[q];
    __syncthreads();
    {
        const int r = tid >> 4, u = tid & 15;
        float h0 = b1[u], h1 = b1[u + 16];
#pragma unroll 8
        for (int k = 0; k < 128; ++k) {
            const float xv = sx[r][k];
            h0 = fmaf(xv, sw1[k][u], h0);
            h1 = fmaf(xv, sw1[k][u + 16], h1);
        }
        sh[r][u]      = fmaxf(h0, 0.f);
        sh[r][u + 16] = fmaxf(h1, 0.f);
    }
    __syncthreads();
    const int wv = tid >> 6, lane = tid & 63;
#pragma unroll
    for (int r = 0; r < 4; ++r) {
        const int rl = wv * 4 + r;
        float a0 = b2[lane], a1 = b2[lane + 64];
#pragma unroll 8
        for (int k = 0; k < 32; ++k) {
            const float hv = sh[rl][k];
            a0 = fmaf(hv, sw2[k][lane], a0);
            a1 = fmaf(hv, sw2[k][lane + 64], a1);
        }
        const float v0 = a0 + sx[rl][lane];
        const float v1 = a1 + sx[rl][lane + 64];
        float sum = v0 + v1, sq = v0 * v0 + v1 * v1;
#pragma unroll
        for (int o = 32; o >= 1; o >>= 1) { sum += __shfl_xor(sum, o); sq += __shfl_xor(sq, o); }
        const float mean = sum * (1.f / 128.f);
        const float var = sq * (1.f / 128.f) - mean * mean;
        const float rs = rsqrtf(var + 1e-5f);
        const int row = r0 + rl;
        xout[row * 128 + lane]      = (v0 - mean) * rs * g[lane] + bb[lane];
        xout[row * 128 + lane + 64] = (v1 - mean) * rs * g[lane + 64] + bb[lane + 64];
    }
}

// ================= head =================
__global__ __launch_bounds__(256) void head_prep_kernel(
    const float* __restrict__ psi, const float* __restrict__ W_q, const float* __restrict__ W_k,
    const float* __restrict__ f_b, const float* __restrict__ hmix, const float* __restrict__ attn_a,
    float* __restrict__ mixb, float* __restrict__ alphab, float* __restrict__ bft,
    float* __restrict__ Qb, float* __restrict__ Kb)
{
    const int tid = threadIdx.x;
    const float m0 = hmix[0], m1 = hmix[1], m2 = hmix[2], m3 = hmix[3];
    const float mx = fmaxf(fmaxf(m0, m1), fmaxf(m2, m3));
    const float e0 = __expf(m0 - mx), e1 = __expf(m1 - mx), e2 = __expf(m2 - mx), e3 = __expf(m3 - mx);
    const float inv = 1.f / (e0 + e1 + e2 + e3);
    float mixv[4] = {e0 * inv, e1 * inv, e2 * inv, e3 * inv};
    if (tid < 4) mixb[tid] = mixv[tid];
    if (tid == 4) alphab[0] = sigf(attn_a[0]);
    if (tid < 128) {
        float s = 0.f;
        for (int h = 0; h < 4; ++h) {
            float t = 0.f;
            for (int d = 0; d < 10; ++d) t = fmaf(psi[tid * 10 + d], f_b[h * 10 + d], t);
            s = fmaf(mixv[h], t, s);
        }
        bft[tid] = s;
    }
    for (int idx = tid; idx < 5120; idx += 256) {
        const int n = idx / 40, rem = idx - n * 40, h = rem / 10, d = rem - h * 10;
        float q = 0.f, kk = 0.f;
        for (int d0 = 0; d0 < 10; ++d0) {
            const float pv = psi[n * 10 + d0];
            q = fmaf(pv, W_q[(d0 * 4 + h) * 10 + d], q);
            kk = fmaf(pv, W_k[(d0 * 4 + h) * 10 + d], kk);
        }
        Qb[idx] = q; Kb[idx] = kk;
    }
}

__global__ __launch_bounds__(256) void head_qk_kernel(
    const float* __restrict__ psi, const float* __restrict__ psis,
    const float* __restrict__ Qb, const float* __restrict__ Kb,
    float* __restrict__ gbuf, float* __restrict__ qkbuf)
{
    const int idx = blockIdx.x * 256 + threadIdx.x;  // 16384
    const int n = idx >> 7, mcol = idx & 127;
    float d2 = 0.f;
#pragma unroll
    for (int d = 0; d < 10; ++d) { const float df = psi[n * 10 + d] - psi[mcol * 10 + d]; d2 = fmaf(df, df, d2); }
    gbuf[idx] = __expf(-psis[0] * d2);
#pragma unroll
    for (int h = 0; h < 4; ++h) {
        float qq = 0.f;
#pragma unroll
        for (int d = 0; d < 10; ++d) qq = fmaf(Qb[n * 40 + h * 10 + d], Kb[mcol * 40 + h * 10 + d], qq);
        qkbuf[h * 16384 + idx] = qq * 0.3162277660168379332f;  // 1/sqrt(10)
    }
}

__global__ __launch_bounds__(128) void head_aeff_kernel(
    const float* __restrict__ gbuf, const float* __restrict__ qkbuf, const float* __restrict__ alphab,
    float* __restrict__ Aeff, float* __restrict__ StT)
{
    __shared__ float red[128];
    const int h = blockIdx.x >> 7, n = blockIdx.x & 127, mcol = threadIdx.x;
    const float gv = gbuf[n * 128 + mcol];
    const float qv = qkbuf[h * 16384 + n * 128 + mcol];
    float r;
    red[mcol] = gv; __syncthreads();
    for (int s = 64; s >= 1; s >>= 1) { if (mcol < s) red[mcol] = fmaxf(red[mcol], red[mcol + s]); __syncthreads(); }
    r = red[0]; __syncthreads();
    const float eg = __expf(gv - r);
    red[mcol] = eg; __syncthreads();
    for (int s = 64; s >= 1; s >>= 1) { if (mcol < s) red[mcol] += red[mcol + s]; __syncthreads(); }
    const float gsum = red[0]; __syncthreads();
    red[mcol] = qv; __syncthreads();
    for (int s = 64; s >= 1; s >>= 1) { if (mcol < s) red[mcol] = fmaxf(red[mcol], red[mcol + s]); __syncthreads(); }
    r = red[0]; __syncthreads();
    const float eq = __expf(qv - r);
    red[mcol] = eq; __syncthreads();
    for (int s = 64; s >= 1; s >>= 1) { if (mcol < s) red[mcol] += red[mcol + s]; __syncthreads(); }
    const float qsum = red[0];
    const float al = alphab[0];
    const float aeff = al * (eg / gsum) + (1.f - al) * (eq / qsum);
    Aeff[h * 16384 + n * 128 + mcol] = aeff;
    StT[((h * 4 + 1) * 128 + mcol) * 128 + n] = aeff;
    StT[((h * 4 + 0) * 128 + mcol) * 128 + n] = (mcol == n) ? 1.f : 0.f;
}

__global__ __launch_bounds__(256) void head_cheb_kernel(
    const float* __restrict__ Aeff, float* __restrict__ StT, int kk)
{
    const int h = blockIdx.x >> 6;
    const int m0 = ((blockIdx.x & 63) << 1) + (threadIdx.x >> 7);
    const int n = threadIdx.x & 127;
    const float* Ar = Aeff + h * 16384 + n * 128;
    const float* Sp = StT + ((h * 4 + kk - 1) * 128 + m0) * 128;
    float acc = 0.f;
#pragma unroll 8
    for (int p = 0; p < 128; ++p) acc = fmaf(Ar[p], Sp[p], acc);
    const float s2 = StT[((h * 4 + kk - 2) * 128 + m0) * 128 + n];
    StT[((h * 4 + kk) * 128 + m0) * 128 + n] = 2.f * acc - s2;
}

__global__ __launch_bounds__(256) void head_wf_kernel(
    const float* __restrict__ psi, const float* __restrict__ F_w, float* __restrict__ WfT)
{
    const int idx = blockIdx.x * 256 + threadIdx.x;  // 2^20
    const int n = idx & 127, l = (idx >> 7) & 511, k = (idx >> 16) & 3, h = idx >> 18;
    float acc = 0.f;
#pragma unroll
    for (int d = 0; d < 10; ++d)
        acc = fmaf(psi[n * 10 + d], F_w[((h * 10 + d) * 4 + k) * 512 + l], acc);
    WfT[idx] = acc;
}

// head_v3: thread owns (m, n) and 8 l's; 16 StT loads amortized. grid 4096, block 256.
__global__ __launch_bounds__(256) void head_v3_kernel(
    const float* __restrict__ StT, const float* __restrict__ WfT, const float* __restrict__ mixb,
    float* __restrict__ V)
{
    // bx: lt = bx & 63 (l0 = lt*8), mm = bx >> 6 (0..63); thread: n = t&127, mh = t>>7; m = mm*2+mh
    const int tid = threadIdx.x;
    const int lt = blockIdx.x & 63, mm = blockIdx.x >> 6;
    const int n = tid & 127, mh = tid >> 7;
    const int m = mm * 2 + mh;
    const int l0 = lt * 8;
    float sv[16];
#pragma unroll
    for (int h = 0; h < 4; ++h) {
        const float mx = mixb[h];
#pragma unroll
        for (int k = 0; k < 4; ++k)
            sv[h * 4 + k] = mx * StT[(size_t)((h * 4 + k) * 128 + m) * 128 + n];
    }
#pragma unroll
    for (int j = 0; j < 8; ++j) {
        const int l = l0 + j;
        float acc = 0.f;
#pragma unroll
        for (int hk = 0; hk < 16; ++hk)
            acc = fmaf(sv[hk], WfT[(size_t)(hk * 512 + l) * 128 + n], acc);
        V[(size_t)(l * 128 + m) * 128 + n] = acc;
    }
}

__global__ __launch_bounds__(128) void head_ctr_kernel(
    const float* __restrict__ Xf, const float* __restrict__ V, float* __restrict__ partial)
{
    __shared__ float sx[32][128];
    const int l = blockIdx.x, tid = threadIdx.x;
    for (int q = tid; q < 4096; q += 128) {
        const int b = q >> 7, mm = q & 127;
        sx[b][mm] = Xf[(b * 512 + l) * 128 + mm];
    }
    __syncthreads();
    float acc[32];
#pragma unroll
    for (int b = 0; b < 32; ++b) acc[b] = 0.f;
    for (int mm = 0; mm < 128; ++mm) {
        const float v = V[(l * 128 + mm) * 128 + tid];
#pragma unroll
        for (int b = 0; b < 32; ++b) acc[b] = fmaf(sx[b][mm], v, acc[b]);
    }
#pragma unroll
    for (int b = 0; b < 32; ++b) partial[(blockIdx.x * 32 + b) * 128 + tid] = acc[b];
}

__global__ __launch_bounds__(128) void head_out_kernel(
    const float* __restrict__ partial, const float* __restrict__ bft,
    const float* __restrict__ head_w, const float* __restrict__ head_b, float* __restrict__ out)
{
    __shared__ float red[128];
    const int b = blockIdx.x, n = threadIdx.x;
    float s = bft[n];
    for (int c = 0; c < 512; ++c) s += partial[(c * 32 + b) * 128 + n];
    red[n] = s * head_w[n];
    __syncthreads();
    for (int st = 64; st >= 1; st >>= 1) { if (n < st) red[n] += red[n + st]; __syncthreads(); }
    if (n == 0) out[b] = red[0] + head_b[0];
    out[32 + b * 128 + n] = 0.f;   // log_var = zeros
}

extern "C" void kernel_launch(void* const* d_in, const int* in_sizes, int n_in,
                              void* d_out, int out_size, void* d_ws, size_t ws_size,
                              hipStream_t stream) {
    const float* x_in    = (const float*)d_in[0];
    const float* in_w    = (const float*)d_in[1];
    const float* conv_w  = (const float*)d_in[2];
    const float* conv_b  = (const float*)d_in[3];
    const float* xproj_w = (const float*)d_in[4];
    const float* dt_w    = (const float*)d_in[5];
    const float* dt_b    = (const float*)d_in[6];
    const float* Alog    = (const float*)d_in[7];
    const float* Dp      = (const float*)d_in[8];
    const float* out_w   = (const float*)d_in[9];
    const float* ln1_g   = (const float*)d_in[10];
    const float* ln1_b   = (const float*)d_in[11];
    const float* ln2_g   = (const float*)d_in[12];
    const float* ln2_b   = (const float*)d_in[13];
    const float* ffn_w1  = (const float*)d_in[14];
    const float* ffn_b1  = (const float*)d_in[15];
    const float* ffn_w2  = (const float*)d_in[16];
    const float* ffn_b2  = (const float*)d_in[17];
    const float* psi_emb = (const float*)d_in[18];
    const float* psi_s   = (const float*)d_in[19];
    const float* W_q     = (const float*)d_in[20];
    const float* W_k     = (const float*)d_in[21];
    const float* attn_a  = (const float*)d_in[22];
    const float* F_w     = (const float*)d_in[23];
    const float* f_b     = (const float*)d_in[24];
    const float* hmix    = (const float*)d_in[25];
    const float* head_w  = (const float*)d_in[26];
    const float* head_b  = (const float*)d_in[27];
    float* ws = (float*)d_ws;
    float* outp = (float*)d_out;

    for (int i = 0; i < 3; ++i) {
        const float* xcur = (i == 0) ? x_in : (ws + OFF_X);
        const int mF = 2 * i, mB = 2 * i + 1;
        gemm_in2_kernel<<<512, 256, 0, stream>>>(
            xcur, in_w + mF * 16384, in_w + mB * 16384, ws + OFF_XZF, ws + OFF_XZB);
        prep3_kernel<<<2048, 256, 0, stream>>>(
            ws + OFF_XZF, ws + OFF_XZB, conv_w, conv_b, xproj_w, dt_w, dt_b, i,
            ws + OFF_XPF, ws + OFF_XPB, ws + OFF_XBCF, ws + OFF_XBCB, ws + OFF_PKF, ws + OFF_PKB);
        scan3_kernel<<<256, 256, 0, stream>>>(
            ws + OFF_XBCF, ws + OFF_XBCB, ws + OFF_PKF, ws + OFF_PKB,
            Alog + mF * 4096, Alog + mB * 4096, ws + OFF_YSF, ws + OFF_YSB);
        gate3_kernel<<<512, 256, 0, stream>>>(
            ws + OFF_YSF, ws + OFF_YSB, ws + OFF_XPF, ws + OFF_XPB, ws + OFF_XZF, ws + OFF_XZB,
            Dp, i, ws + OFF_YGF, ws + OFF_YGB);
        opln_kernel<<<1024, 256, 0, stream>>>(
            ws + OFF_YGF, ws + OFF_YGB, xcur, out_w, i,
            ln1_g + i * 128, ln1_b + i * 128, ws + OFF_Y3);
        ffn_kernel<<<1024, 256, 0, stream>>>(
            ws + OFF_Y3, ffn_w1 + i * 4096, ffn_b1 + i * 32,
            ffn_w2 + i * 4096, ffn_b2 + i * 128,
            ln2_g + i * 128, ln2_b + i * 128, ws + OFF_X);
    }
    // head
    head_prep_kernel<<<1, 256, 0, stream>>>(
        psi_emb, W_q, W_k, f_b, hmix, attn_a,
        ws + OFF_MIX, ws + OFF_ALPH, ws + OFF_BFT, ws + OFF_QB, ws + OFF_KB);
    head_qk_kernel<<<64, 256, 0, stream>>>(
        psi_emb, psi_s, ws + OFF_QB, ws + OFF_KB, ws + OFF_GB, ws + OFF_QKB);
    head_aeff_kernel<<<512, 128, 0, stream>>>(
        ws + OFF_GB, ws + OFF_QKB, ws + OFF_ALPH, ws + OFF_AEFF, ws + OFF_STT);
    head_cheb_kernel<<<256, 256, 0, stream>>>(ws + OFF_AEFF, ws + OFF_STT, 2);
    head_cheb_kernel<<<256, 256, 0, stream>>>(ws + OFF_AEFF, ws + OFF_STT, 3);
    head_wf_kernel<<<4096, 256, 0, stream>>>(psi_emb, F_w, ws + OFF_WFT);
    head_v3_kernel<<<4096, 256, 0, stream>>>(ws + OFF_STT, ws + OFF_WFT, ws + OFF_MIX, ws + OFF_V);
    head_ctr_kernel<<<512, 128, 0, stream>>>(ws + OFF_X, ws + OFF_V, ws + OFF_PART);
    head_out_kernel<<<32, 128, 0, stream>>>(
        ws + OFF_PART, ws + OFF_BFT, head_w, head_b, outp);
}

// Round 4
// 687.949 us; speedup vs baseline: 1.4114x; 1.4114x over previous
//
#include <hip/hip_runtime.h>
#include <hip/hip_bf16.h>

// MAMBA_BayesMAGAC: B=32, L=512, D=128, E=64, HS=64, DTR=4, U=32, R=3, K=3, DE=10, NH=4
// Round 4: scan v4 = scan2 occupancy (wave=(b,e), lane=n, 4 waves/SIMD) + LDS-staged
// double-buffered B/C tiles (interleaved), static-indexed 16-step bodies.
// head_ctr rebuilt for occupancy (256 thr, m-split).

#define B_ 32
#define L_ 512
#define D_ 128
#define E_ 64
#define HS_ 64

// ---- workspace offsets (floats) ----
#define OFF_X     0u          // 2,097,152  x [b][l][128]
#define OFF_XZF   2097152u    // 2,097,152  xz fwd [b][l][128]
#define OFF_XZB   4194304u
#define OFF_XPF   6291456u    // 1,048,576  xp [b][l][64]
#define OFF_XPB   7340032u
#define OFF_PKF   8388608u    // 2,097,152  (dl,du) [b][l][64][2]
#define OFF_PKB   10485760u
#define OFF_XBCF  12582912u   // 2,097,152  (B,C) interleaved [b][l][n][2]
#define OFF_XBCB  14680064u
#define OFF_YSF   16777216u   // 1,048,576  scan y [b][e][l]
#define OFF_YSB   17825792u   // end 18,874,368 floats = 75.5 MB
// reuse (liveness-checked):
#define OFF_YGF   8388608u    // over PKF (dead after scan)
#define OFF_YGB   9437184u
#define OFF_Y3    16777216u   // over YSF+YSB (dead after gate)
// head phase (only OFF_X live):
#define OFF_V     2097152u    // 8,388,608  V [l][m][n]
#define OFF_WFT   10485760u   // 1,048,576  Wf [h][k][l][n]
#define OFF_STT   11534336u   // 262,144    S^T [h][k][m][n]
#define OFF_AEFF  11796480u   // 65,536
#define OFF_GB    11862016u   // 16,384
#define OFF_QKB   11878400u   // 65,536
#define OFF_QB    11943936u   // 5,120
#define OFF_KB    11949056u   // 5,120
#define OFF_MIX   11954176u   // 4
#define OFF_ALPH  11954180u   // 1
#define OFF_BFT   11954184u   // 128
#define OFF_PART  12582912u   // 4,194,304  partial [512][2][32][128] (ends 16,777,216)

__device__ __forceinline__ float sigf(float x) { return 1.f / (1.f + __expf(-x)); }

// ---------------- in-projection: xz = x @ in_w (both dirs), 32 rows/block ----------------
__global__ __launch_bounds__(256) void gemm_in2_kernel(
    const float* __restrict__ X, const float* __restrict__ WF, const float* __restrict__ WB,
    float* __restrict__ xzF, float* __restrict__ xzB)
{
    __shared__ float sxT[128][36];    // transposed x tile, padded
    __shared__ float sw[2][16][128];
    const int tid = threadIdx.x;
    const int r0 = blockIdx.x * 32;
    for (int q = tid; q < 32 * 128; q += 256) {
        const int r = q >> 7, k = q & 127;
        sxT[k][r] = X[(r0 + r) * 128 + k];
    }
    const int wv = tid >> 6, lane = tid & 63;
    const int d = wv >> 1, ch = wv & 1;
    const int r4 = lane >> 4, c16 = lane & 15;
    float4 acc[8];
#pragma unroll
    for (int j = 0; j < 8; ++j) acc[j] = float4{0.f, 0.f, 0.f, 0.f};
    for (int ko = 0; ko < 128; ko += 16) {
        __syncthreads();
        for (int q = tid; q < 2 * 16 * 128; q += 256) {
            const int dd = q >> 11, kk = (q >> 7) & 15, c = q & 127;
            sw[dd][kk][c] = (dd ? WB : WF)[(ko + kk) * 128 + c];
        }
        __syncthreads();
#pragma unroll
        for (int kk = 0; kk < 16; ++kk) {
            const float4 w4 = *(const float4*)&sw[d][kk][ch * 64 + c16 * 4];
            const float4 xa = *(const float4*)&sxT[ko + kk][r4 * 8];
            const float4 xb = *(const float4*)&sxT[ko + kk][r4 * 8 + 4];
            const float xs[8] = {xa.x, xa.y, xa.z, xa.w, xb.x, xb.y, xb.z, xb.w};
#pragma unroll
            for (int j = 0; j < 8; ++j) {
                acc[j].x = fmaf(xs[j], w4.x, acc[j].x);
                acc[j].y = fmaf(xs[j], w4.y, acc[j].y);
                acc[j].z = fmaf(xs[j], w4.z, acc[j].z);
                acc[j].w = fmaf(xs[j], w4.w, acc[j].w);
            }
        }
    }
    float* xz = d ? xzB : xzF;
#pragma unroll
    for (int j = 0; j < 8; ++j) {
        *(float4*)&xz[(r0 + r4 * 8 + j) * 128 + ch * 64 + c16 * 4] = acc[j];
    }
}

// ------------- conv + silu + xproj + delta, both dirs. grid 2048 (16 rows/block) -------------
__global__ __launch_bounds__(256) void prep3_kernel(
    const float* __restrict__ xzF_, const float* __restrict__ xzB_,
    const float* __restrict__ conv_w, const float* __restrict__ conv_b,
    const float* __restrict__ xproj_w, const float* __restrict__ dt_w,
    const float* __restrict__ dt_b, int layer,
    float* __restrict__ xpF_, float* __restrict__ xpB_,
    float* __restrict__ xbcF_, float* __restrict__ xbcB_,
    float* __restrict__ pkF_, float* __restrict__ pkB_)
{
    __shared__ float sW[64 * 132];
    __shared__ float sxp[4][64];
    __shared__ float sdl[4][4];
    const int tid = threadIdx.x, wv = tid >> 6, lane = tid & 63;
    const int dir = (int)(blockIdx.x >= 1024);        // block-uniform
    const int r0 = (blockIdx.x & 1023) * 16;          // 16 rows, same b
    const int b = r0 >> 9;
    const int m = layer * 2 + dir;
    const float* Wg = xproj_w + m * 8448;
    for (int q = tid; q < 8448; q += 256) sW[q] = Wg[q];
    const float* xz = dir ? xzB_ : xzF_;
    float* xp  = dir ? xpB_  : xpF_;
    float* xbc = dir ? xbcB_ : xbcF_;
    float* pkx = dir ? pkB_  : pkF_;
    const float* cw = conv_w + m * 192 + lane * 3;
    const float cw0 = cw[0], cw1 = cw[1], cw2 = cw[2];
    const float cb  = conv_b[m * 64 + lane];
    const float dtb = dt_b[m * 64 + lane];
    const float* dwp = dt_w + m * 256;
    const float dw0 = dwp[lane], dw1 = dwp[64 + lane], dw2 = dwp[128 + lane], dw3 = dwp[192 + lane];
    __syncthreads();
    const int jdt = lane & 3;
    for (int it = 0; it < 4; ++it) {
        const int row = r0 + wv * 4 + it;
        const int l = row & 511;
        const int l1 = dir ? l + 1 : l - 1;
        const int l2 = dir ? l + 2 : l - 2;
        float acc = cb;
        const float x0 = xz[(size_t)row * 128 + lane];
        const float x1 = (l1 >= 0 && l1 < 512) ? xz[(size_t)(b * 512 + l1) * 128 + lane] : 0.f;
        const float x2 = (l2 >= 0 && l2 < 512) ? xz[(size_t)(b * 512 + l2) * 128 + lane] : 0.f;
        acc += cw0 * x2 + cw1 * x1 + cw2 * x0;
        const float u = acc * sigf(acc);   // silu
        xp[row * 64 + lane] = u;
        sxp[wv][lane] = u;
        float aB = 0.f, aC = 0.f, adt = 0.f;
#pragma unroll 8
        for (int k = 0; k < 64; ++k) {
            const float xv = sxp[wv][k];
            aB  = fmaf(xv, sW[k * 132 + 4 + lane], aB);
            aC  = fmaf(xv, sW[k * 132 + 68 + lane], aC);
            adt = fmaf(xv, sW[k * 132 + jdt], adt);
        }
        // interleaved (B,C): xbc[row][n][2]
        ((float2*)(xbc + (size_t)row * 128))[lane] = float2{aB, aC};
        if (lane < 4) sdl[wv][lane] = adt;
        float dpre = fmaf(sdl[wv][0], dw0, dtb);
        dpre = fmaf(sdl[wv][1], dw1, dpre);
        dpre = fmaf(sdl[wv][2], dw2, dpre);
        dpre = fmaf(sdl[wv][3], dw3, dpre);
        const float dlt = (dpre > 20.f) ? dpre : log1pf(__expf(dpre));
        ((float2*)pkx)[row * 64 + lane] = float2{dlt, dlt * u};
    }
}

// ------------- selective scan v4. grid 1024 (block = (dir,b,e-quad)), block 256 -------------
// wave wv owns e = e0+wv, lane = n. B/C tiles block-shared in LDS, dbuf + reg prefetch.
__global__ __launch_bounds__(256, 4) void scan4_kernel(
    const float* __restrict__ xbcF, const float* __restrict__ xbcB,
    const float* __restrict__ pkF, const float* __restrict__ pkB,
    const float* __restrict__ AlogF, const float* __restrict__ AlogB,
    float* __restrict__ ysF, float* __restrict__ ysB)
{
    __shared__ float sbc[2][16][128];     // 16 KB: [buf][slot][n*2] (B,C interleaved)
    __shared__ float spk[2][4][16][2];    // 1 KB:  [buf][wave_e][slot][dl,du]
    __shared__ float ytile[4][16][68];    // 17.4 KB: per-wave [step][n] (padded)
    const int tid = threadIdx.x, wv = tid >> 6, lane = tid & 63;
    const int bx = blockIdx.x;
    const int dir = bx >> 9;              // block-uniform
    const int b   = (bx >> 4) & 31;
    const int e0  = (bx & 15) * 4;
    const int e   = e0 + wv;
    const float* xbc = dir ? xbcB : xbcF;
    const float* pk  = dir ? pkB  : pkF;
    const float* Aw  = dir ? AlogB : AlogF;
    float* ys = dir ? ysB : ysF;
    const float a2 = -__expf(Aw[e * 64 + lane]) * 1.4426950408889634f;
    float s = 0.f;
    float* yrow = ys + (size_t)(b * 64 + e) * 512;

    // staging coords
    const int psl = tid & 15, pw_ = tid >> 4;   // tid<64: pk (slot, wave_e)

#define STG_LOAD(RS)                                                              \
    {                                                                             \
        nba = *(const float4*)(xbc + (size_t)(RS) * 128 + tid * 8);               \
        nbb = *(const float4*)(xbc + (size_t)(RS) * 128 + tid * 8 + 4);           \
        if (tid < 64)                                                             \
            npp = *(const float2*)(pk + (size_t)((RS) + psl) * 128 + (e0 + pw_) * 2); \
    }
#define STG_WRITE(BUF)                                                            \
    {                                                                             \
        *(float4*)(&sbc[BUF][0][0] + tid * 8)     = nba;                          \
        *(float4*)(&sbc[BUF][0][0] + tid * 8 + 4) = nbb;                          \
        if (tid < 64) *(float2*)(&spk[BUF][pw_][psl][0]) = npp;                   \
    }

    // 16 steps from buffer `cur`; REV=0 slots 0..15, REV=1 slots 15..0. Static indices only.
#define SCAN16(REV)                                                               \
    {                                                                             \
        const float* bc = &sbc[cur][0][0];                                        \
        const float* pq = &spk[cur][wv][0][0];                                    \
        _Pragma("unroll")                                                         \
        for (int j = 0; j < 8; ++j) {                                             \
            const int pj = (REV) ? 7 - j : j;                                     \
            const float4 pk4 = *(const float4*)(pq + pj * 4);                     \
            const int sA = (REV) ? 15 - 2 * j : 2 * j;                            \
            const int sB = (REV) ? 14 - 2 * j : 2 * j + 1;                        \
            const float dlA = (REV) ? pk4.z : pk4.x;                              \
            const float duA = (REV) ? pk4.w : pk4.y;                              \
            const float dlB = (REV) ? pk4.x : pk4.z;                              \
            const float duB = (REV) ? pk4.y : pk4.w;                              \
            const float2 BCa = *(const float2*)(bc + sA * 128 + lane * 2);        \
            s = fmaf(exp2f(dlA * a2), s, duA * BCa.x);                            \
            ytile[wv][2 * j][lane] = s * BCa.y;                                   \
            const float2 BCb = *(const float2*)(bc + sB * 128 + lane * 2);        \
            s = fmaf(exp2f(dlB * a2), s, duB * BCb.x);                            \
            ytile[wv][2 * j + 1][lane] = s * BCb.y;                               \
        }                                                                         \
    }

    // prologue: stage tile 0
    {
        float4 nba, nbb; float2 npp;
        const int rs0 = b * 512 + (dir ? 496 : 0);
        STG_LOAD(rs0);
        STG_WRITE(0);
    }
    __syncthreads();

    int cur = 0;
    const int rr = lane & 15, sg = lane >> 4;
    for (int t = 0; t < 32; ++t) {
        float4 nba, nbb; float2 npp;
        const bool more = (t + 1) < 32;
        if (more) {
            const int rs = b * 512 + (dir ? (496 - (t + 1) * 16) : ((t + 1) * 16));
            STG_LOAD(rs);
        }
        if (dir == 0) { SCAN16(0) } else { SCAN16(1) }
        // per-wave reduce of own ytile: lane -> (step rr, segment sg of 16 n's)
        {
            const float* yt = &ytile[wv][rr][sg * 16];
            const float4 A0 = *(const float4*)yt;
            const float4 A1 = *(const float4*)(yt + 4);
            const float4 A2 = *(const float4*)(yt + 8);
            const float4 A3 = *(const float4*)(yt + 12);
            float p = ((A0.x + A0.y) + (A0.z + A0.w)) + ((A1.x + A1.y) + (A1.z + A1.w))
                    + ((A2.x + A2.y) + (A2.z + A2.w)) + ((A3.x + A3.y) + (A3.z + A3.w));
            p += __shfl_xor(p, 16);
            p += __shfl_xor(p, 32);
            if (lane < 16) {
                const int lg = dir ? (511 - (t * 16 + rr)) : (t * 16 + rr);
                yrow[lg] = p;
            }
        }
        __syncthreads();
        if (more) STG_WRITE(cur ^ 1);
        __syncthreads();
        cur ^= 1;
    }
#undef STG_LOAD
#undef STG_WRITE
#undef SCAN16
}

// ------------- gate v3: LDS transpose of ys + gate math. grid 512, block 256 ----
__global__ __launch_bounds__(256) void gate3_kernel(
    const float* __restrict__ ysF_, const float* __restrict__ ysB_,
    const float* __restrict__ xpF_, const float* __restrict__ xpB_,
    const float* __restrict__ xzF_, const float* __restrict__ xzB_,
    const float* __restrict__ Dp, int layer,
    float* __restrict__ ygF_, float* __restrict__ ygB_)
{
    __shared__ float sy[64][65];
    const int tid = threadIdx.x;
    const int dir = blockIdx.x >> 8;
    const int rem = blockIdx.x & 255;
    const int b = rem >> 3, lt = rem & 7;
    const int l0 = lt * 64;
    const float* ys = dir ? ysB_ : ysF_;
    const float* xp = dir ? xpB_ : xpF_;
    const float* xz = dir ? xzB_ : xzF_;
    float* yg = dir ? ygB_ : ygF_;
    for (int q = tid; q < 4096; q += 256) {
        const int e = q >> 6, l = q & 63;
        sy[e][l] = ys[(size_t)(b * 64 + e) * 512 + l0 + l];
    }
    __syncthreads();
    const int m = layer * 2 + dir;
    for (int q = tid; q < 4096; q += 256) {
        const int l = q >> 6, e = q & 63;
        const int bl = b * 512 + l0 + l;
        const float dv = Dp[m * 64 + e];
        const float u = xp[(size_t)bl * 64 + e];
        const float res = xz[(size_t)bl * 128 + 64 + e];
        yg[(size_t)bl * 64 + e] = (sy[e][l] + u * dv) * sigf(res);
    }
}

// ------------- out-proj (both dirs as K=128 GEMM) + residual + LN1 -> Y3 -------------
__global__ __launch_bounds__(256) void opln_kernel(
    const float* __restrict__ ygF, const float* __restrict__ ygB,
    const float* __restrict__ Xc, const float* __restrict__ out_w, int layer,
    const float* __restrict__ g, const float* __restrict__ bb,
    float* __restrict__ Y3)
{
    __shared__ float sy[16][128];   // [row][ygF|ygB]
    __shared__ float sw[32][128];
    const int tid = threadIdx.x;
    const int r0 = blockIdx.x * 16;
    for (int q = tid; q < 2048; q += 256) {
        const int r = q >> 7, c = q & 127;
        sy[r][c] = (c < 64) ? ygF[(r0 + r) * 64 + c] : ygB[(r0 + r) * 64 + (c - 64)];
    }
    const int wv = tid >> 6, lane = tid & 63;
    const float* WFp = out_w + (layer * 2) * 8192;
    const float* WBp = out_w + (layer * 2 + 1) * 8192;
    float acc[4][2];
#pragma unroll
    for (int r = 0; r < 4; ++r) { acc[r][0] = 0.f; acc[r][1] = 0.f; }
    for (int ko = 0; ko < 128; ko += 32) {
        __syncthreads();
        for (int q = tid; q < 4096; q += 256) {
            const int kk = q >> 7, c = q & 127;
            const int kg = ko + kk;
            sw[kk][c] = (kg < 64) ? WFp[kg * 128 + c] : WBp[(kg - 64) * 128 + c];
        }
        __syncthreads();
#pragma unroll
        for (int kk = 0; kk < 32; ++kk) {
            const float w0 = sw[kk][lane], w1 = sw[kk][lane + 64];
            const int kg = ko + kk;
#pragma unroll
            for (int r = 0; r < 4; ++r) {
                const float yv = sy[wv * 4 + r][kg];
                acc[r][0] = fmaf(yv, w0, acc[r][0]);
                acc[r][1] = fmaf(yv, w1, acc[r][1]);
            }
        }
    }
#pragma unroll
    for (int r = 0; r < 4; ++r) {
        const int row = r0 + wv * 4 + r;
        float v0 = acc[r][0] + Xc[row * 128 + lane];
        float v1 = acc[r][1] + Xc[row * 128 + lane + 64];
        float sum = v0 + v1, sq = v0 * v0 + v1 * v1;
#pragma unroll
        for (int o = 32; o >= 1; o >>= 1) { sum += __shfl_xor(sum, o); sq += __shfl_xor(sq, o); }
        const float mean = sum * (1.f / 128.f);
        const float var = sq * (1.f / 128.f) - mean * mean;
        const float rs = rsqrtf(var + 1e-5f);
        Y3[row * 128 + lane]      = (v0 - mean) * rs * g[lane] + bb[lane];
        Y3[row * 128 + lane + 64] = (v1 - mean) * rs * g[lane + 64] + bb[lane + 64];
    }
}

// ------------- FFN1 + FFN2 + residual + LN2 -> x. grid 1024, block 256 (16 rows) -------------
__global__ __launch_bounds__(256) void ffn_kernel(
    const float* __restrict__ Y3, const float* __restrict__ W1, const float* __restrict__ b1,
    const float* __restrict__ W2, const float* __restrict__ b2,
    const float* __restrict__ g, const float* __restrict__ bb, float* __restrict__ xout)
{
    __shared__ float sx[16][128];
    __shared__ float sw1[128][32];
    __shared__ float sh[16][32];
    __shared__ float sw2[32][128];
    const int tid = threadIdx.x;
    const int r0 = blockIdx.x * 16;
    for (int q = tid; q < 2048; q += 256) sx[q >> 7][q & 127] = Y3[r0 * 128 + q];
    for (int q = tid; q < 4096; q += 256) sw1[q >> 5][q & 31] = W1[q];
    for (int q = tid; q < 4096; q += 256) sw2[q >> 7][q & 127] = W2[q];
    __syncthreads();
    {
        const int r = tid >> 4, u = tid & 15;
        float h0 = b1[u], h1 = b1[u + 16];
#pragma unroll 8
        for (int k = 0; k < 128; ++k) {
            const float xv = sx[r][k];
            h0 = fmaf(xv, sw1[k][u], h0);
            h1 = fmaf(xv, sw1[k][u + 16], h1);
        }
        sh[r][u]      = fmaxf(h0, 0.f);
        sh[r][u + 16] = fmaxf(h1, 0.f);
    }
    __syncthreads();
    const int wv = tid >> 6, lane = tid & 63;
#pragma unroll
    for (int r = 0; r < 4; ++r) {
        const int rl = wv * 4 + r;
        float a0 = b2[lane], a1 = b2[lane + 64];
#pragma unroll 8
        for (int k = 0; k < 32; ++k) {
            const float hv = sh[rl][k];
            a0 = fmaf(hv, sw2[k][lane], a0);
            a1 = fmaf(hv, sw2[k][lane + 64], a1);
        }
        const float v0 = a0 + sx[rl][lane];
        const float v1 = a1 + sx[rl][lane + 64];
        float sum = v0 + v1, sq = v0 * v0 + v1 * v1;
#pragma unroll
        for (int o = 32; o >= 1; o >>= 1) { sum += __shfl_xor(sum, o); sq += __shfl_xor(sq, o); }
        const float mean = sum * (1.f / 128.f);
        const float var = sq * (1.f / 128.f) - mean * mean;
        const float rs = rsqrtf(var + 1e-5f);
        const int row = r0 + rl;
        xout[row * 128 + lane]      = (v0 - mean) * rs * g[lane] + bb[lane];
        xout[row * 128 + lane + 64] = (v1 - mean) * rs * g[lane + 64] + bb[lane + 64];
    }
}

// ================= head =================
__global__ __launch_bounds__(256) void head_prep_kernel(
    const float* __restrict__ psi, const float* __restrict__ W_q, const float* __restrict__ W_k,
    const float* __restrict__ f_b, const float* __restrict__ hmix, const float* __restrict__ attn_a,
    float* __restrict__ mixb, float* __restrict__ alphab, float* __restrict__ bft,
    float* __restrict__ Qb, float* __restrict__ Kb)
{
    const int tid = threadIdx.x;
    const float m0 = hmix[0], m1 = hmix[1], m2 = hmix[2], m3 = hmix[3];
    const float mx = fmaxf(fmaxf(m0, m1), fmaxf(m2, m3));
    const float e0 = __expf(m0 - mx), e1 = __expf(m1 - mx), e2 = __expf(m2 - mx), e3 = __expf(m3 - mx);
    const float inv = 1.f / (e0 + e1 + e2 + e3);
    float mixv[4] = {e0 * inv, e1 * inv, e2 * inv, e3 * inv};
    if (tid < 4) mixb[tid] = mixv[tid];
    if (tid == 4) alphab[0] = sigf(attn_a[0]);
    if (tid < 128) {
        float s = 0.f;
        for (int h = 0; h < 4; ++h) {
            float t = 0.f;
            for (int d = 0; d < 10; ++d) t = fmaf(psi[tid * 10 + d], f_b[h * 10 + d], t);
            s = fmaf(mixv[h], t, s);
        }
        bft[tid] = s;
    }
    for (int idx = tid; idx < 5120; idx += 256) {
        const int n = idx / 40, rem = idx - n * 40, h = rem / 10, d = rem - h * 10;
        float q = 0.f, kk = 0.f;
        for (int d0 = 0; d0 < 10; ++d0) {
            const float pv = psi[n * 10 + d0];
            q = fmaf(pv, W_q[(d0 * 4 + h) * 10 + d], q);
            kk = fmaf(pv, W_k[(d0 * 4 + h) * 10 + d], kk);
        }
        Qb[idx] = q; Kb[idx] = kk;
    }
}

__global__ __launch_bounds__(256) void head_qk_kernel(
    const float* __restrict__ psi, const float* __restrict__ psis,
    const float* __restrict__ Qb, const float* __restrict__ Kb,
    float* __restrict__ gbuf, float* __restrict__ qkbuf)
{
    const int idx = blockIdx.x * 256 + threadIdx.x;  // 16384
    const int n = idx >> 7, mcol = idx & 127;
    float d2 = 0.f;
#pragma unroll
    for (int d = 0; d < 10; ++d) { const float df = psi[n * 10 + d] - psi[mcol * 10 + d]; d2 = fmaf(df, df, d2); }
    gbuf[idx] = __expf(-psis[0] * d2);
#pragma unroll
    for (int h = 0; h < 4; ++h) {
        float qq = 0.f;
#pragma unroll
        for (int d = 0; d < 10; ++d) qq = fmaf(Qb[n * 40 + h * 10 + d], Kb[mcol * 40 + h * 10 + d], qq);
        qkbuf[h * 16384 + idx] = qq * 0.3162277660168379332f;  // 1/sqrt(10)
    }
}

__global__ __launch_bounds__(128) void head_aeff_kernel(
    const float* __restrict__ gbuf, const float* __restrict__ qkbuf, const float* __restrict__ alphab,
    float* __restrict__ Aeff, float* __restrict__ StT)
{
    __shared__ float red[128];
    const int h = blockIdx.x >> 7, n = blockIdx.x & 127, mcol = threadIdx.x;
    const float gv = gbuf[n * 128 + mcol];
    const float qv = qkbuf[h * 16384 + n * 128 + mcol];
    float r;
    red[mcol] = gv; __syncthreads();
    for (int s = 64; s >= 1; s >>= 1) { if (mcol < s) red[mcol] = fmaxf(red[mcol], red[mcol + s]); __syncthreads(); }
    r = red[0]; __syncthreads();
    const float eg = __expf(gv - r);
    red[mcol] = eg; __syncthreads();
    for (int s = 64; s >= 1; s >>= 1) { if (mcol < s) red[mcol] += red[mcol + s]; __syncthreads(); }
    const float gsum = red[0]; __syncthreads();
    red[mcol] = qv; __syncthreads();
    for (int s = 64; s >= 1; s >>= 1) { if (mcol < s) red[mcol] = fmaxf(red[mcol], red[mcol + s]); __syncthreads(); }
    r = red[0]; __syncthreads();
    const float eq = __expf(qv - r);
    red[mcol] = eq; __syncthreads();
    for (int s = 64; s >= 1; s >>= 1) { if (mcol < s) red[mcol] += red[mcol + s]; __syncthreads(); }
    const float qsum = red[0];
    const float al = alphab[0];
    const float aeff = al * (eg / gsum) + (1.f - al) * (eq / qsum);
    Aeff[h * 16384 + n * 128 + mcol] = aeff;
    StT[((h * 4 + 1) * 128 + mcol) * 128 + n] = aeff;
    StT[((h * 4 + 0) * 128 + mcol) * 128 + n] = (mcol == n) ? 1.f : 0.f;
}

__global__ __launch_bounds__(256) void head_cheb_kernel(
    const float* __restrict__ Aeff, float* __restrict__ StT, int kk)
{
    const int h = blockIdx.x >> 6;
    const int m0 = ((blockIdx.x & 63) << 1) + (threadIdx.x >> 7);
    const int n = threadIdx.x & 127;
    const float* Ar = Aeff + h * 16384 + n * 128;
    const float* Sp = StT + ((h * 4 + kk - 1) * 128 + m0) * 128;
    float acc = 0.f;
#pragma unroll 8
    for (int p = 0; p < 128; ++p) acc = fmaf(Ar[p], Sp[p], acc);
    const float s2 = StT[((h * 4 + kk - 2) * 128 + m0) * 128 + n];
    StT[((h * 4 + kk) * 128 + m0) * 128 + n] = 2.f * acc - s2;
}

__global__ __launch_bounds__(256) void head_wf_kernel(
    const float* __restrict__ psi, const float* __restrict__ F_w, float* __restrict__ WfT)
{
    const int idx = blockIdx.x * 256 + threadIdx.x;  // 2^20
    const int n = idx & 127, l = (idx >> 7) & 511, k = (idx >> 16) & 3, h = idx >> 18;
    float acc = 0.f;
#pragma unroll
    for (int d = 0; d < 10; ++d)
        acc = fmaf(psi[n * 10 + d], F_w[((h * 10 + d) * 4 + k) * 512 + l], acc);
    WfT[idx] = acc;
}

// head_v3: thread owns (m, n) and 8 l's; 16 StT loads amortized. grid 4096, block 256.
__global__ __launch_bounds__(256) void head_v3_kernel(
    const float* __restrict__ StT, const float* __restrict__ WfT, const float* __restrict__ mixb,
    float* __restrict__ V)
{
    const int tid = threadIdx.x;
    const int lt = blockIdx.x & 63, mm = blockIdx.x >> 6;
    const int n = tid & 127, mh = tid >> 7;
    const int m = mm * 2 + mh;
    const int l0 = lt * 8;
    float sv[16];
#pragma unroll
    for (int h = 0; h < 4; ++h) {
        const float mx = mixb[h];
#pragma unroll
        for (int k = 0; k < 4; ++k)
            sv[h * 4 + k] = mx * StT[(size_t)((h * 4 + k) * 128 + m) * 128 + n];
    }
#pragma unroll
    for (int j = 0; j < 8; ++j) {
        const int l = l0 + j;
        float acc = 0.f;
#pragma unroll
        for (int hk = 0; hk < 16; ++hk)
            acc = fmaf(sv[hk], WfT[(size_t)(hk * 512 + l) * 128 + n], acc);
        V[(size_t)(l * 128 + m) * 128 + n] = acc;
    }
}

// head_ctr v2: grid 512 (l), block 256: n = tid&127, m-half = tid>>7. 2 blocks/CU.
__global__ __launch_bounds__(256) void head_ctr_kernel(
    const float* __restrict__ Xf, const float* __restrict__ V, float* __restrict__ partial)
{
    __shared__ float sx[32][128];
    const int l = blockIdx.x, tid = threadIdx.x;
    const int n = tid & 127, mh = tid >> 7;
    for (int q = tid; q < 4096; q += 256) {
        const int b = q >> 7, mm = q & 127;
        sx[b][mm] = Xf[(b * 512 + l) * 128 + mm];
    }
    __syncthreads();
    float acc[32];
#pragma unroll
    for (int b = 0; b < 32; ++b) acc[b] = 0.f;
    const float* vp = V + (size_t)(l * 128 + mh * 64) * 128 + n;
    for (int mm = 0; mm < 64; ++mm) {
        const float v = vp[(size_t)mm * 128];
        const int m = mh * 64 + mm;
#pragma unroll
        for (int b = 0; b < 32; ++b) acc[b] = fmaf(sx[b][m], v, acc[b]);
    }
#pragma unroll
    for (int b = 0; b < 32; ++b)
        partial[(size_t)((l * 2 + mh) * 32 + b) * 128 + n] = acc[b];
}

__global__ __launch_bounds__(128) void head_out_kernel(
    const float* __restrict__ partial, const float* __restrict__ bft,
    const float* __restrict__ head_w, const float* __restrict__ head_b, float* __restrict__ out)
{
    __shared__ float red[128];
    const int b = blockIdx.x, n = threadIdx.x;
    float s = bft[n];
    for (int c = 0; c < 1024; ++c) s += partial[(size_t)(c * 32 + b) * 128 + n];
    red[n] = s * head_w[n];
    __syncthreads();
    for (int st = 64; st >= 1; st >>= 1) { if (n < st) red[n] += red[n + st]; __syncthreads(); }
    if (n == 0) out[b] = red[0] + head_b[0];
    out[32 + b * 128 + n] = 0.f;   // log_var = zeros
}

extern "C" void kernel_launch(void* const* d_in, const int* in_sizes, int n_in,
                              void* d_out, int out_size, void* d_ws, size_t ws_size,
                              hipStream_t stream) {
    const float* x_in    = (const float*)d_in[0];
    const float* in_w    = (const float*)d_in[1];
    const float* conv_w  = (const float*)d_in[2];
    const float* conv_b  = (const float*)d_in[3];
    const float* xproj_w = (const float*)d_in[4];
    const float* dt_w    = (const float*)d_in[5];
    const float* dt_b    = (const float*)d_in[6];
    const float* Alog    = (const float*)d_in[7];
    const float* Dp      = (const float*)d_in[8];
    const float* out_w   = (const float*)d_in[9];
    const float* ln1_g   = (const float*)d_in[10];
    const float* ln1_b   = (const float*)d_in[11];
    const float* ln2_g   = (const float*)d_in[12];
    const float* ln2_b   = (const float*)d_in[13];
    const float* ffn_w1  = (const float*)d_in[14];
    const float* ffn_b1  = (const float*)d_in[15];
    const float* ffn_w2  = (const float*)d_in[16];
    const float* ffn_b2  = (const float*)d_in[17];
    const float* psi_emb = (const float*)d_in[18];
    const float* psi_s   = (const float*)d_in[19];
    const float* W_q     = (const float*)d_in[20];
    const float* W_k     = (const float*)d_in[21];
    const float* attn_a  = (const float*)d_in[22];
    const float* F_w     = (const float*)d_in[23];
    const float* f_b     = (const float*)d_in[24];
    const float* hmix    = (const float*)d_in[25];
    const float* head_w  = (const float*)d_in[26];
    const float* head_b  = (const float*)d_in[27];
    float* ws = (float*)d_ws;
    float* outp = (float*)d_out;

    for (int i = 0; i < 3; ++i) {
        const float* xcur = (i == 0) ? x_in : (ws + OFF_X);
        const int mF = 2 * i, mB = 2 * i + 1;
        gemm_in2_kernel<<<512, 256, 0, stream>>>(
            xcur, in_w + mF * 16384, in_w + mB * 16384, ws + OFF_XZF, ws + OFF_XZB);
        prep3_kernel<<<2048, 256, 0, stream>>>(
            ws + OFF_XZF, ws + OFF_XZB, conv_w, conv_b, xproj_w, dt_w, dt_b, i,
            ws + OFF_XPF, ws + OFF_XPB, ws + OFF_XBCF, ws + OFF_XBCB, ws + OFF_PKF, ws + OFF_PKB);
        scan4_kernel<<<1024, 256, 0, stream>>>(
            ws + OFF_XBCF, ws + OFF_XBCB, ws + OFF_PKF, ws + OFF_PKB,
            Alog + mF * 4096, Alog + mB * 4096, ws + OFF_YSF, ws + OFF_YSB);
        gate3_kernel<<<512, 256, 0, stream>>>(
            ws + OFF_YSF, ws + OFF_YSB, ws + OFF_XPF, ws + OFF_XPB, ws + OFF_XZF, ws + OFF_XZB,
            Dp, i, ws + OFF_YGF, ws + OFF_YGB);
        opln_kernel<<<1024, 256, 0, stream>>>(
            ws + OFF_YGF, ws + OFF_YGB, xcur, out_w, i,
            ln1_g + i * 128, ln1_b + i * 128, ws + OFF_Y3);
        ffn_kernel<<<1024, 256, 0, stream>>>(
            ws + OFF_Y3, ffn_w1 + i * 4096, ffn_b1 + i * 32,
            ffn_w2 + i * 4096, ffn_b2 + i * 128,
            ln2_g + i * 128, ln2_b + i * 128, ws + OFF_X);
    }
    // head
    head_prep_kernel<<<1, 256, 0, stream>>>(
        psi_emb, W_q, W_k, f_b, hmix, attn_a,
        ws + OFF_MIX, ws + OFF_ALPH, ws + OFF_BFT, ws + OFF_QB, ws + OFF_KB);
    head_qk_kernel<<<64, 256, 0, stream>>>(
        psi_emb, psi_s, ws + OFF_QB, ws + OFF_KB, ws + OFF_GB, ws + OFF_QKB);
    head_aeff_kernel<<<512, 128, 0, stream>>>(
        ws + OFF_GB, ws + OFF_QKB, ws + OFF_ALPH, ws + OFF_AEFF, ws + OFF_STT);
    head_cheb_kernel<<<256, 256, 0, stream>>>(ws + OFF_AEFF, ws + OFF_STT, 2);
    head_cheb_kernel<<<256, 256, 0, stream>>>(ws + OFF_AEFF, ws + OFF_STT, 3);
    head_wf_kernel<<<4096, 256, 0, stream>>>(psi_emb, F_w, ws + OFF_WFT);
    head_v3_kernel<<<4096, 256, 0, stream>>>(ws + OFF_STT, ws + OFF_WFT, ws + OFF_MIX, ws + OFF_V);
    head_ctr_kernel<<<512, 256, 0, stream>>>(ws + OFF_X, ws + OFF_V, ws + OFF_PART);
    head_out_kernel<<<32, 128, 0, stream>>>(
        ws + OFF_PART, ws + OFF_BFT, head_w, head_b, outp);
}

// Round 5
// 632.946 us; speedup vs baseline: 1.5341x; 1.0869x over previous
//
#include <hip/hip_runtime.h>
#include <hip/hip_bf16.h>

// MAMBA_BayesMAGAC: B=32, L=512, D=128, E=64, HS=64, DTR=4, U=32, R=3, K=3, DE=10, NH=4
// Round 5: scan5 (XCD-local block map, deinterleaved B/C, balanced staging, 1 barrier/tile),
// opfn (gate+outproj+LN1+FFN+LN2 fused, Y3 in LDS), head qk+aeff fused. 20 dispatches.

#define B_ 32
#define L_ 512
#define D_ 128
#define E_ 64
#define HS_ 64

// ---- workspace offsets (floats) ----
#define OFF_X     0u          // 2,097,152  x [b][l][128]
#define OFF_XZF   2097152u    // 2,097,152  xz fwd [b][l][128]
#define OFF_XZB   4194304u
#define OFF_XPF   6291456u    // 1,048,576  xp [b][l][64]
#define OFF_XPB   7340032u
#define OFF_PKF   8388608u    // 2,097,152  (dl,du) [b][l][64][2]
#define OFF_PKB   10485760u
#define OFF_XBCF  12582912u   // 2,097,152  (B|C) [b][l][128] (B cols 0-63, C cols 64-127)
#define OFF_XBCB  14680064u
#define OFF_YSF   16777216u   // 1,048,576  scan y [b][e][l]
#define OFF_YSB   17825792u   // end 18,874,368 floats = 75.5 MB
// head phase (only OFF_X live):
#define OFF_V     2097152u    // 8,388,608  V [l][m][n]
#define OFF_WFT   10485760u   // 1,048,576  Wf [h][k][l][n]
#define OFF_STT   11534336u   // 262,144    S^T [h][k][m][n]
#define OFF_AEFF  11796480u   // 65,536
#define OFF_QB    11943936u   // 5,120
#define OFF_KB    11949056u   // 5,120
#define OFF_MIX   11954176u   // 4
#define OFF_ALPH  11954180u   // 1
#define OFF_BFT   11954184u   // 128
#define OFF_PART  12582912u   // 4,194,304  partial [512][2][32][128]

__device__ __forceinline__ float sigf(float x) { return 1.f / (1.f + __expf(-x)); }

// ---------------- in-projection: xz = x @ in_w (both dirs), 32 rows/block ----------------
__global__ __launch_bounds__(256) void gemm_in2_kernel(
    const float* __restrict__ X, const float* __restrict__ WF, const float* __restrict__ WB,
    float* __restrict__ xzF, float* __restrict__ xzB)
{
    __shared__ float sxT[128][36];    // transposed x tile, padded
    __shared__ float sw[2][16][128];
    const int tid = threadIdx.x;
    const int r0 = blockIdx.x * 32;
    for (int q = tid; q < 32 * 128; q += 256) {
        const int r = q >> 7, k = q & 127;
        sxT[k][r] = X[(r0 + r) * 128 + k];
    }
    const int wv = tid >> 6, lane = tid & 63;
    const int d = wv >> 1, ch = wv & 1;
    const int r4 = lane >> 4, c16 = lane & 15;
    float4 acc[8];
#pragma unroll
    for (int j = 0; j < 8; ++j) acc[j] = float4{0.f, 0.f, 0.f, 0.f};
    for (int ko = 0; ko < 128; ko += 16) {
        __syncthreads();
        for (int q = tid; q < 2 * 16 * 128; q += 256) {
            const int dd = q >> 11, kk = (q >> 7) & 15, c = q & 127;
            sw[dd][kk][c] = (dd ? WB : WF)[(ko + kk) * 128 + c];
        }
        __syncthreads();
#pragma unroll
        for (int kk = 0; kk < 16; ++kk) {
            const float4 w4 = *(const float4*)&sw[d][kk][ch * 64 + c16 * 4];
            const float4 xa = *(const float4*)&sxT[ko + kk][r4 * 8];
            const float4 xb = *(const float4*)&sxT[ko + kk][r4 * 8 + 4];
            const float xs[8] = {xa.x, xa.y, xa.z, xa.w, xb.x, xb.y, xb.z, xb.w};
#pragma unroll
            for (int j = 0; j < 8; ++j) {
                acc[j].x = fmaf(xs[j], w4.x, acc[j].x);
                acc[j].y = fmaf(xs[j], w4.y, acc[j].y);
                acc[j].z = fmaf(xs[j], w4.z, acc[j].z);
                acc[j].w = fmaf(xs[j], w4.w, acc[j].w);
            }
        }
    }
    float* xz = d ? xzB : xzF;
#pragma unroll
    for (int j = 0; j < 8; ++j) {
        *(float4*)&xz[(r0 + r4 * 8 + j) * 128 + ch * 64 + c16 * 4] = acc[j];
    }
}

// ------------- conv + silu + xproj + delta, both dirs. grid 2048 (16 rows/block) -------------
__global__ __launch_bounds__(256) void prep3_kernel(
    const float* __restrict__ xzF_, const float* __restrict__ xzB_,
    const float* __restrict__ conv_w, const float* __restrict__ conv_b,
    const float* __restrict__ xproj_w, const float* __restrict__ dt_w,
    const float* __restrict__ dt_b, int layer,
    float* __restrict__ xpF_, float* __restrict__ xpB_,
    float* __restrict__ xbcF_, float* __restrict__ xbcB_,
    float* __restrict__ pkF_, float* __restrict__ pkB_)
{
    __shared__ float sW[64 * 132];
    __shared__ float sxp[4][64];
    __shared__ float sdl[4][4];
    const int tid = threadIdx.x, wv = tid >> 6, lane = tid & 63;
    const int dir = (int)(blockIdx.x >= 1024);        // block-uniform
    const int r0 = (blockIdx.x & 1023) * 16;          // 16 rows, same b
    const int b = r0 >> 9;
    const int m = layer * 2 + dir;
    const float* Wg = xproj_w + m * 8448;
    for (int q = tid; q < 8448; q += 256) sW[q] = Wg[q];
    const float* xz = dir ? xzB_ : xzF_;
    float* xp  = dir ? xpB_  : xpF_;
    float* xbc = dir ? xbcB_ : xbcF_;
    float* pkx = dir ? pkB_  : pkF_;
    const float* cw = conv_w + m * 192 + lane * 3;
    const float cw0 = cw[0], cw1 = cw[1], cw2 = cw[2];
    const float cb  = conv_b[m * 64 + lane];
    const float dtb = dt_b[m * 64 + lane];
    const float* dwp = dt_w + m * 256;
    const float dw0 = dwp[lane], dw1 = dwp[64 + lane], dw2 = dwp[128 + lane], dw3 = dwp[192 + lane];
    __syncthreads();
    const int jdt = lane & 3;
    for (int it = 0; it < 4; ++it) {
        const int row = r0 + wv * 4 + it;
        const int l = row & 511;
        const int l1 = dir ? l + 1 : l - 1;
        const int l2 = dir ? l + 2 : l - 2;
        float acc = cb;
        const float x0 = xz[(size_t)row * 128 + lane];
        const float x1 = (l1 >= 0 && l1 < 512) ? xz[(size_t)(b * 512 + l1) * 128 + lane] : 0.f;
        const float x2 = (l2 >= 0 && l2 < 512) ? xz[(size_t)(b * 512 + l2) * 128 + lane] : 0.f;
        acc += cw0 * x2 + cw1 * x1 + cw2 * x0;
        const float u = acc * sigf(acc);   // silu
        xp[row * 64 + lane] = u;
        sxp[wv][lane] = u;
        float aB = 0.f, aC = 0.f, adt = 0.f;
#pragma unroll 8
        for (int k = 0; k < 64; ++k) {
            const float xv = sxp[wv][k];
            aB  = fmaf(xv, sW[k * 132 + 4 + lane], aB);
            aC  = fmaf(xv, sW[k * 132 + 68 + lane], aC);
            adt = fmaf(xv, sW[k * 132 + jdt], adt);
        }
        // deinterleaved: B cols 0-63, C cols 64-127
        xbc[row * 128 + lane]      = aB;
        xbc[row * 128 + 64 + lane] = aC;
        if (lane < 4) sdl[wv][lane] = adt;
        float dpre = fmaf(sdl[wv][0], dw0, dtb);
        dpre = fmaf(sdl[wv][1], dw1, dpre);
        dpre = fmaf(sdl[wv][2], dw2, dpre);
        dpre = fmaf(sdl[wv][3], dw3, dpre);
        const float dlt = (dpre > 20.f) ? dpre : log1pf(__expf(dpre));
        ((float2*)pkx)[row * 64 + lane] = float2{dlt, dlt * u};
    }
}

// ------------- selective scan v5. grid 1024, block 256 -------------
// Block id: low 6 bits = (dir,b) so all 16 e-quad blocks of one (dir,b) share an XCD.
// wave wv owns e = e0+wv, lane = n. Deinterleaved B/C, balanced staging, 1 barrier/tile.
__global__ __launch_bounds__(256, 4) void scan5_kernel(
    const float* __restrict__ xbcF, const float* __restrict__ xbcB,
    const float* __restrict__ pkF, const float* __restrict__ pkB,
    const float* __restrict__ AlogF, const float* __restrict__ AlogB,
    float* __restrict__ ysF, float* __restrict__ ysB)
{
    __shared__ float sbc[2][2048];        // 16 KB: exact copy of 16 rows x 128 floats
    __shared__ float spk[2][4][16][2];    // 1 KB
    __shared__ float ytile[4][16][68];    // 17.4 KB
    const int tid = threadIdx.x, wv = tid >> 6, lane = tid & 63;
    const int bx = blockIdx.x;
    const int db = bx & 63;               // (dir,b) in low bits -> same XCD for all e-quads
    const int dir = db >> 5;
    const int b   = db & 31;
    const int e0  = (bx >> 6) * 4;
    const int e   = e0 + wv;
    const float* xbc = dir ? xbcB : xbcF;
    const float* pk  = dir ? pkB  : pkF;
    const float* Aw  = dir ? AlogB : AlogF;
    float* ys = dir ? ysB : ysF;
    const float a2 = -__expf(Aw[e * 64 + lane]) * 1.4426950408889634f;
    float s = 0.f;
    float* yrow = ys + (size_t)(b * 64 + e) * 512;

    const int psl = tid & 15, pw_ = tid >> 4;   // tid<64: pk staging coords

#define STG_LOAD(RS)                                                              \
    {                                                                             \
        nba = *(const float4*)(xbc + (size_t)(RS) * 128 + tid * 4);               \
        nbb = *(const float4*)(xbc + (size_t)(RS) * 128 + 1024 + tid * 4);        \
        if (tid < 64)                                                             \
            npp = *(const float2*)(pk + (size_t)((RS) + psl) * 128 + (e0 + pw_) * 2); \
    }
#define STG_WRITE(BUF)                                                            \
    {                                                                             \
        *(float4*)(&sbc[BUF][tid * 4])        = nba;                              \
        *(float4*)(&sbc[BUF][1024 + tid * 4]) = nbb;                              \
        if (tid < 64) *(float2*)(&spk[BUF][pw_][psl][0]) = npp;                   \
    }

#define SCAN16(REV)                                                               \
    {                                                                             \
        const float* bc = &sbc[cur][0];                                           \
        const float* pq = &spk[cur][wv][0][0];                                    \
        _Pragma("unroll")                                                         \
        for (int j = 0; j < 8; ++j) {                                             \
            const int pj = (REV) ? 7 - j : j;                                     \
            const float4 pk4 = *(const float4*)(pq + pj * 4);                     \
            const int sA = (REV) ? 15 - 2 * j : 2 * j;                            \
            const int sB = (REV) ? 14 - 2 * j : 2 * j + 1;                        \
            const float dlA = (REV) ? pk4.z : pk4.x;                              \
            const float duA = (REV) ? pk4.w : pk4.y;                              \
            const float dlB = (REV) ? pk4.x : pk4.z;                              \
            const float duB = (REV) ? pk4.y : pk4.w;                              \
            const float BnA = bc[sA * 128 + lane];                                \
            const float CnA = bc[sA * 128 + 64 + lane];                           \
            s = fmaf(exp2f(dlA * a2), s, duA * BnA);                              \
            ytile[wv][2 * j][lane] = s * CnA;                                     \
            const float BnB = bc[sB * 128 + lane];                                \
            const float CnB = bc[sB * 128 + 64 + lane];                           \
            s = fmaf(exp2f(dlB * a2), s, duB * BnB);                              \
            ytile[wv][2 * j + 1][lane] = s * CnB;                                 \
        }                                                                         \
    }

    // prologue: stage tile 0
    {
        float4 nba, nbb; float2 npp;
        const int rs0 = b * 512 + (dir ? 496 : 0);
        STG_LOAD(rs0);
        STG_WRITE(0);
    }
    __syncthreads();

    int cur = 0;
    const int rr = lane & 15, sg = lane >> 4;
    for (int t = 0; t < 32; ++t) {
        float4 nba, nbb; float2 npp;
        const bool more = (t + 1) < 32;
        if (more) {
            const int rs = b * 512 + (dir ? (496 - (t + 1) * 16) : ((t + 1) * 16));
            STG_LOAD(rs);
        }
        if (dir == 0) { SCAN16(0) } else { SCAN16(1) }
        // per-wave reduce of own ytile (wave-private, no barrier needed)
        {
            const float* yt = &ytile[wv][rr][sg * 16];
            const float4 A0 = *(const float4*)yt;
            const float4 A1 = *(const float4*)(yt + 4);
            const float4 A2 = *(const float4*)(yt + 8);
            const float4 A3 = *(const float4*)(yt + 12);
            float p = ((A0.x + A0.y) + (A0.z + A0.w)) + ((A1.x + A1.y) + (A1.z + A1.w))
                    + ((A2.x + A2.y) + (A2.z + A2.w)) + ((A3.x + A3.y) + (A3.z + A3.w));
            p += __shfl_xor(p, 16);
            p += __shfl_xor(p, 32);
            if (lane < 16) {
                const int lg = dir ? (511 - (t * 16 + rr)) : (t * 16 + rr);
                yrow[lg] = p;
            }
        }
        if (more) STG_WRITE(cur ^ 1);
        __syncthreads();
        cur ^= 1;
    }
#undef STG_LOAD
#undef STG_WRITE
#undef SCAN16
}

// ------------- opfn: gate + out-proj + LN1 + FFN + LN2 fused. grid 1024 (16 rows), block 256 --
__global__ __launch_bounds__(256) void opfn_kernel(
    const float* __restrict__ ysF, const float* __restrict__ ysB,
    const float* __restrict__ xpF, const float* __restrict__ xpB,
    const float* __restrict__ xzF, const float* __restrict__ xzB,
    const float* __restrict__ Dp, int layer,
    const float* __restrict__ Xc, const float* __restrict__ out_w,
    const float* __restrict__ W1, const float* __restrict__ b1,
    const float* __restrict__ W2, const float* __restrict__ b2,
    const float* __restrict__ g1, const float* __restrict__ bb1,
    const float* __restrict__ g2, const float* __restrict__ bb2,
    float* __restrict__ xout)
{
    __shared__ float smem[8832];
    float* syt = smem;            // [2][64][17] = 2176 (dead after phase1)
    float* y3  = smem;            // [16][128] = 2048 (over syt)
    float* sy  = smem + 2176;     // [16][128] = 2048
    float* sw  = smem + 4224;     // [32][128] = 4096
    float* sh  = smem + 8320;     // [16][32]  = 512
    const int tid = threadIdx.x;
    const int r0 = blockIdx.x * 16;
    const int b = r0 >> 9, l0 = r0 & 511;

    // phase 0: load ys (both dirs) transposed into syt
    for (int q = tid; q < 2048; q += 256) {
        const int d = q >> 10, ee = (q >> 4) & 63, r = q & 15;
        const float* ysp = d ? ysB : ysF;
        syt[(d * 64 + ee) * 17 + r] = ysp[(size_t)(b * 64 + ee) * 512 + l0 + r];
    }
    __syncthreads();
    // phase 1: gate -> sy[r][c] (c<64: fwd e=c; c>=64: bwd e=c-64)
    for (int q = tid; q < 2048; q += 256) {
        const int r = q >> 7, c = q & 127;
        const int d = c >> 6, ee = c & 63;
        const int row = r0 + r;
        const float dv  = Dp[(layer * 2 + d) * 64 + ee];
        const float u   = (d ? xpB : xpF)[(size_t)row * 64 + ee];
        const float res = (d ? xzB : xzF)[(size_t)row * 128 + 64 + ee];
        sy[r * 128 + c] = (syt[(d * 64 + ee) * 17 + r] + u * dv) * sigf(res);
    }
    // phase 2: out-proj GEMM (K=128: fwd 0-63, bwd 64-127) + residual + LN1 -> y3 (LDS)
    const int wv = tid >> 6, lane = tid & 63;
    const float* WFp = out_w + (layer * 2) * 8192;
    const float* WBp = out_w + (layer * 2 + 1) * 8192;
    float acc[4][2];
#pragma unroll
    for (int r = 0; r < 4; ++r) { acc[r][0] = 0.f; acc[r][1] = 0.f; }
    for (int ko = 0; ko < 128; ko += 32) {
        __syncthreads();   // first iter: also covers sy writes
        for (int q = tid; q < 4096; q += 256) {
            const int kk = q >> 7, c = q & 127;
            const int kg = ko + kk;
            sw[kk * 128 + c] = (kg < 64) ? WFp[kg * 128 + c] : WBp[(kg - 64) * 128 + c];
        }
        __syncthreads();
#pragma unroll
        for (int kk = 0; kk < 32; ++kk) {
            const float w0 = sw[kk * 128 + lane], w1 = sw[kk * 128 + lane + 64];
            const int kg = ko + kk;
#pragma unroll
            for (int r = 0; r < 4; ++r) {
                const float yv = sy[(wv * 4 + r) * 128 + kg];
                acc[r][0] = fmaf(yv, w0, acc[r][0]);
                acc[r][1] = fmaf(yv, w1, acc[r][1]);
            }
        }
    }
    __syncthreads();       // sy/syt dead; safe to overwrite y3 region
#pragma unroll
    for (int r = 0; r < 4; ++r) {
        const int rl = wv * 4 + r;
        const int row = r0 + rl;
        float v0 = acc[r][0] + Xc[(size_t)row * 128 + lane];
        float v1 = acc[r][1] + Xc[(size_t)row * 128 + lane + 64];
        float sum = v0 + v1, sq = v0 * v0 + v1 * v1;
#pragma unroll
        for (int o = 32; o >= 1; o >>= 1) { sum += __shfl_xor(sum, o); sq += __shfl_xor(sq, o); }
        const float mean = sum * (1.f / 128.f);
        const float var = sq * (1.f / 128.f) - mean * mean;
        const float rs = rsqrtf(var + 1e-5f);
        y3[rl * 128 + lane]      = (v0 - mean) * rs * g1[lane] + bb1[lane];
        y3[rl * 128 + lane + 64] = (v1 - mean) * rs * g1[lane + 64] + bb1[lane + 64];
    }
    __syncthreads();
    // phase 3: hid = relu(y3 @ W1 + b1) -> sh  (W1 direct, L1-served)
    {
        const int r = tid >> 4, u = tid & 15;
        float h0 = b1[u], h1 = b1[u + 16];
#pragma unroll 8
        for (int k = 0; k < 128; ++k) {
            const float xv = y3[r * 128 + k];
            h0 = fmaf(xv, W1[k * 32 + u], h0);
            h1 = fmaf(xv, W1[k * 32 + u + 16], h1);
        }
        sh[r * 32 + u]      = fmaxf(h0, 0.f);
        sh[r * 32 + u + 16] = fmaxf(h1, 0.f);
    }
    __syncthreads();
    // phase 4: FFN2 + residual(y3) + LN2 -> xout
#pragma unroll
    for (int r = 0; r < 4; ++r) {
        const int rl = wv * 4 + r;
        float a0 = b2[lane], a1 = b2[lane + 64];
#pragma unroll 8
        for (int k = 0; k < 32; ++k) {
            const float hv = sh[rl * 32 + k];
            a0 = fmaf(hv, W2[k * 128 + lane], a0);
            a1 = fmaf(hv, W2[k * 128 + lane + 64], a1);
        }
        const float v0 = a0 + y3[rl * 128 + lane];
        const float v1 = a1 + y3[rl * 128 + lane + 64];
        float sum = v0 + v1, sq = v0 * v0 + v1 * v1;
#pragma unroll
        for (int o = 32; o >= 1; o >>= 1) { sum += __shfl_xor(sum, o); sq += __shfl_xor(sq, o); }
        const float mean = sum * (1.f / 128.f);
        const float var = sq * (1.f / 128.f) - mean * mean;
        const float rs = rsqrtf(var + 1e-5f);
        const int row = r0 + rl;
        xout[(size_t)row * 128 + lane]      = (v0 - mean) * rs * g2[lane] + bb2[lane];
        xout[(size_t)row * 128 + lane + 64] = (v1 - mean) * rs * g2[lane + 64] + bb2[lane + 64];
    }
}

// ================= head =================
__global__ __launch_bounds__(256) void head_prep_kernel(
    const float* __restrict__ psi, const float* __restrict__ W_q, const float* __restrict__ W_k,
    const float* __restrict__ f_b, const float* __restrict__ hmix, const float* __restrict__ attn_a,
    float* __restrict__ mixb, float* __restrict__ alphab, float* __restrict__ bft,
    float* __restrict__ Qb, float* __restrict__ Kb)
{
    const int tid = threadIdx.x;
    const float m0 = hmix[0], m1 = hmix[1], m2 = hmix[2], m3 = hmix[3];
    const float mx = fmaxf(fmaxf(m0, m1), fmaxf(m2, m3));
    const float e0 = __expf(m0 - mx), e1 = __expf(m1 - mx), e2 = __expf(m2 - mx), e3 = __expf(m3 - mx);
    const float inv = 1.f / (e0 + e1 + e2 + e3);
    float mixv[4] = {e0 * inv, e1 * inv, e2 * inv, e3 * inv};
    if (tid < 4) mixb[tid] = mixv[tid];
    if (tid == 4) alphab[0] = sigf(attn_a[0]);
    if (tid < 128) {
        float s = 0.f;
        for (int h = 0; h < 4; ++h) {
            float t = 0.f;
            for (int d = 0; d < 10; ++d) t = fmaf(psi[tid * 10 + d], f_b[h * 10 + d], t);
            s = fmaf(mixv[h], t, s);
        }
        bft[tid] = s;
    }
    for (int idx = tid; idx < 5120; idx += 256) {
        const int n = idx / 40, rem = idx - n * 40, h = rem / 10, d = rem - h * 10;
        float q = 0.f, kk = 0.f;
        for (int d0 = 0; d0 < 10; ++d0) {
            const float pv = psi[n * 10 + d0];
            q = fmaf(pv, W_q[(d0 * 4 + h) * 10 + d], q);
            kk = fmaf(pv, W_k[(d0 * 4 + h) * 10 + d], kk);
        }
        Qb[idx] = q; Kb[idx] = kk;
    }
}

// fused qk + aeff: grid 512 (h,n), block 128 (m)
__global__ __launch_bounds__(128) void head_qkaeff_kernel(
    const float* __restrict__ psi, const float* __restrict__ psis,
    const float* __restrict__ Qb, const float* __restrict__ Kb,
    const float* __restrict__ alphab,
    float* __restrict__ Aeff, float* __restrict__ StT)
{
    __shared__ float spn[10];
    __shared__ float red[128];
    const int h = blockIdx.x >> 7, n = blockIdx.x & 127, mcol = threadIdx.x;
    if (mcol < 10) spn[mcol] = psi[n * 10 + mcol];
    __syncthreads();
    float d2 = 0.f;
#pragma unroll
    for (int d = 0; d < 10; ++d) { const float df = spn[d] - psi[mcol * 10 + d]; d2 = fmaf(df, df, d2); }
    const float gv = __expf(-psis[0] * d2);
    float qv = 0.f;
#pragma unroll
    for (int d = 0; d < 10; ++d) qv = fmaf(Qb[n * 40 + h * 10 + d], Kb[mcol * 40 + h * 10 + d], qv);
    qv *= 0.3162277660168379332f;  // 1/sqrt(10)
    float r;
    red[mcol] = gv; __syncthreads();
    for (int s = 64; s >= 1; s >>= 1) { if (mcol < s) red[mcol] = fmaxf(red[mcol], red[mcol + s]); __syncthreads(); }
    r = red[0]; __syncthreads();
    const float eg = __expf(gv - r);
    red[mcol] = eg; __syncthreads();
    for (int s = 64; s >= 1; s >>= 1) { if (mcol < s) red[mcol] += red[mcol + s]; __syncthreads(); }
    const float gsum = red[0]; __syncthreads();
    red[mcol] = qv; __syncthreads();
    for (int s = 64; s >= 1; s >>= 1) { if (mcol < s) red[mcol] = fmaxf(red[mcol], red[mcol + s]); __syncthreads(); }
    r = red[0]; __syncthreads();
    const float eq = __expf(qv - r);
    red[mcol] = eq; __syncthreads();
    for (int s = 64; s >= 1; s >>= 1) { if (mcol < s) red[mcol] += red[mcol + s]; __syncthreads(); }
    const float qsum = red[0];
    const float al = alphab[0];
    const float aeff = al * (eg / gsum) + (1.f - al) * (eq / qsum);
    Aeff[h * 16384 + n * 128 + mcol] = aeff;
    StT[((h * 4 + 1) * 128 + mcol) * 128 + n] = aeff;
    StT[((h * 4 + 0) * 128 + mcol) * 128 + n] = (mcol == n) ? 1.f : 0.f;
}

__global__ __launch_bounds__(256) void head_cheb_kernel(
    const float* __restrict__ Aeff, float* __restrict__ StT, int kk)
{
    const int h = blockIdx.x >> 6;
    const int m0 = ((blockIdx.x & 63) << 1) + (threadIdx.x >> 7);
    const int n = threadIdx.x & 127;
    const float* Ar = Aeff + h * 16384 + n * 128;
    const float* Sp = StT + ((h * 4 + kk - 1) * 128 + m0) * 128;
    float acc = 0.f;
#pragma unroll 8
    for (int p = 0; p < 128; ++p) acc = fmaf(Ar[p], Sp[p], acc);
    const float s2 = StT[((h * 4 + kk - 2) * 128 + m0) * 128 + n];
    StT[((h * 4 + kk) * 128 + m0) * 128 + n] = 2.f * acc - s2;
}

__global__ __launch_bounds__(256) void head_wf_kernel(
    const float* __restrict__ psi, const float* __restrict__ F_w, float* __restrict__ WfT)
{
    const int idx = blockIdx.x * 256 + threadIdx.x;  // 2^20
    const int n = idx & 127, l = (idx >> 7) & 511, k = (idx >> 16) & 3, h = idx >> 18;
    float acc = 0.f;
#pragma unroll
    for (int d = 0; d < 10; ++d)
        acc = fmaf(psi[n * 10 + d], F_w[((h * 10 + d) * 4 + k) * 512 + l], acc);
    WfT[idx] = acc;
}

__global__ __launch_bounds__(256) void head_v3_kernel(
    const float* __restrict__ StT, const float* __restrict__ WfT, const float* __restrict__ mixb,
    float* __restrict__ V)
{
    const int tid = threadIdx.x;
    const int lt = blockIdx.x & 63, mm = blockIdx.x >> 6;
    const int n = tid & 127, mh = tid >> 7;
    const int m = mm * 2 + mh;
    const int l0 = lt * 8;
    float sv[16];
#pragma unroll
    for (int h = 0; h < 4; ++h) {
        const float mx = mixb[h];
#pragma unroll
        for (int k = 0; k < 4; ++k)
            sv[h * 4 + k] = mx * StT[(size_t)((h * 4 + k) * 128 + m) * 128 + n];
    }
#pragma unroll
    for (int j = 0; j < 8; ++j) {
        const int l = l0 + j;
        float acc = 0.f;
#pragma unroll
        for (int hk = 0; hk < 16; ++hk)
            acc = fmaf(sv[hk], WfT[(size_t)(hk * 512 + l) * 128 + n], acc);
        V[(size_t)(l * 128 + m) * 128 + n] = acc;
    }
}

__global__ __launch_bounds__(256) void head_ctr_kernel(
    const float* __restrict__ Xf, const float* __restrict__ V, float* __restrict__ partial)
{
    __shared__ float sx[32][128];
    const int l = blockIdx.x, tid = threadIdx.x;
    const int n = tid & 127, mh = tid >> 7;
    for (int q = tid; q < 4096; q += 256) {
        const int b = q >> 7, mm = q & 127;
        sx[b][mm] = Xf[(b * 512 + l) * 128 + mm];
    }
    __syncthreads();
    float acc[32];
#pragma unroll
    for (int b = 0; b < 32; ++b) acc[b] = 0.f;
    const float* vp = V + (size_t)(l * 128 + mh * 64) * 128 + n;
    for (int mm = 0; mm < 64; ++mm) {
        const float v = vp[(size_t)mm * 128];
        const int m = mh * 64 + mm;
#pragma unroll
        for (int b = 0; b < 32; ++b) acc[b] = fmaf(sx[b][m], v, acc[b]);
    }
#pragma unroll
    for (int b = 0; b < 32; ++b)
        partial[(size_t)((l * 2 + mh) * 32 + b) * 128 + n] = acc[b];
}

__global__ __launch_bounds__(128) void head_out_kernel(
    const float* __restrict__ partial, const float* __restrict__ bft,
    const float* __restrict__ head_w, const float* __restrict__ head_b, float* __restrict__ out)
{
    __shared__ float red[128];
    const int b = blockIdx.x, n = threadIdx.x;
    float s = bft[n];
    for (int c = 0; c < 1024; ++c) s += partial[(size_t)(c * 32 + b) * 128 + n];
    red[n] = s * head_w[n];
    __syncthreads();
    for (int st = 64; st >= 1; st >>= 1) { if (n < st) red[n] += red[n + st]; __syncthreads(); }
    if (n == 0) out[b] = red[0] + head_b[0];
    out[32 + b * 128 + n] = 0.f;   // log_var = zeros
}

extern "C" void kernel_launch(void* const* d_in, const int* in_sizes, int n_in,
                              void* d_out, int out_size, void* d_ws, size_t ws_size,
                              hipStream_t stream) {
    const float* x_in    = (const float*)d_in[0];
    const float* in_w    = (const float*)d_in[1];
    const float* conv_w  = (const float*)d_in[2];
    const float* conv_b  = (const float*)d_in[3];
    const float* xproj_w = (const float*)d_in[4];
    const float* dt_w    = (const float*)d_in[5];
    const float* dt_b    = (const float*)d_in[6];
    const float* Alog    = (const float*)d_in[7];
    const float* Dp      = (const float*)d_in[8];
    const float* out_w   = (const float*)d_in[9];
    const float* ln1_g   = (const float*)d_in[10];
    const float* ln1_b   = (const float*)d_in[11];
    const float* ln2_g   = (const float*)d_in[12];
    const float* ln2_b   = (const float*)d_in[13];
    const float* ffn_w1  = (const float*)d_in[14];
    const float* ffn_b1  = (const float*)d_in[15];
    const float* ffn_w2  = (const float*)d_in[16];
    const float* ffn_b2  = (const float*)d_in[17];
    const float* psi_emb = (const float*)d_in[18];
    const float* psi_s   = (const float*)d_in[19];
    const float* W_q     = (const float*)d_in[20];
    const float* W_k     = (const float*)d_in[21];
    const float* attn_a  = (const float*)d_in[22];
    const float* F_w     = (const float*)d_in[23];
    const float* f_b     = (const float*)d_in[24];
    const float* hmix    = (const float*)d_in[25];
    const float* head_w  = (const float*)d_in[26];
    const float* head_b  = (const float*)d_in[27];
    float* ws = (float*)d_ws;
    float* outp = (float*)d_out;

    for (int i = 0; i < 3; ++i) {
        const float* xcur = (i == 0) ? x_in : (ws + OFF_X);
        const int mF = 2 * i, mB = 2 * i + 1;
        gemm_in2_kernel<<<512, 256, 0, stream>>>(
            xcur, in_w + mF * 16384, in_w + mB * 16384, ws + OFF_XZF, ws + OFF_XZB);
        prep3_kernel<<<2048, 256, 0, stream>>>(
            ws + OFF_XZF, ws + OFF_XZB, conv_w, conv_b, xproj_w, dt_w, dt_b, i,
            ws + OFF_XPF, ws + OFF_XPB, ws + OFF_XBCF, ws + OFF_XBCB, ws + OFF_PKF, ws + OFF_PKB);
        scan5_kernel<<<1024, 256, 0, stream>>>(
            ws + OFF_XBCF, ws + OFF_XBCB, ws + OFF_PKF, ws + OFF_PKB,
            Alog + mF * 4096, Alog + mB * 4096, ws + OFF_YSF, ws + OFF_YSB);
        opfn_kernel<<<1024, 256, 0, stream>>>(
            ws + OFF_YSF, ws + OFF_YSB, ws + OFF_XPF, ws + OFF_XPB, ws + OFF_XZF, ws + OFF_XZB,
            Dp, i, xcur, out_w,
            ffn_w1 + i * 4096, ffn_b1 + i * 32, ffn_w2 + i * 4096, ffn_b2 + i * 128,
            ln1_g + i * 128, ln1_b + i * 128, ln2_g + i * 128, ln2_b + i * 128,
            ws + OFF_X);
    }
    // head
    head_prep_kernel<<<1, 256, 0, stream>>>(
        psi_emb, W_q, W_k, f_b, hmix, attn_a,
        ws + OFF_MIX, ws + OFF_ALPH, ws + OFF_BFT, ws + OFF_QB, ws + OFF_KB);
    head_qkaeff_kernel<<<512, 128, 0, stream>>>(
        psi_emb, psi_s, ws + OFF_QB, ws + OFF_KB, ws + OFF_ALPH, ws + OFF_AEFF, ws + OFF_STT);
    head_cheb_kernel<<<256, 256, 0, stream>>>(ws + OFF_AEFF, ws + OFF_STT, 2);
    head_cheb_kernel<<<256, 256, 0, stream>>>(ws + OFF_AEFF, ws + OFF_STT, 3);
    head_wf_kernel<<<4096, 256, 0, stream>>>(psi_emb, F_w, ws + OFF_WFT);
    head_v3_kernel<<<4096, 256, 0, stream>>>(ws + OFF_STT, ws + OFF_WFT, ws + OFF_MIX, ws + OFF_V);
    head_ctr_kernel<<<512, 256, 0, stream>>>(ws + OFF_X, ws + OFF_V, ws + OFF_PART);
    head_out_kernel<<<32, 128, 0, stream>>>(
        ws + OFF_PART, ws + OFF_BFT, head_w, head_b, outp);
}

// Round 6
// 602.650 us; speedup vs baseline: 1.6112x; 1.0503x over previous
//
#include <hip/hip_runtime.h>
#include <hip/hip_bf16.h>

// MAMBA_BayesMAGAC: B=32, L=512, D=128, E=64, HS=64, DTR=4, U=32, R=3, K=3, DE=10, NH=4
// Round 6: scan6 (__expf native exp, 2 instr), head_out 2-stage reduce, opfn float4 y-reads.

#define B_ 32
#define L_ 512
#define D_ 128
#define E_ 64
#define HS_ 64

// ---- workspace offsets (floats) ----
#define OFF_X     0u          // 2,097,152  x [b][l][128]
#define OFF_XZF   2097152u    // 2,097,152  xz fwd [b][l][128]
#define OFF_XZB   4194304u
#define OFF_XPF   6291456u    // 1,048,576  xp [b][l][64]
#define OFF_XPB   7340032u
#define OFF_PKF   8388608u    // 2,097,152  (dl,du) [b][l][64][2]
#define OFF_PKB   10485760u
#define OFF_XBCF  12582912u   // 2,097,152  (B|C) [b][l][128] (B cols 0-63, C cols 64-127)
#define OFF_XBCB  14680064u
#define OFF_YSF   16777216u   // 1,048,576  scan y [b][e][l]
#define OFF_YSB   17825792u   // end 18,874,368 floats = 75.5 MB
// head phase (only OFF_X live):
#define OFF_V     2097152u    // 8,388,608  V [l][m][n]
#define OFF_WFT   10485760u   // 1,048,576  Wf [h][k][l][n]
#define OFF_STT   11534336u   // 262,144    S^T [h][k][m][n]
#define OFF_AEFF  11796480u   // 65,536
#define OFF_QB    11943936u   // 5,120
#define OFF_KB    11949056u   // 5,120
#define OFF_MIX   11954176u   // 4
#define OFF_ALPH  11954180u   // 1
#define OFF_BFT   11954184u   // 128
#define OFF_PART  12582912u   // 4,194,304  partial [1024][32][128]
#define OFF_RED1  16777216u   // 131,072    red1 [32][32][128] (over YSF, dead in head)

__device__ __forceinline__ float sigf(float x) { return 1.f / (1.f + __expf(-x)); }

// ---------------- in-projection: xz = x @ in_w (both dirs), 32 rows/block ----------------
__global__ __launch_bounds__(256) void gemm_in2_kernel(
    const float* __restrict__ X, const float* __restrict__ WF, const float* __restrict__ WB,
    float* __restrict__ xzF, float* __restrict__ xzB)
{
    __shared__ float sxT[128][36];    // transposed x tile, padded
    __shared__ float sw[2][16][128];
    const int tid = threadIdx.x;
    const int r0 = blockIdx.x * 32;
    for (int q = tid; q < 32 * 128; q += 256) {
        const int r = q >> 7, k = q & 127;
        sxT[k][r] = X[(r0 + r) * 128 + k];
    }
    const int wv = tid >> 6, lane = tid & 63;
    const int d = wv >> 1, ch = wv & 1;
    const int r4 = lane >> 4, c16 = lane & 15;
    float4 acc[8];
#pragma unroll
    for (int j = 0; j < 8; ++j) acc[j] = float4{0.f, 0.f, 0.f, 0.f};
    for (int ko = 0; ko < 128; ko += 16) {
        __syncthreads();
        for (int q = tid; q < 2 * 16 * 128; q += 256) {
            const int dd = q >> 11, kk = (q >> 7) & 15, c = q & 127;
            sw[dd][kk][c] = (dd ? WB : WF)[(ko + kk) * 128 + c];
        }
        __syncthreads();
#pragma unroll
        for (int kk = 0; kk < 16; ++kk) {
            const float4 w4 = *(const float4*)&sw[d][kk][ch * 64 + c16 * 4];
            const float4 xa = *(const float4*)&sxT[ko + kk][r4 * 8];
            const float4 xb = *(const float4*)&sxT[ko + kk][r4 * 8 + 4];
            const float xs[8] = {xa.x, xa.y, xa.z, xa.w, xb.x, xb.y, xb.z, xb.w};
#pragma unroll
            for (int j = 0; j < 8; ++j) {
                acc[j].x = fmaf(xs[j], w4.x, acc[j].x);
                acc[j].y = fmaf(xs[j], w4.y, acc[j].y);
                acc[j].z = fmaf(xs[j], w4.z, acc[j].z);
                acc[j].w = fmaf(xs[j], w4.w, acc[j].w);
            }
        }
    }
    float* xz = d ? xzB : xzF;
#pragma unroll
    for (int j = 0; j < 8; ++j) {
        *(float4*)&xz[(r0 + r4 * 8 + j) * 128 + ch * 64 + c16 * 4] = acc[j];
    }
}

// ------------- conv + silu + xproj + delta, both dirs. grid 2048 (16 rows/block) -------------
__global__ __launch_bounds__(256) void prep3_kernel(
    const float* __restrict__ xzF_, const float* __restrict__ xzB_,
    const float* __restrict__ conv_w, const float* __restrict__ conv_b,
    const float* __restrict__ xproj_w, const float* __restrict__ dt_w,
    const float* __restrict__ dt_b, int layer,
    float* __restrict__ xpF_, float* __restrict__ xpB_,
    float* __restrict__ xbcF_, float* __restrict__ xbcB_,
    float* __restrict__ pkF_, float* __restrict__ pkB_)
{
    __shared__ float sW[64 * 132];
    __shared__ float sxp[4][64];
    __shared__ float sdl[4][4];
    const int tid = threadIdx.x, wv = tid >> 6, lane = tid & 63;
    const int dir = (int)(blockIdx.x >= 1024);        // block-uniform
    const int r0 = (blockIdx.x & 1023) * 16;          // 16 rows, same b
    const int b = r0 >> 9;
    const int m = layer * 2 + dir;
    const float* Wg = xproj_w + m * 8448;
    for (int q = tid; q < 8448; q += 256) sW[q] = Wg[q];
    const float* xz = dir ? xzB_ : xzF_;
    float* xp  = dir ? xpB_  : xpF_;
    float* xbc = dir ? xbcB_ : xbcF_;
    float* pkx = dir ? pkB_  : pkF_;
    const float* cw = conv_w + m * 192 + lane * 3;
    const float cw0 = cw[0], cw1 = cw[1], cw2 = cw[2];
    const float cb  = conv_b[m * 64 + lane];
    const float dtb = dt_b[m * 64 + lane];
    const float* dwp = dt_w + m * 256;
    const float dw0 = dwp[lane], dw1 = dwp[64 + lane], dw2 = dwp[128 + lane], dw3 = dwp[192 + lane];
    __syncthreads();
    const int jdt = lane & 3;
    for (int it = 0; it < 4; ++it) {
        const int row = r0 + wv * 4 + it;
        const int l = row & 511;
        const int l1 = dir ? l + 1 : l - 1;
        const int l2 = dir ? l + 2 : l - 2;
        float acc = cb;
        const float x0 = xz[(size_t)row * 128 + lane];
        const float x1 = (l1 >= 0 && l1 < 512) ? xz[(size_t)(b * 512 + l1) * 128 + lane] : 0.f;
        const float x2 = (l2 >= 0 && l2 < 512) ? xz[(size_t)(b * 512 + l2) * 128 + lane] : 0.f;
        acc += cw0 * x2 + cw1 * x1 + cw2 * x0;
        const float u = acc * sigf(acc);   // silu
        xp[row * 64 + lane] = u;
        sxp[wv][lane] = u;
        float aB = 0.f, aC = 0.f, adt = 0.f;
#pragma unroll 8
        for (int k = 0; k < 64; ++k) {
            const float xv = sxp[wv][k];
            aB  = fmaf(xv, sW[k * 132 + 4 + lane], aB);
            aC  = fmaf(xv, sW[k * 132 + 68 + lane], aC);
            adt = fmaf(xv, sW[k * 132 + jdt], adt);
        }
        // deinterleaved: B cols 0-63, C cols 64-127
        xbc[row * 128 + lane]      = aB;
        xbc[row * 128 + 64 + lane] = aC;
        if (lane < 4) sdl[wv][lane] = adt;
        float dpre = fmaf(sdl[wv][0], dw0, dtb);
        dpre = fmaf(sdl[wv][1], dw1, dpre);
        dpre = fmaf(sdl[wv][2], dw2, dpre);
        dpre = fmaf(sdl[wv][3], dw3, dpre);
        const float dlt = (dpre > 20.f) ? dpre : log1pf(__expf(dpre));
        ((float2*)pkx)[row * 64 + lane] = float2{dlt, dlt * u};
    }
}

// ------------- selective scan v6. grid 1024, block 256 -------------
// Block id: low 6 bits = (dir,b) so all 16 e-quad blocks of one (dir,b) share an XCD.
// wave wv owns e = e0+wv, lane = n. __expf (native, 2 instr) for dA.
__global__ __launch_bounds__(256, 4) void scan6_kernel(
    const float* __restrict__ xbcF, const float* __restrict__ xbcB,
    const float* __restrict__ pkF, const float* __restrict__ pkB,
    const float* __restrict__ AlogF, const float* __restrict__ AlogB,
    float* __restrict__ ysF, float* __restrict__ ysB)
{
    __shared__ float sbc[2][2048];        // 16 KB
    __shared__ float spk[2][4][16][2];    // 1 KB
    __shared__ float ytile[4][16][68];    // 17.4 KB
    const int tid = threadIdx.x, wv = tid >> 6, lane = tid & 63;
    const int bx = blockIdx.x;
    const int db = bx & 63;               // (dir,b) in low bits -> same XCD for all e-quads
    const int dir = db >> 5;
    const int b   = db & 31;
    const int e0  = (bx >> 6) * 4;
    const int e   = e0 + wv;
    const float* xbc = dir ? xbcB : xbcF;
    const float* pk  = dir ? pkB  : pkF;
    const float* Aw  = dir ? AlogB : AlogF;
    float* ys = dir ? ysB : ysF;
    const float a = -__expf(Aw[e * 64 + lane]);   // raw A (native exp path in-loop)
    float s = 0.f;
    float* yrow = ys + (size_t)(b * 64 + e) * 512;

    const int psl = tid & 15, pw_ = tid >> 4;   // tid<64: pk staging coords

#define STG_LOAD(RS)                                                              \
    {                                                                             \
        nba = *(const float4*)(xbc + (size_t)(RS) * 128 + tid * 4);               \
        nbb = *(const float4*)(xbc + (size_t)(RS) * 128 + 1024 + tid * 4);        \
        if (tid < 64)                                                             \
            npp = *(const float2*)(pk + (size_t)((RS) + psl) * 128 + (e0 + pw_) * 2); \
    }
#define STG_WRITE(BUF)                                                            \
    {                                                                             \
        *(float4*)(&sbc[BUF][tid * 4])        = nba;                              \
        *(float4*)(&sbc[BUF][1024 + tid * 4]) = nbb;                              \
        if (tid < 64) *(float2*)(&spk[BUF][pw_][psl][0]) = npp;                   \
    }

#define SCAN16(REV)                                                               \
    {                                                                             \
        const float* bc = &sbc[cur][0];                                           \
        const float* pq = &spk[cur][wv][0][0];                                    \
        _Pragma("unroll")                                                         \
        for (int j = 0; j < 8; ++j) {                                             \
            const int pj = (REV) ? 7 - j : j;                                     \
            const float4 pk4 = *(const float4*)(pq + pj * 4);                     \
            const int sA = (REV) ? 15 - 2 * j : 2 * j;                            \
            const int sB = (REV) ? 14 - 2 * j : 2 * j + 1;                        \
            const float dlA = (REV) ? pk4.z : pk4.x;                              \
            const float duA = (REV) ? pk4.w : pk4.y;                              \
            const float dlB = (REV) ? pk4.x : pk4.z;                              \
            const float duB = (REV) ? pk4.y : pk4.w;                              \
            const float BnA = bc[sA * 128 + lane];                                \
            const float CnA = bc[sA * 128 + 64 + lane];                           \
            s = fmaf(__expf(dlA * a), s, duA * BnA);                              \
            ytile[wv][2 * j][lane] = s * CnA;                                     \
            const float BnB = bc[sB * 128 + lane];                                \
            const float CnB = bc[sB * 128 + 64 + lane];                           \
            s = fmaf(__expf(dlB * a), s, duB * BnB);                              \
            ytile[wv][2 * j + 1][lane] = s * CnB;                                 \
        }                                                                         \
    }

    // prologue: stage tile 0
    {
        float4 nba, nbb; float2 npp;
        const int rs0 = b * 512 + (dir ? 496 : 0);
        STG_LOAD(rs0);
        STG_WRITE(0);
    }
    __syncthreads();

    int cur = 0;
    const int rr = lane & 15, sg = lane >> 4;
    for (int t = 0; t < 32; ++t) {
        float4 nba, nbb; float2 npp;
        const bool more = (t + 1) < 32;
        if (more) {
            const int rs = b * 512 + (dir ? (496 - (t + 1) * 16) : ((t + 1) * 16));
            STG_LOAD(rs);
        }
        if (dir == 0) { SCAN16(0) } else { SCAN16(1) }
        // per-wave reduce of own ytile (wave-private, no barrier needed)
        {
            const float* yt = &ytile[wv][rr][sg * 16];
            const float4 A0 = *(const float4*)yt;
            const float4 A1 = *(const float4*)(yt + 4);
            const float4 A2 = *(const float4*)(yt + 8);
            const float4 A3 = *(const float4*)(yt + 12);
            float p = ((A0.x + A0.y) + (A0.z + A0.w)) + ((A1.x + A1.y) + (A1.z + A1.w))
                    + ((A2.x + A2.y) + (A2.z + A2.w)) + ((A3.x + A3.y) + (A3.z + A3.w));
            p += __shfl_xor(p, 16);
            p += __shfl_xor(p, 32);
            if (lane < 16) {
                const int lg = dir ? (511 - (t * 16 + rr)) : (t * 16 + rr);
                yrow[lg] = p;
            }
        }
        if (more) STG_WRITE(cur ^ 1);
        __syncthreads();
        cur ^= 1;
    }
#undef STG_LOAD
#undef STG_WRITE
#undef SCAN16
}

// ------------- opfn: gate + out-proj + LN1 + FFN + LN2 fused. grid 1024 (16 rows), block 256 --
__global__ __launch_bounds__(256) void opfn_kernel(
    const float* __restrict__ ysF, const float* __restrict__ ysB,
    const float* __restrict__ xpF, const float* __restrict__ xpB,
    const float* __restrict__ xzF, const float* __restrict__ xzB,
    const float* __restrict__ Dp, int layer,
    const float* __restrict__ Xc, const float* __restrict__ out_w,
    const float* __restrict__ W1, const float* __restrict__ b1,
    const float* __restrict__ W2, const float* __restrict__ b2,
    const float* __restrict__ g1, const float* __restrict__ bb1,
    const float* __restrict__ g2, const float* __restrict__ bb2,
    float* __restrict__ xout)
{
    __shared__ float smem[8832];
    float* syt = smem;            // [2][64][17] = 2176 (dead after phase1)
    float* y3  = smem;            // [16][128] = 2048 (over syt)
    float* sy  = smem + 2176;     // [16][128] = 2048
    float* sw  = smem + 4224;     // [32][128] = 4096
    float* sh  = smem + 8320;     // [16][32]  = 512
    const int tid = threadIdx.x;
    const int r0 = blockIdx.x * 16;
    const int b = r0 >> 9, l0 = r0 & 511;

    // phase 0: load ys (both dirs) transposed into syt
    for (int q = tid; q < 2048; q += 256) {
        const int d = q >> 10, ee = (q >> 4) & 63, r = q & 15;
        const float* ysp = d ? ysB : ysF;
        syt[(d * 64 + ee) * 17 + r] = ysp[(size_t)(b * 64 + ee) * 512 + l0 + r];
    }
    __syncthreads();
    // phase 1: gate -> sy[r][c] (c<64: fwd e=c; c>=64: bwd e=c-64)
    for (int q = tid; q < 2048; q += 256) {
        const int r = q >> 7, c = q & 127;
        const int d = c >> 6, ee = c & 63;
        const int row = r0 + r;
        const float dv  = Dp[(layer * 2 + d) * 64 + ee];
        const float u   = (d ? xpB : xpF)[(size_t)row * 64 + ee];
        const float res = (d ? xzB : xzF)[(size_t)row * 128 + 64 + ee];
        sy[r * 128 + c] = (syt[(d * 64 + ee) * 17 + r] + u * dv) * sigf(res);
    }
    // phase 2: out-proj GEMM (K=128) + residual + LN1 -> y3 (LDS)
    const int wv = tid >> 6, lane = tid & 63;
    const float* WFp = out_w + (layer * 2) * 8192;
    const float* WBp = out_w + (layer * 2 + 1) * 8192;
    float acc[4][2];
#pragma unroll
    for (int r = 0; r < 4; ++r) { acc[r][0] = 0.f; acc[r][1] = 0.f; }
    for (int ko = 0; ko < 128; ko += 32) {
        __syncthreads();   // first iter: also covers sy writes
        for (int q = tid; q < 4096; q += 256) {
            const int kk = q >> 7, c = q & 127;
            const int kg = ko + kk;
            sw[kk * 128 + c] = (kg < 64) ? WFp[kg * 128 + c] : WBp[(kg - 64) * 128 + c];
        }
        __syncthreads();
#define OPSTEP(COMP, J)                                                           \
        {                                                                         \
            const float w0 = sw[(kk + (J)) * 128 + lane];                         \
            const float w1 = sw[(kk + (J)) * 128 + lane + 64];                    \
            acc[0][0] = fmaf(y40.COMP, w0, acc[0][0]);                            \
            acc[0][1] = fmaf(y40.COMP, w1, acc[0][1]);                            \
            acc[1][0] = fmaf(y41.COMP, w0, acc[1][0]);                            \
            acc[1][1] = fmaf(y41.COMP, w1, acc[1][1]);                            \
            acc[2][0] = fmaf(y42.COMP, w0, acc[2][0]);                            \
            acc[2][1] = fmaf(y42.COMP, w1, acc[2][1]);                            \
            acc[3][0] = fmaf(y43.COMP, w0, acc[3][0]);                            \
            acc[3][1] = fmaf(y43.COMP, w1, acc[3][1]);                            \
        }
#pragma unroll
        for (int kk = 0; kk < 32; kk += 4) {
            const float4 y40 = *(const float4*)&sy[(wv * 4 + 0) * 128 + ko + kk];
            const float4 y41 = *(const float4*)&sy[(wv * 4 + 1) * 128 + ko + kk];
            const float4 y42 = *(const float4*)&sy[(wv * 4 + 2) * 128 + ko + kk];
            const float4 y43 = *(const float4*)&sy[(wv * 4 + 3) * 128 + ko + kk];
            OPSTEP(x, 0) OPSTEP(y, 1) OPSTEP(z, 2) OPSTEP(w, 3)
        }
#undef OPSTEP
    }
    __syncthreads();       // sy/syt dead; safe to overwrite y3 region
#pragma unroll
    for (int r = 0; r < 4; ++r) {
        const int rl = wv * 4 + r;
        const int row = r0 + rl;
        float v0 = acc[r][0] + Xc[(size_t)row * 128 + lane];
        float v1 = acc[r][1] + Xc[(size_t)row * 128 + lane + 64];
        float sum = v0 + v1, sq = v0 * v0 + v1 * v1;
#pragma unroll
        for (int o = 32; o >= 1; o >>= 1) { sum += __shfl_xor(sum, o); sq += __shfl_xor(sq, o); }
        const float mean = sum * (1.f / 128.f);
        const float var = sq * (1.f / 128.f) - mean * mean;
        const float rs = rsqrtf(var + 1e-5f);
        y3[rl * 128 + lane]      = (v0 - mean) * rs * g1[lane] + bb1[lane];
        y3[rl * 128 + lane + 64] = (v1 - mean) * rs * g1[lane + 64] + bb1[lane + 64];
    }
    __syncthreads();
    // phase 3: hid = relu(y3 @ W1 + b1) -> sh
    {
        const int r = tid >> 4, u = tid & 15;
        float h0 = b1[u], h1 = b1[u + 16];
#pragma unroll 8
        for (int k = 0; k < 128; ++k) {
            const float xv = y3[r * 128 + k];
            h0 = fmaf(xv, W1[k * 32 + u], h0);
            h1 = fmaf(xv, W1[k * 32 + u + 16], h1);
        }
        sh[r * 32 + u]      = fmaxf(h0, 0.f);
        sh[r * 32 + u + 16] = fmaxf(h1, 0.f);
    }
    __syncthreads();
    // phase 4: FFN2 + residual(y3) + LN2 -> xout
#pragma unroll
    for (int r = 0; r < 4; ++r) {
        const int rl = wv * 4 + r;
        float a0 = b2[lane], a1 = b2[lane + 64];
#pragma unroll 8
        for (int k = 0; k < 32; ++k) {
            const float hv = sh[rl * 32 + k];
            a0 = fmaf(hv, W2[k * 128 + lane], a0);
            a1 = fmaf(hv, W2[k * 128 + lane + 64], a1);
        }
        const float v0 = a0 + y3[rl * 128 + lane];
        const float v1 = a1 + y3[rl * 128 + lane + 64];
        float sum = v0 + v1, sq = v0 * v0 + v1 * v1;
#pragma unroll
        for (int o = 32; o >= 1; o >>= 1) { sum += __shfl_xor(sum, o); sq += __shfl_xor(sq, o); }
        const float mean = sum * (1.f / 128.f);
        const float var = sq * (1.f / 128.f) - mean * mean;
        const float rs = rsqrtf(var + 1e-5f);
        const int row = r0 + rl;
        xout[(size_t)row * 128 + lane]      = (v0 - mean) * rs * g2[lane] + bb2[lane];
        xout[(size_t)row * 128 + lane + 64] = (v1 - mean) * rs * g2[lane + 64] + bb2[lane + 64];
    }
}

// ================= head =================
__global__ __launch_bounds__(256) void head_prep_kernel(
    const float* __restrict__ psi, const float* __restrict__ W_q, const float* __restrict__ W_k,
    const float* __restrict__ f_b, const float* __restrict__ hmix, const float* __restrict__ attn_a,
    float* __restrict__ mixb, float* __restrict__ alphab, float* __restrict__ bft,
    float* __restrict__ Qb, float* __restrict__ Kb)
{
    const int tid = threadIdx.x;
    const float m0 = hmix[0], m1 = hmix[1], m2 = hmix[2], m3 = hmix[3];
    const float mx = fmaxf(fmaxf(m0, m1), fmaxf(m2, m3));
    const float e0 = __expf(m0 - mx), e1 = __expf(m1 - mx), e2 = __expf(m2 - mx), e3 = __expf(m3 - mx);
    const float inv = 1.f / (e0 + e1 + e2 + e3);
    float mixv[4] = {e0 * inv, e1 * inv, e2 * inv, e3 * inv};
    if (tid < 4) mixb[tid] = mixv[tid];
    if (tid == 4) alphab[0] = sigf(attn_a[0]);
    if (tid < 128) {
        float s = 0.f;
        for (int h = 0; h < 4; ++h) {
            float t = 0.f;
            for (int d = 0; d < 10; ++d) t = fmaf(psi[tid * 10 + d], f_b[h * 10 + d], t);
            s = fmaf(mixv[h], t, s);
        }
        bft[tid] = s;
    }
    for (int idx = tid; idx < 5120; idx += 256) {
        const int n = idx / 40, rem = idx - n * 40, h = rem / 10, d = rem - h * 10;
        float q = 0.f, kk = 0.f;
        for (int d0 = 0; d0 < 10; ++d0) {
            const float pv = psi[n * 10 + d0];
            q = fmaf(pv, W_q[(d0 * 4 + h) * 10 + d], q);
            kk = fmaf(pv, W_k[(d0 * 4 + h) * 10 + d], kk);
        }
        Qb[idx] = q; Kb[idx] = kk;
    }
}

// fused qk + aeff: grid 512 (h,n), block 128 (m)
__global__ __launch_bounds__(128) void head_qkaeff_kernel(
    const float* __restrict__ psi, const float* __restrict__ psis,
    const float* __restrict__ Qb, const float* __restrict__ Kb,
    const float* __restrict__ alphab,
    float* __restrict__ Aeff, float* __restrict__ StT)
{
    __shared__ float spn[10];
    __shared__ float red[128];
    const int h = blockIdx.x >> 7, n = blockIdx.x & 127, mcol = threadIdx.x;
    if (mcol < 10) spn[mcol] = psi[n * 10 + mcol];
    __syncthreads();
    float d2 = 0.f;
#pragma unroll
    for (int d = 0; d < 10; ++d) { const float df = spn[d] - psi[mcol * 10 + d]; d2 = fmaf(df, df, d2); }
    const float gv = __expf(-psis[0] * d2);
    float qv = 0.f;
#pragma unroll
    for (int d = 0; d < 10; ++d) qv = fmaf(Qb[n * 40 + h * 10 + d], Kb[mcol * 40 + h * 10 + d], qv);
    qv *= 0.3162277660168379332f;  // 1/sqrt(10)
    float r;
    red[mcol] = gv; __syncthreads();
    for (int s = 64; s >= 1; s >>= 1) { if (mcol < s) red[mcol] = fmaxf(red[mcol], red[mcol + s]); __syncthreads(); }
    r = red[0]; __syncthreads();
    const float eg = __expf(gv - r);
    red[mcol] = eg; __syncthreads();
    for (int s = 64; s >= 1; s >>= 1) { if (mcol < s) red[mcol] += red[mcol + s]; __syncthreads(); }
    const float gsum = red[0]; __syncthreads();
    red[mcol] = qv; __syncthreads();
    for (int s = 64; s >= 1; s >>= 1) { if (mcol < s) red[mcol] = fmaxf(red[mcol], red[mcol + s]); __syncthreads(); }
    r = red[0]; __syncthreads();
    const float eq = __expf(qv - r);
    red[mcol] = eq; __syncthreads();
    for (int s = 64; s >= 1; s >>= 1) { if (mcol < s) red[mcol] += red[mcol + s]; __syncthreads(); }
    const float qsum = red[0];
    const float al = alphab[0];
    const float aeff = al * (eg / gsum) + (1.f - al) * (eq / qsum);
    Aeff[h * 16384 + n * 128 + mcol] = aeff;
    StT[((h * 4 + 1) * 128 + mcol) * 128 + n] = aeff;
    StT[((h * 4 + 0) * 128 + mcol) * 128 + n] = (mcol == n) ? 1.f : 0.f;
}

__global__ __launch_bounds__(256) void head_cheb_kernel(
    const float* __restrict__ Aeff, float* __restrict__ StT, int kk)
{
    const int h = blockIdx.x >> 6;
    const int m0 = ((blockIdx.x & 63) << 1) + (threadIdx.x >> 7);
    const int n = threadIdx.x & 127;
    const float* Ar = Aeff + h * 16384 + n * 128;
    const float* Sp = StT + ((h * 4 + kk - 1) * 128 + m0) * 128;
    float acc = 0.f;
#pragma unroll 8
    for (int p = 0; p < 128; ++p) acc = fmaf(Ar[p], Sp[p], acc);
    const float s2 = StT[((h * 4 + kk - 2) * 128 + m0) * 128 + n];
    StT[((h * 4 + kk) * 128 + m0) * 128 + n] = 2.f * acc - s2;
}

__global__ __launch_bounds__(256) void head_wf_kernel(
    const float* __restrict__ psi, const float* __restrict__ F_w, float* __restrict__ WfT)
{
    const int idx = blockIdx.x * 256 + threadIdx.x;  // 2^20
    const int n = idx & 127, l = (idx >> 7) & 511, k = (idx >> 16) & 3, h = idx >> 18;
    float acc = 0.f;
#pragma unroll
    for (int d = 0; d < 10; ++d)
        acc = fmaf(psi[n * 10 + d], F_w[((h * 10 + d) * 4 + k) * 512 + l], acc);
    WfT[idx] = acc;
}

__global__ __launch_bounds__(256) void head_v3_kernel(
    const float* __restrict__ StT, const float* __restrict__ WfT, const float* __restrict__ mixb,
    float* __restrict__ V)
{
    const int tid = threadIdx.x;
    const int lt = blockIdx.x & 63, mm = blockIdx.x >> 6;
    const int n = tid & 127, mh = tid >> 7;
    const int m = mm * 2 + mh;
    const int l0 = lt * 8;
    float sv[16];
#pragma unroll
    for (int h = 0; h < 4; ++h) {
        const float mx = mixb[h];
#pragma unroll
        for (int k = 0; k < 4; ++k)
            sv[h * 4 + k] = mx * StT[(size_t)((h * 4 + k) * 128 + m) * 128 + n];
    }
#pragma unroll
    for (int j = 0; j < 8; ++j) {
        const int l = l0 + j;
        float acc = 0.f;
#pragma unroll
        for (int hk = 0; hk < 16; ++hk)
            acc = fmaf(sv[hk], WfT[(size_t)(hk * 512 + l) * 128 + n], acc);
        V[(size_t)(l * 128 + m) * 128 + n] = acc;
    }
}

__global__ __launch_bounds__(256) void head_ctr_kernel(
    const float* __restrict__ Xf, const float* __restrict__ V, float* __restrict__ partial)
{
    __shared__ float sx[32][128];
    const int l = blockIdx.x, tid = threadIdx.x;
    const int n = tid & 127, mh = tid >> 7;
    for (int q = tid; q < 4096; q += 256) {
        const int b = q >> 7, mm = q & 127;
        sx[b][mm] = Xf[(b * 512 + l) * 128 + mm];
    }
    __syncthreads();
    float acc[32];
#pragma unroll
    for (int b = 0; b < 32; ++b) acc[b] = 0.f;
    const float* vp = V + (size_t)(l * 128 + mh * 64) * 128 + n;
    for (int mm = 0; mm < 64; ++mm) {
        const float v = vp[(size_t)mm * 128];
        const int m = mh * 64 + mm;
#pragma unroll
        for (int b = 0; b < 32; ++b) acc[b] = fmaf(sx[b][m], v, acc[b]);
    }
#pragma unroll
    for (int b = 0; b < 32; ++b)
        partial[(size_t)((l * 2 + mh) * 32 + b) * 128 + n] = acc[b];
}

// stage 1: reduce partial[1024][32][128] over 32-chunk slices. grid 1024 (b,cs), block 128.
__global__ __launch_bounds__(128) void head_red_kernel(
    const float* __restrict__ partial, float* __restrict__ red1)
{
    const int b = blockIdx.x >> 5, cs = blockIdx.x & 31, n = threadIdx.x;
    const float* p = partial + ((size_t)(cs * 32) * 32 + b) * 128 + n;
    float s = 0.f;
#pragma unroll 8
    for (int c = 0; c < 32; ++c) s += p[(size_t)c * 4096];
    red1[(b * 32 + cs) * 128 + n] = s;
}

// stage 2: final reduce + bias + head_w dot + log_var. grid 32, block 128.
__global__ __launch_bounds__(128) void head_out_kernel(
    const float* __restrict__ red1, const float* __restrict__ bft,
    const float* __restrict__ head_w, const float* __restrict__ head_b, float* __restrict__ out)
{
    __shared__ float red[128];
    const int b = blockIdx.x, n = threadIdx.x;
    float s = bft[n];
#pragma unroll 8
    for (int cs = 0; cs < 32; ++cs) s += red1[(b * 32 + cs) * 128 + n];
    red[n] = s * head_w[n];
    __syncthreads();
    for (int st = 64; st >= 1; st >>= 1) { if (n < st) red[n] += red[n + st]; __syncthreads(); }
    if (n == 0) out[b] = red[0] + head_b[0];
    out[32 + b * 128 + n] = 0.f;   // log_var = zeros
}

extern "C" void kernel_launch(void* const* d_in, const int* in_sizes, int n_in,
                              void* d_out, int out_size, void* d_ws, size_t ws_size,
                              hipStream_t stream) {
    const float* x_in    = (const float*)d_in[0];
    const float* in_w    = (const float*)d_in[1];
    const float* conv_w  = (const float*)d_in[2];
    const float* conv_b  = (const float*)d_in[3];
    const float* xproj_w = (const float*)d_in[4];
    const float* dt_w    = (const float*)d_in[5];
    const float* dt_b    = (const float*)d_in[6];
    const float* Alog    = (const float*)d_in[7];
    const float* Dp      = (const float*)d_in[8];
    const float* out_w   = (const float*)d_in[9];
    const float* ln1_g   = (const float*)d_in[10];
    const float* ln1_b   = (const float*)d_in[11];
    const float* ln2_g   = (const float*)d_in[12];
    const float* ln2_b   = (const float*)d_in[13];
    const float* ffn_w1  = (const float*)d_in[14];
    const float* ffn_b1  = (const float*)d_in[15];
    const float* ffn_w2  = (const float*)d_in[16];
    const float* ffn_b2  = (const float*)d_in[17];
    const float* psi_emb = (const float*)d_in[18];
    const float* psi_s   = (const float*)d_in[19];
    const float* W_q     = (const float*)d_in[20];
    const float* W_k     = (const float*)d_in[21];
    const float* attn_a  = (const float*)d_in[22];
    const float* F_w     = (const float*)d_in[23];
    const float* f_b     = (const float*)d_in[24];
    const float* hmix    = (const float*)d_in[25];
    const float* head_w  = (const float*)d_in[26];
    const float* head_b  = (const float*)d_in[27];
    float* ws = (float*)d_ws;
    float* outp = (float*)d_out;

    for (int i = 0; i < 3; ++i) {
        const float* xcur = (i == 0) ? x_in : (ws + OFF_X);
        const int mF = 2 * i, mB = 2 * i + 1;
        gemm_in2_kernel<<<512, 256, 0, stream>>>(
            xcur, in_w + mF * 16384, in_w + mB * 16384, ws + OFF_XZF, ws + OFF_XZB);
        prep3_kernel<<<2048, 256, 0, stream>>>(
            ws + OFF_XZF, ws + OFF_XZB, conv_w, conv_b, xproj_w, dt_w, dt_b, i,
            ws + OFF_XPF, ws + OFF_XPB, ws + OFF_XBCF, ws + OFF_XBCB, ws + OFF_PKF, ws + OFF_PKB);
        scan6_kernel<<<1024, 256, 0, stream>>>(
            ws + OFF_XBCF, ws + OFF_XBCB, ws + OFF_PKF, ws + OFF_PKB,
            Alog + mF * 4096, Alog + mB * 4096, ws + OFF_YSF, ws + OFF_YSB);
        opfn_kernel<<<1024, 256, 0, stream>>>(
            ws + OFF_YSF, ws + OFF_YSB, ws + OFF_XPF, ws + OFF_XPB, ws + OFF_XZF, ws + OFF_XZB,
            Dp, i, xcur, out_w,
            ffn_w1 + i * 4096, ffn_b1 + i * 32, ffn_w2 + i * 4096, ffn_b2 + i * 128,
            ln1_g + i * 128, ln1_b + i * 128, ln2_g + i * 128, ln2_b + i * 128,
            ws + OFF_X);
    }
    // head
    head_prep_kernel<<<1, 256, 0, stream>>>(
        psi_emb, W_q, W_k, f_b, hmix, attn_a,
        ws + OFF_MIX, ws + OFF_ALPH, ws + OFF_BFT, ws + OFF_QB, ws + OFF_KB);
    head_qkaeff_kernel<<<512, 128, 0, stream>>>(
        psi_emb, psi_s, ws + OFF_QB, ws + OFF_KB, ws + OFF_ALPH, ws + OFF_AEFF, ws + OFF_STT);
    head_cheb_kernel<<<256, 256, 0, stream>>>(ws + OFF_AEFF, ws + OFF_STT, 2);
    head_cheb_kernel<<<256, 256, 0, stream>>>(ws + OFF_AEFF, ws + OFF_STT, 3);
    head_wf_kernel<<<4096, 256, 0, stream>>>(psi_emb, F_w, ws + OFF_WFT);
    head_v3_kernel<<<4096, 256, 0, stream>>>(ws + OFF_STT, ws + OFF_WFT, ws + OFF_MIX, ws + OFF_V);
    head_ctr_kernel<<<512, 256, 0, stream>>>(ws + OFF_X, ws + OFF_V, ws + OFF_PART);
    head_red_kernel<<<1024, 128, 0, stream>>>(ws + OFF_PART, ws + OFF_RED1);
    head_out_kernel<<<32, 128, 0, stream>>>(
        ws + OFF_RED1, ws + OFF_BFT, head_w, head_b, outp);
}

// Round 7
// 588.621 us; speedup vs baseline: 1.6496x; 1.0238x over previous
//
#include <hip/hip_runtime.h>
#include <hip/hip_bf16.h>

// MAMBA_BayesMAGAC: B=32, L=512, D=128, E=64, HS=64, DTR=4, U=32, R=3, K=3, DE=10, NH=4
// Round 7: scan7 (packed bf16 B/C -> 1 ds_read_b32/step, halved LDS+HBM traffic),
// opfn stages W1/W2 in LDS (kills per-thread VMEM loops).

#define B_ 32
#define L_ 512
#define D_ 128
#define E_ 64
#define HS_ 64

// ---- workspace offsets (floats) ----
#define OFF_X     0u          // 2,097,152  x [b][l][128]
#define OFF_XZF   2097152u    // 2,097,152  xz fwd [b][l][128]
#define OFF_XZB   4194304u
#define OFF_XPF   6291456u    // 1,048,576  xp [b][l][64]
#define OFF_XPB   7340032u
#define OFF_PKF   8388608u    // 2,097,152  (dl,du) [b][l][64][2]
#define OFF_PKB   10485760u
#define OFF_XBCF  12582912u   // 1,048,576 u32: packed bf16 (C<<16|B) [b][l][64]
#define OFF_XBCB  14680064u
#define OFF_YSF   16777216u   // 1,048,576  scan y [b][e][l]
#define OFF_YSB   17825792u   // end 18,874,368 floats = 75.5 MB
// head phase (only OFF_X live):
#define OFF_V     2097152u    // 8,388,608  V [l][m][n]
#define OFF_WFT   10485760u   // 1,048,576  Wf [h][k][l][n]
#define OFF_STT   11534336u   // 262,144    S^T [h][k][m][n]
#define OFF_AEFF  11796480u   // 65,536
#define OFF_QB    11943936u   // 5,120
#define OFF_KB    11949056u   // 5,120
#define OFF_MIX   11954176u   // 4
#define OFF_ALPH  11954180u   // 1
#define OFF_BFT   11954184u   // 128
#define OFF_PART  12582912u   // 4,194,304  partial [1024][32][128]
#define OFF_RED1  16777216u   // 131,072    red1 [32][32][128]

__device__ __forceinline__ float sigf(float x) { return 1.f / (1.f + __expf(-x)); }
__device__ __forceinline__ unsigned int bf16r(float x) {
    unsigned int u = __float_as_uint(x);
    return (u + 0x7fffu + ((u >> 16) & 1u)) >> 16;   // RNE to bf16, return low 16
}

// ---------------- in-projection: xz = x @ in_w (both dirs), 32 rows/block ----------------
__global__ __launch_bounds__(256) void gemm_in2_kernel(
    const float* __restrict__ X, const float* __restrict__ WF, const float* __restrict__ WB,
    float* __restrict__ xzF, float* __restrict__ xzB)
{
    __shared__ float sxT[128][36];    // transposed x tile, padded
    __shared__ float sw[2][16][128];
    const int tid = threadIdx.x;
    const int r0 = blockIdx.x * 32;
    for (int q = tid; q < 32 * 128; q += 256) {
        const int r = q >> 7, k = q & 127;
        sxT[k][r] = X[(r0 + r) * 128 + k];
    }
    const int wv = tid >> 6, lane = tid & 63;
    const int d = wv >> 1, ch = wv & 1;
    const int r4 = lane >> 4, c16 = lane & 15;
    float4 acc[8];
#pragma unroll
    for (int j = 0; j < 8; ++j) acc[j] = float4{0.f, 0.f, 0.f, 0.f};
    for (int ko = 0; ko < 128; ko += 16) {
        __syncthreads();
        for (int q = tid; q < 2 * 16 * 128; q += 256) {
            const int dd = q >> 11, kk = (q >> 7) & 15, c = q & 127;
            sw[dd][kk][c] = (dd ? WB : WF)[(ko + kk) * 128 + c];
        }
        __syncthreads();
#pragma unroll
        for (int kk = 0; kk < 16; ++kk) {
            const float4 w4 = *(const float4*)&sw[d][kk][ch * 64 + c16 * 4];
            const float4 xa = *(const float4*)&sxT[ko + kk][r4 * 8];
            const float4 xb = *(const float4*)&sxT[ko + kk][r4 * 8 + 4];
            const float xs[8] = {xa.x, xa.y, xa.z, xa.w, xb.x, xb.y, xb.z, xb.w};
#pragma unroll
            for (int j = 0; j < 8; ++j) {
                acc[j].x = fmaf(xs[j], w4.x, acc[j].x);
                acc[j].y = fmaf(xs[j], w4.y, acc[j].y);
                acc[j].z = fmaf(xs[j], w4.z, acc[j].z);
                acc[j].w = fmaf(xs[j], w4.w, acc[j].w);
            }
        }
    }
    float* xz = d ? xzB : xzF;
#pragma unroll
    for (int j = 0; j < 8; ++j) {
        *(float4*)&xz[(r0 + r4 * 8 + j) * 128 + ch * 64 + c16 * 4] = acc[j];
    }
}

// ------------- conv + silu + xproj + delta, both dirs. grid 2048 (16 rows/block) -------------
__global__ __launch_bounds__(256) void prep3_kernel(
    const float* __restrict__ xzF_, const float* __restrict__ xzB_,
    const float* __restrict__ conv_w, const float* __restrict__ conv_b,
    const float* __restrict__ xproj_w, const float* __restrict__ dt_w,
    const float* __restrict__ dt_b, int layer,
    float* __restrict__ xpF_, float* __restrict__ xpB_,
    unsigned int* __restrict__ xbcF_, unsigned int* __restrict__ xbcB_,
    float* __restrict__ pkF_, float* __restrict__ pkB_)
{
    __shared__ float sW[64 * 132];
    __shared__ float sxp[4][64];
    __shared__ float sdl[4][4];
    const int tid = threadIdx.x, wv = tid >> 6, lane = tid & 63;
    const int dir = (int)(blockIdx.x >= 1024);        // block-uniform
    const int r0 = (blockIdx.x & 1023) * 16;          // 16 rows, same b
    const int b = r0 >> 9;
    const int m = layer * 2 + dir;
    const float* Wg = xproj_w + m * 8448;
    for (int q = tid; q < 8448; q += 256) sW[q] = Wg[q];
    const float* xz = dir ? xzB_ : xzF_;
    float* xp  = dir ? xpB_  : xpF_;
    unsigned int* xbc = dir ? xbcB_ : xbcF_;
    float* pkx = dir ? pkB_  : pkF_;
    const float* cw = conv_w + m * 192 + lane * 3;
    const float cw0 = cw[0], cw1 = cw[1], cw2 = cw[2];
    const float cb  = conv_b[m * 64 + lane];
    const float dtb = dt_b[m * 64 + lane];
    const float* dwp = dt_w + m * 256;
    const float dw0 = dwp[lane], dw1 = dwp[64 + lane], dw2 = dwp[128 + lane], dw3 = dwp[192 + lane];
    __syncthreads();
    const int jdt = lane & 3;
    for (int it = 0; it < 4; ++it) {
        const int row = r0 + wv * 4 + it;
        const int l = row & 511;
        const int l1 = dir ? l + 1 : l - 1;
        const int l2 = dir ? l + 2 : l - 2;
        float acc = cb;
        const float x0 = xz[(size_t)row * 128 + lane];
        const float x1 = (l1 >= 0 && l1 < 512) ? xz[(size_t)(b * 512 + l1) * 128 + lane] : 0.f;
        const float x2 = (l2 >= 0 && l2 < 512) ? xz[(size_t)(b * 512 + l2) * 128 + lane] : 0.f;
        acc += cw0 * x2 + cw1 * x1 + cw2 * x0;
        const float u = acc * sigf(acc);   // silu
        xp[row * 64 + lane] = u;
        sxp[wv][lane] = u;
        float aB = 0.f, aC = 0.f, adt = 0.f;
#pragma unroll 8
        for (int k = 0; k < 64; ++k) {
            const float xv = sxp[wv][k];
            aB  = fmaf(xv, sW[k * 132 + 4 + lane], aB);
            aC  = fmaf(xv, sW[k * 132 + 68 + lane], aC);
            adt = fmaf(xv, sW[k * 132 + jdt], adt);
        }
        // packed bf16: C in high 16, B in low 16
        xbc[row * 64 + lane] = (bf16r(aC) << 16) | bf16r(aB);
        if (lane < 4) sdl[wv][lane] = adt;
        float dpre = fmaf(sdl[wv][0], dw0, dtb);
        dpre = fmaf(sdl[wv][1], dw1, dpre);
        dpre = fmaf(sdl[wv][2], dw2, dpre);
        dpre = fmaf(sdl[wv][3], dw3, dpre);
        const float dlt = (dpre > 20.f) ? dpre : log1pf(__expf(dpre));
        ((float2*)pkx)[row * 64 + lane] = float2{dlt, dlt * u};
    }
}

// ------------- selective scan v7. grid 1024, block 256, packed bf16 B/C -------------
__global__ __launch_bounds__(256, 4) void scan7_kernel(
    const unsigned int* __restrict__ xbcF, const unsigned int* __restrict__ xbcB,
    const float* __restrict__ pkF, const float* __restrict__ pkB,
    const float* __restrict__ AlogF, const float* __restrict__ AlogB,
    float* __restrict__ ysF, float* __restrict__ ysB)
{
    __shared__ unsigned int sbc[2][1024]; // 8 KB: 16 slots x 64 packed (C<<16|B)
    __shared__ float spk[2][4][16][2];    // 1 KB
    __shared__ float ytile[4][16][68];    // 17.4 KB
    const int tid = threadIdx.x, wv = tid >> 6, lane = tid & 63;
    const int bx = blockIdx.x;
    const int db = bx & 63;               // (dir,b) in low bits -> same XCD for all e-quads
    const int dir = db >> 5;
    const int b   = db & 31;
    const int e0  = (bx >> 6) * 4;
    const int e   = e0 + wv;
    const unsigned int* xbc = dir ? xbcB : xbcF;
    const float* pk  = dir ? pkB  : pkF;
    const float* Aw  = dir ? AlogB : AlogF;
    float* ys = dir ? ysB : ysF;
    const float a = -__expf(Aw[e * 64 + lane]);
    float s = 0.f;
    float* yrow = ys + (size_t)(b * 64 + e) * 512;

    const int psl = tid & 15, pw_ = tid >> 4;   // tid<64: pk staging coords

#define STG_LOAD(RS)                                                              \
    {                                                                             \
        nb = *(const uint4*)(xbc + (size_t)(RS) * 64 + tid * 4);                  \
        if (tid < 64)                                                             \
            npp = *(const float2*)(pk + (size_t)((RS) + psl) * 128 + (e0 + pw_) * 2); \
    }
#define STG_WRITE(BUF)                                                            \
    {                                                                             \
        *(uint4*)(&sbc[BUF][tid * 4]) = nb;                                       \
        if (tid < 64) *(float2*)(&spk[BUF][pw_][psl][0]) = npp;                   \
    }

#define SCAN16(REV)                                                               \
    {                                                                             \
        const unsigned int* bc = &sbc[cur][0];                                    \
        const float* pq = &spk[cur][wv][0][0];                                    \
        _Pragma("unroll")                                                         \
        for (int j = 0; j < 8; ++j) {                                             \
            const int pj = (REV) ? 7 - j : j;                                     \
            const float4 pk4 = *(const float4*)(pq + pj * 4);                     \
            const int sA = (REV) ? 15 - 2 * j : 2 * j;                            \
            const int sB = (REV) ? 14 - 2 * j : 2 * j + 1;                        \
            const float dlA = (REV) ? pk4.z : pk4.x;                              \
            const float duA = (REV) ? pk4.w : pk4.y;                              \
            const float dlB = (REV) ? pk4.x : pk4.z;                              \
            const float duB = (REV) ? pk4.y : pk4.w;                              \
            const unsigned int bA = bc[sA * 64 + lane];                           \
            const float BnA = __uint_as_float(bA << 16);                          \
            const float CnA = __uint_as_float(bA & 0xffff0000u);                  \
            s = fmaf(__expf(dlA * a), s, duA * BnA);                              \
            ytile[wv][2 * j][lane] = s * CnA;                                     \
            const unsigned int bB = bc[sB * 64 + lane];                           \
            const float BnB = __uint_as_float(bB << 16);                          \
            const float CnB = __uint_as_float(bB & 0xffff0000u);                  \
            s = fmaf(__expf(dlB * a), s, duB * BnB);                              \
            ytile[wv][2 * j + 1][lane] = s * CnB;                                 \
        }                                                                         \
    }

    // prologue: stage tile 0
    {
        uint4 nb; float2 npp;
        const int rs0 = b * 512 + (dir ? 496 : 0);
        STG_LOAD(rs0);
        STG_WRITE(0);
    }
    __syncthreads();

    int cur = 0;
    const int rr = lane & 15, sg = lane >> 4;
    for (int t = 0; t < 32; ++t) {
        uint4 nb; float2 npp;
        const bool more = (t + 1) < 32;
        if (more) {
            const int rs = b * 512 + (dir ? (496 - (t + 1) * 16) : ((t + 1) * 16));
            STG_LOAD(rs);
        }
        if (dir == 0) { SCAN16(0) } else { SCAN16(1) }
        // per-wave reduce of own ytile (wave-private)
        {
            const float* yt = &ytile[wv][rr][sg * 16];
            const float4 A0 = *(const float4*)yt;
            const float4 A1 = *(const float4*)(yt + 4);
            const float4 A2 = *(const float4*)(yt + 8);
            const float4 A3 = *(const float4*)(yt + 12);
            float p = ((A0.x + A0.y) + (A0.z + A0.w)) + ((A1.x + A1.y) + (A1.z + A1.w))
                    + ((A2.x + A2.y) + (A2.z + A2.w)) + ((A3.x + A3.y) + (A3.z + A3.w));
            p += __shfl_xor(p, 16);
            p += __shfl_xor(p, 32);
            if (lane < 16) {
                const int lg = dir ? (511 - (t * 16 + rr)) : (t * 16 + rr);
                yrow[lg] = p;
            }
        }
        if (more) STG_WRITE(cur ^ 1);
        __syncthreads();
        cur ^= 1;
    }
#undef STG_LOAD
#undef STG_WRITE
#undef SCAN16
}

// ------------- opfn: gate + out-proj + LN1 + FFN + LN2 fused. grid 1024 (16 rows), block 256 --
__global__ __launch_bounds__(256) void opfn_kernel(
    const float* __restrict__ ysF, const float* __restrict__ ysB,
    const float* __restrict__ xpF, const float* __restrict__ xpB,
    const float* __restrict__ xzF, const float* __restrict__ xzB,
    const float* __restrict__ Dp, int layer,
    const float* __restrict__ Xc, const float* __restrict__ out_w,
    const float* __restrict__ W1, const float* __restrict__ b1,
    const float* __restrict__ W2, const float* __restrict__ b2,
    const float* __restrict__ g1, const float* __restrict__ bb1,
    const float* __restrict__ g2, const float* __restrict__ bb2,
    float* __restrict__ xout)
{
    __shared__ float smem[8832];
    float* syt = smem;            // [2][64][17] = 2176 (dead after phase1)
    float* y3  = smem;            // [16][128] = 2048 (over syt)
    float* sy  = smem + 2176;     // [16][128] = 2048
    float* sw  = smem + 4224;     // [32][128] = 4096 (GEMM W; later W1, then W2)
    float* sh  = smem + 8320;     // [16][32]  = 512
    const int tid = threadIdx.x;
    const int r0 = blockIdx.x * 16;
    const int b = r0 >> 9, l0 = r0 & 511;

    // phase 0: load ys (both dirs) transposed into syt
    for (int q = tid; q < 2048; q += 256) {
        const int d = q >> 10, ee = (q >> 4) & 63, r = q & 15;
        const float* ysp = d ? ysB : ysF;
        syt[(d * 64 + ee) * 17 + r] = ysp[(size_t)(b * 64 + ee) * 512 + l0 + r];
    }
    __syncthreads();
    // phase 1: gate -> sy[r][c]
    for (int q = tid; q < 2048; q += 256) {
        const int r = q >> 7, c = q & 127;
        const int d = c >> 6, ee = c & 63;
        const int row = r0 + r;
        const float dv  = Dp[(layer * 2 + d) * 64 + ee];
        const float u   = (d ? xpB : xpF)[(size_t)row * 64 + ee];
        const float res = (d ? xzB : xzF)[(size_t)row * 128 + 64 + ee];
        sy[r * 128 + c] = (syt[(d * 64 + ee) * 17 + r] + u * dv) * sigf(res);
    }
    // phase 2: out-proj GEMM (K=128) + residual + LN1 -> y3 (LDS)
    const int wv = tid >> 6, lane = tid & 63;
    const float* WFp = out_w + (layer * 2) * 8192;
    const float* WBp = out_w + (layer * 2 + 1) * 8192;
    float acc[4][2];
#pragma unroll
    for (int r = 0; r < 4; ++r) { acc[r][0] = 0.f; acc[r][1] = 0.f; }
    for (int ko = 0; ko < 128; ko += 32) {
        __syncthreads();   // first iter: also covers sy writes
        for (int q = tid; q < 4096; q += 256) {
            const int kk = q >> 7, c = q & 127;
            const int kg = ko + kk;
            sw[kk * 128 + c] = (kg < 64) ? WFp[kg * 128 + c] : WBp[(kg - 64) * 128 + c];
        }
        __syncthreads();
#define OPSTEP(COMP, J)                                                           \
        {                                                                         \
            const float w0 = sw[(kk + (J)) * 128 + lane];                         \
            const float w1 = sw[(kk + (J)) * 128 + lane + 64];                    \
            acc[0][0] = fmaf(y40.COMP, w0, acc[0][0]);                            \
            acc[0][1] = fmaf(y40.COMP, w1, acc[0][1]);                            \
            acc[1][0] = fmaf(y41.COMP, w0, acc[1][0]);                            \
            acc[1][1] = fmaf(y41.COMP, w1, acc[1][1]);                            \
            acc[2][0] = fmaf(y42.COMP, w0, acc[2][0]);                            \
            acc[2][1] = fmaf(y42.COMP, w1, acc[2][1]);                            \
            acc[3][0] = fmaf(y43.COMP, w0, acc[3][0]);                            \
            acc[3][1] = fmaf(y43.COMP, w1, acc[3][1]);                            \
        }
#pragma unroll
        for (int kk = 0; kk < 32; kk += 4) {
            const float4 y40 = *(const float4*)&sy[(wv * 4 + 0) * 128 + ko + kk];
            const float4 y41 = *(const float4*)&sy[(wv * 4 + 1) * 128 + ko + kk];
            const float4 y42 = *(const float4*)&sy[(wv * 4 + 2) * 128 + ko + kk];
            const float4 y43 = *(const float4*)&sy[(wv * 4 + 3) * 128 + ko + kk];
            OPSTEP(x, 0) OPSTEP(y, 1) OPSTEP(z, 2) OPSTEP(w, 3)
        }
#undef OPSTEP
    }
    __syncthreads();       // sy/syt dead; sw free
    // stage W1 into sw (4096 floats) + write y3
    for (int q = tid; q < 4096; q += 256) sw[q] = W1[q];
#pragma unroll
    for (int r = 0; r < 4; ++r) {
        const int rl = wv * 4 + r;
        const int row = r0 + rl;
        float v0 = acc[r][0] + Xc[(size_t)row * 128 + lane];
        float v1 = acc[r][1] + Xc[(size_t)row * 128 + lane + 64];
        float sum = v0 + v1, sq = v0 * v0 + v1 * v1;
#pragma unroll
        for (int o = 32; o >= 1; o >>= 1) { sum += __shfl_xor(sum, o); sq += __shfl_xor(sq, o); }
        const float mean = sum * (1.f / 128.f);
        const float var = sq * (1.f / 128.f) - mean * mean;
        const float rs = rsqrtf(var + 1e-5f);
        y3[rl * 128 + lane]      = (v0 - mean) * rs * g1[lane] + bb1[lane];
        y3[rl * 128 + lane + 64] = (v1 - mean) * rs * g1[lane + 64] + bb1[lane + 64];
    }
    __syncthreads();
    // phase 3: hid = relu(y3 @ W1 + b1) -> sh  (W1 from LDS)
    {
        const int r = tid >> 4, u = tid & 15;
        float h0 = b1[u], h1 = b1[u + 16];
#pragma unroll 8
        for (int k = 0; k < 128; ++k) {
            const float xv = y3[r * 128 + k];
            h0 = fmaf(xv, sw[k * 32 + u], h0);
            h1 = fmaf(xv, sw[k * 32 + u + 16], h1);
        }
        sh[r * 32 + u]      = fmaxf(h0, 0.f);
        sh[r * 32 + u + 16] = fmaxf(h1, 0.f);
    }
    __syncthreads();
    // stage W2 into sw
    for (int q = tid; q < 4096; q += 256) sw[q] = W2[q];
    __syncthreads();
    // phase 4: FFN2 + residual(y3) + LN2 -> xout (W2 from LDS)
#pragma unroll
    for (int r = 0; r < 4; ++r) {
        const int rl = wv * 4 + r;
        float a0 = b2[lane], a1 = b2[lane + 64];
#pragma unroll 8
        for (int k = 0; k < 32; ++k) {
            const float hv = sh[rl * 32 + k];
            a0 = fmaf(hv, sw[k * 128 + lane], a0);
            a1 = fmaf(hv, sw[k * 128 + lane + 64], a1);
        }
        const float v0 = a0 + y3[rl * 128 + lane];
        const float v1 = a1 + y3[rl * 128 + lane + 64];
        float sum = v0 + v1, sq = v0 * v0 + v1 * v1;
#pragma unroll
        for (int o = 32; o >= 1; o >>= 1) { sum += __shfl_xor(sum, o); sq += __shfl_xor(sq, o); }
        const float mean = sum * (1.f / 128.f);
        const float var = sq * (1.f / 128.f) - mean * mean;
        const float rs = rsqrtf(var + 1e-5f);
        const int row = r0 + rl;
        xout[(size_t)row * 128 + lane]      = (v0 - mean) * rs * g2[lane] + bb2[lane];
        xout[(size_t)row * 128 + lane + 64] = (v1 - mean) * rs * g2[lane + 64] + bb2[lane + 64];
    }
}

// ================= head =================
__global__ __launch_bounds__(256) void head_prep_kernel(
    const float* __restrict__ psi, const float* __restrict__ W_q, const float* __restrict__ W_k,
    const float* __restrict__ f_b, const float* __restrict__ hmix, const float* __restrict__ attn_a,
    float* __restrict__ mixb, float* __restrict__ alphab, float* __restrict__ bft,
    float* __restrict__ Qb, float* __restrict__ Kb)
{
    const int tid = threadIdx.x;
    const float m0 = hmix[0], m1 = hmix[1], m2 = hmix[2], m3 = hmix[3];
    const float mx = fmaxf(fmaxf(m0, m1), fmaxf(m2, m3));
    const float e0 = __expf(m0 - mx), e1 = __expf(m1 - mx), e2 = __expf(m2 - mx), e3 = __expf(m3 - mx);
    const float inv = 1.f / (e0 + e1 + e2 + e3);
    float mixv[4] = {e0 * inv, e1 * inv, e2 * inv, e3 * inv};
    if (tid < 4) mixb[tid] = mixv[tid];
    if (tid == 4) alphab[0] = sigf(attn_a[0]);
    if (tid < 128) {
        float s = 0.f;
        for (int h = 0; h < 4; ++h) {
            float t = 0.f;
            for (int d = 0; d < 10; ++d) t = fmaf(psi[tid * 10 + d], f_b[h * 10 + d], t);
            s = fmaf(mixv[h], t, s);
        }
        bft[tid] = s;
    }
    for (int idx = tid; idx < 5120; idx += 256) {
        const int n = idx / 40, rem = idx - n * 40, h = rem / 10, d = rem - h * 10;
        float q = 0.f, kk = 0.f;
        for (int d0 = 0; d0 < 10; ++d0) {
            const float pv = psi[n * 10 + d0];
            q = fmaf(pv, W_q[(d0 * 4 + h) * 10 + d], q);
            kk = fmaf(pv, W_k[(d0 * 4 + h) * 10 + d], kk);
        }
        Qb[idx] = q; Kb[idx] = kk;
    }
}

// fused qk + aeff: grid 512 (h,n), block 128 (m)
__global__ __launch_bounds__(128) void head_qkaeff_kernel(
    const float* __restrict__ psi, const float* __restrict__ psis,
    const float* __restrict__ Qb, const float* __restrict__ Kb,
    const float* __restrict__ alphab,
    float* __restrict__ Aeff, float* __restrict__ StT)
{
    __shared__ float spn[10];
    __shared__ float red[128];
    const int h = blockIdx.x >> 7, n = blockIdx.x & 127, mcol = threadIdx.x;
    if (mcol < 10) spn[mcol] = psi[n * 10 + mcol];
    __syncthreads();
    float d2 = 0.f;
#pragma unroll
    for (int d = 0; d < 10; ++d) { const float df = spn[d] - psi[mcol * 10 + d]; d2 = fmaf(df, df, d2); }
    const float gv = __expf(-psis[0] * d2);
    float qv = 0.f;
#pragma unroll
    for (int d = 0; d < 10; ++d) qv = fmaf(Qb[n * 40 + h * 10 + d], Kb[mcol * 40 + h * 10 + d], qv);
    qv *= 0.3162277660168379332f;  // 1/sqrt(10)
    float r;
    red[mcol] = gv; __syncthreads();
    for (int s = 64; s >= 1; s >>= 1) { if (mcol < s) red[mcol] = fmaxf(red[mcol], red[mcol + s]); __syncthreads(); }
    r = red[0]; __syncthreads();
    const float eg = __expf(gv - r);
    red[mcol] = eg; __syncthreads();
    for (int s = 64; s >= 1; s >>= 1) { if (mcol < s) red[mcol] += red[mcol + s]; __syncthreads(); }
    const float gsum = red[0]; __syncthreads();
    red[mcol] = qv; __syncthreads();
    for (int s = 64; s >= 1; s >>= 1) { if (mcol < s) red[mcol] = fmaxf(red[mcol], red[mcol + s]); __syncthreads(); }
    r = red[0]; __syncthreads();
    const float eq = __expf(qv - r);
    red[mcol] = eq; __syncthreads();
    for (int s = 64; s >= 1; s >>= 1) { if (mcol < s) red[mcol] += red[mcol + s]; __syncthreads(); }
    const float qsum = red[0];
    const float al = alphab[0];
    const float aeff = al * (eg / gsum) + (1.f - al) * (eq / qsum);
    Aeff[h * 16384 + n * 128 + mcol] = aeff;
    StT[((h * 4 + 1) * 128 + mcol) * 128 + n] = aeff;
    StT[((h * 4 + 0) * 128 + mcol) * 128 + n] = (mcol == n) ? 1.f : 0.f;
}

__global__ __launch_bounds__(256) void head_cheb_kernel(
    const float* __restrict__ Aeff, float* __restrict__ StT, int kk)
{
    const int h = blockIdx.x >> 6;
    const int m0 = ((blockIdx.x & 63) << 1) + (threadIdx.x >> 7);
    const int n = threadIdx.x & 127;
    const float* Ar = Aeff + h * 16384 + n * 128;
    const float* Sp = StT + ((h * 4 + kk - 1) * 128 + m0) * 128;
    float acc = 0.f;
#pragma unroll 8
    for (int p = 0; p < 128; ++p) acc = fmaf(Ar[p], Sp[p], acc);
    const float s2 = StT[((h * 4 + kk - 2) * 128 + m0) * 128 + n];
    StT[((h * 4 + kk) * 128 + m0) * 128 + n] = 2.f * acc - s2;
}

__global__ __launch_bounds__(256) void head_wf_kernel(
    const float* __restrict__ psi, const float* __restrict__ F_w, float* __restrict__ WfT)
{
    const int idx = blockIdx.x * 256 + threadIdx.x;  // 2^20
    const int n = idx & 127, l = (idx >> 7) & 511, k = (idx >> 16) & 3, h = idx >> 18;
    float acc = 0.f;
#pragma unroll
    for (int d = 0; d < 10; ++d)
        acc = fmaf(psi[n * 10 + d], F_w[((h * 10 + d) * 4 + k) * 512 + l], acc);
    WfT[idx] = acc;
}

__global__ __launch_bounds__(256) void head_v3_kernel(
    const float* __restrict__ StT, const float* __restrict__ WfT, const float* __restrict__ mixb,
    float* __restrict__ V)
{
    const int tid = threadIdx.x;
    const int lt = blockIdx.x & 63, mm = blockIdx.x >> 6;
    const int n = tid & 127, mh = tid >> 7;
    const int m = mm * 2 + mh;
    const int l0 = lt * 8;
    float sv[16];
#pragma unroll
    for (int h = 0; h < 4; ++h) {
        const float mx = mixb[h];
#pragma unroll
        for (int k = 0; k < 4; ++k)
            sv[h * 4 + k] = mx * StT[(size_t)((h * 4 + k) * 128 + m) * 128 + n];
    }
#pragma unroll
    for (int j = 0; j < 8; ++j) {
        const int l = l0 + j;
        float acc = 0.f;
#pragma unroll
        for (int hk = 0; hk < 16; ++hk)
            acc = fmaf(sv[hk], WfT[(size_t)(hk * 512 + l) * 128 + n], acc);
        V[(size_t)(l * 128 + m) * 128 + n] = acc;
    }
}

__global__ __launch_bounds__(256) void head_ctr_kernel(
    const float* __restrict__ Xf, const float* __restrict__ V, float* __restrict__ partial)
{
    __shared__ float sx[32][128];
    const int l = blockIdx.x, tid = threadIdx.x;
    const int n = tid & 127, mh = tid >> 7;
    for (int q = tid; q < 4096; q += 256) {
        const int b = q >> 7, mm = q & 127;
        sx[b][mm] = Xf[(b * 512 + l) * 128 + mm];
    }
    __syncthreads();
    float acc[32];
#pragma unroll
    for (int b = 0; b < 32; ++b) acc[b] = 0.f;
    const float* vp = V + (size_t)(l * 128 + mh * 64) * 128 + n;
    for (int mm = 0; mm < 64; ++mm) {
        const float v = vp[(size_t)mm * 128];
        const int m = mh * 64 + mm;
#pragma unroll
        for (int b = 0; b < 32; ++b) acc[b] = fmaf(sx[b][m], v, acc[b]);
    }
#pragma unroll
    for (int b = 0; b < 32; ++b)
        partial[(size_t)((l * 2 + mh) * 32 + b) * 128 + n] = acc[b];
}

__global__ __launch_bounds__(128) void head_red_kernel(
    const float* __restrict__ partial, float* __restrict__ red1)
{
    const int b = blockIdx.x >> 5, cs = blockIdx.x & 31, n = threadIdx.x;
    const float* p = partial + ((size_t)(cs * 32) * 32 + b) * 128 + n;
    float s = 0.f;
#pragma unroll 8
    for (int c = 0; c < 32; ++c) s += p[(size_t)c * 4096];
    red1[(b * 32 + cs) * 128 + n] = s;
}

__global__ __launch_bounds__(128) void head_out_kernel(
    const float* __restrict__ red1, const float* __restrict__ bft,
    const float* __restrict__ head_w, const float* __restrict__ head_b, float* __restrict__ out)
{
    __shared__ float red[128];
    const int b = blockIdx.x, n = threadIdx.x;
    float s = bft[n];
#pragma unroll 8
    for (int cs = 0; cs < 32; ++cs) s += red1[(b * 32 + cs) * 128 + n];
    red[n] = s * head_w[n];
    __syncthreads();
    for (int st = 64; st >= 1; st >>= 1) { if (n < st) red[n] += red[n + st]; __syncthreads(); }
    if (n == 0) out[b] = red[0] + head_b[0];
    out[32 + b * 128 + n] = 0.f;   // log_var = zeros
}

extern "C" void kernel_launch(void* const* d_in, const int* in_sizes, int n_in,
                              void* d_out, int out_size, void* d_ws, size_t ws_size,
                              hipStream_t stream) {
    const float* x_in    = (const float*)d_in[0];
    const float* in_w    = (const float*)d_in[1];
    const float* conv_w  = (const float*)d_in[2];
    const float* conv_b  = (const float*)d_in[3];
    const float* xproj_w = (const float*)d_in[4];
    const float* dt_w    = (const float*)d_in[5];
    const float* dt_b    = (const float*)d_in[6];
    const float* Alog    = (const float*)d_in[7];
    const float* Dp      = (const float*)d_in[8];
    const float* out_w   = (const float*)d_in[9];
    const float* ln1_g   = (const float*)d_in[10];
    const float* ln1_b   = (const float*)d_in[11];
    const float* ln2_g   = (const float*)d_in[12];
    const float* ln2_b   = (const float*)d_in[13];
    const float* ffn_w1  = (const float*)d_in[14];
    const float* ffn_b1  = (const float*)d_in[15];
    const float* ffn_w2  = (const float*)d_in[16];
    const float* ffn_b2  = (const float*)d_in[17];
    const float* psi_emb = (const float*)d_in[18];
    const float* psi_s   = (const float*)d_in[19];
    const float* W_q     = (const float*)d_in[20];
    const float* W_k     = (const float*)d_in[21];
    const float* attn_a  = (const float*)d_in[22];
    const float* F_w     = (const float*)d_in[23];
    const float* f_b     = (const float*)d_in[24];
    const float* hmix    = (const float*)d_in[25];
    const float* head_w  = (const float*)d_in[26];
    const float* head_b  = (const float*)d_in[27];
    float* ws = (float*)d_ws;
    float* outp = (float*)d_out;

    for (int i = 0; i < 3; ++i) {
        const float* xcur = (i == 0) ? x_in : (ws + OFF_X);
        const int mF = 2 * i, mB = 2 * i + 1;
        gemm_in2_kernel<<<512, 256, 0, stream>>>(
            xcur, in_w + mF * 16384, in_w + mB * 16384, ws + OFF_XZF, ws + OFF_XZB);
        prep3_kernel<<<2048, 256, 0, stream>>>(
            ws + OFF_XZF, ws + OFF_XZB, conv_w, conv_b, xproj_w, dt_w, dt_b, i,
            ws + OFF_XPF, ws + OFF_XPB,
            (unsigned int*)(ws + OFF_XBCF), (unsigned int*)(ws + OFF_XBCB),
            ws + OFF_PKF, ws + OFF_PKB);
        scan7_kernel<<<1024, 256, 0, stream>>>(
            (const unsigned int*)(ws + OFF_XBCF), (const unsigned int*)(ws + OFF_XBCB),
            ws + OFF_PKF, ws + OFF_PKB,
            Alog + mF * 4096, Alog + mB * 4096, ws + OFF_YSF, ws + OFF_YSB);
        opfn_kernel<<<1024, 256, 0, stream>>>(
            ws + OFF_YSF, ws + OFF_YSB, ws + OFF_XPF, ws + OFF_XPB, ws + OFF_XZF, ws + OFF_XZB,
            Dp, i, xcur, out_w,
            ffn_w1 + i * 4096, ffn_b1 + i * 32, ffn_w2 + i * 4096, ffn_b2 + i * 128,
            ln1_g + i * 128, ln1_b + i * 128, ln2_g + i * 128, ln2_b + i * 128,
            ws + OFF_X);
    }
    // head
    head_prep_kernel<<<1, 256, 0, stream>>>(
        psi_emb, W_q, W_k, f_b, hmix, attn_a,
        ws + OFF_MIX, ws + OFF_ALPH, ws + OFF_BFT, ws + OFF_QB, ws + OFF_KB);
    head_qkaeff_kernel<<<512, 128, 0, stream>>>(
        psi_emb, psi_s, ws + OFF_QB, ws + OFF_KB, ws + OFF_ALPH, ws + OFF_AEFF, ws + OFF_STT);
    head_cheb_kernel<<<256, 256, 0, stream>>>(ws + OFF_AEFF, ws + OFF_STT, 2);
    head_cheb_kernel<<<256, 256, 0, stream>>>(ws + OFF_AEFF, ws + OFF_STT, 3);
    head_wf_kernel<<<4096, 256, 0, stream>>>(psi_emb, F_w, ws + OFF_WFT);
    head_v3_kernel<<<4096, 256, 0, stream>>>(ws + OFF_STT, ws + OFF_WFT, ws + OFF_MIX, ws + OFF_V);
    head_ctr_kernel<<<512, 256, 0, stream>>>(ws + OFF_X, ws + OFF_V, ws + OFF_PART);
    head_red_kernel<<<1024, 128, 0, stream>>>(ws + OFF_PART, ws + OFF_RED1);
    head_out_kernel<<<32, 128, 0, stream>>>(
        ws + OFF_RED1, ws + OFF_BFT, head_w, head_b, outp);
}

// Round 8
// 519.670 us; speedup vs baseline: 1.8685x; 1.1327x over previous
//
#include <hip/hip_runtime.h>
#include <hip/hip_bf16.h>

// MAMBA_BayesMAGAC: B=32, L=512, D=128, E=64, HS=64, DTR=4, U=32, R=3, K=3, DE=10, NH=4
// Round 8: prep4 (4-row weight amortization, float4 staging), float4 staging in all
// GEMM-ish kernels, head_v4 (n4-vectorized). scan7 unchanged (near roofline).

#define B_ 32
#define L_ 512
#define D_ 128
#define E_ 64
#define HS_ 64

// ---- workspace offsets (floats) ----
#define OFF_X     0u          // 2,097,152  x [b][l][128]
#define OFF_XZF   2097152u    // 2,097,152  xz fwd [b][l][128]
#define OFF_XZB   4194304u
#define OFF_XPF   6291456u    // 1,048,576  xp [b][l][64]
#define OFF_XPB   7340032u
#define OFF_PKF   8388608u    // 2,097,152  (dl,du) [b][l][64][2]
#define OFF_PKB   10485760u
#define OFF_XBCF  12582912u   // 1,048,576 u32: packed bf16 (C<<16|B) [b][l][64]
#define OFF_XBCB  14680064u
#define OFF_YSF   16777216u   // 1,048,576  scan y [b][e][l]
#define OFF_YSB   17825792u   // end 18,874,368 floats = 75.5 MB
// head phase (only OFF_X live):
#define OFF_V     2097152u    // 8,388,608  V [l][m][n]
#define OFF_WFT   10485760u   // 1,048,576  Wf [h][k][l][n]
#define OFF_STT   11534336u   // 262,144    S^T [h][k][m][n]
#define OFF_AEFF  11796480u   // 65,536
#define OFF_QB    11943936u   // 5,120
#define OFF_KB    11949056u   // 5,120
#define OFF_MIX   11954176u   // 4
#define OFF_ALPH  11954180u   // 1
#define OFF_BFT   11954184u   // 128
#define OFF_PART  12582912u   // 4,194,304  partial [1024][32][128]
#define OFF_RED1  16777216u   // 131,072    red1 [32][32][128]

__device__ __forceinline__ float sigf(float x) { return 1.f / (1.f + __expf(-x)); }
__device__ __forceinline__ unsigned int bf16r(float x) {
    unsigned int u = __float_as_uint(x);
    return (u + 0x7fffu + ((u >> 16) & 1u)) >> 16;   // RNE to bf16, return low 16
}

// ---------------- in-projection: xz = x @ in_w (both dirs), 32 rows/block ----------------
__global__ __launch_bounds__(256) void gemm_in2_kernel(
    const float* __restrict__ X, const float* __restrict__ WF, const float* __restrict__ WB,
    float* __restrict__ xzF, float* __restrict__ xzB)
{
    __shared__ float sxT[128][36];    // transposed x tile, padded
    __shared__ float sw[2][16][128];
    const int tid = threadIdx.x;
    const int r0 = blockIdx.x * 32;
    for (int q = tid; q < 1024; q += 256) {
        const int r = q >> 5, k4 = q & 31;
        const float4 v = *(const float4*)&X[(size_t)(r0 + r) * 128 + k4 * 4];
        sxT[k4 * 4 + 0][r] = v.x; sxT[k4 * 4 + 1][r] = v.y;
        sxT[k4 * 4 + 2][r] = v.z; sxT[k4 * 4 + 3][r] = v.w;
    }
    const int wv = tid >> 6, lane = tid & 63;
    const int d = wv >> 1, ch = wv & 1;
    const int r4 = lane >> 4, c16 = lane & 15;
    float4 acc[8];
#pragma unroll
    for (int j = 0; j < 8; ++j) acc[j] = float4{0.f, 0.f, 0.f, 0.f};
    for (int ko = 0; ko < 128; ko += 16) {
        __syncthreads();
        for (int q = tid; q < 1024; q += 256) {
            const int dd = q >> 9, kk = (q >> 5) & 15, c4 = q & 31;
            *(float4*)&sw[dd][kk][c4 * 4] =
                *(const float4*)&((dd ? WB : WF)[(ko + kk) * 128 + c4 * 4]);
        }
        __syncthreads();
#pragma unroll
        for (int kk = 0; kk < 16; ++kk) {
            const float4 w4 = *(const float4*)&sw[d][kk][ch * 64 + c16 * 4];
            const float4 xa = *(const float4*)&sxT[ko + kk][r4 * 8];
            const float4 xb = *(const float4*)&sxT[ko + kk][r4 * 8 + 4];
            const float xs[8] = {xa.x, xa.y, xa.z, xa.w, xb.x, xb.y, xb.z, xb.w};
#pragma unroll
            for (int j = 0; j < 8; ++j) {
                acc[j].x = fmaf(xs[j], w4.x, acc[j].x);
                acc[j].y = fmaf(xs[j], w4.y, acc[j].y);
                acc[j].z = fmaf(xs[j], w4.z, acc[j].z);
                acc[j].w = fmaf(xs[j], w4.w, acc[j].w);
            }
        }
    }
    float* xz = d ? xzB : xzF;
#pragma unroll
    for (int j = 0; j < 8; ++j) {
        *(float4*)&xz[(r0 + r4 * 8 + j) * 128 + ch * 64 + c16 * 4] = acc[j];
    }
}

// ------------- conv + silu + xproj + delta, 4-row amortized. grid 2048 (16 rows/block) -------
__global__ __launch_bounds__(256) void prep4_kernel(
    const float* __restrict__ xzF_, const float* __restrict__ xzB_,
    const float* __restrict__ conv_w, const float* __restrict__ conv_b,
    const float* __restrict__ xproj_w, const float* __restrict__ dt_w,
    const float* __restrict__ dt_b, int layer,
    float* __restrict__ xpF_, float* __restrict__ xpB_,
    unsigned int* __restrict__ xbcF_, unsigned int* __restrict__ xbcB_,
    float* __restrict__ pkF_, float* __restrict__ pkB_)
{
    __shared__ float sW[8448];
    __shared__ float sxp4[4][64][4];   // [wv][k][it]
    __shared__ float sdl4[4][4][4];    // [wv][it][r]
    const int tid = threadIdx.x, wv = tid >> 6, lane = tid & 63;
    const int dir = (int)(blockIdx.x >= 1024);        // block-uniform
    const int r0 = (blockIdx.x & 1023) * 16;          // 16 rows, same b
    const int b = r0 >> 9;
    const int m = layer * 2 + dir;
    const float* Wg = xproj_w + m * 8448;
    for (int q = tid; q < 2112; q += 256) ((float4*)sW)[q] = ((const float4*)Wg)[q];
    const float* xz = dir ? xzB_ : xzF_;
    float* xp  = dir ? xpB_  : xpF_;
    unsigned int* xbc = dir ? xbcB_ : xbcF_;
    float* pkx = dir ? pkB_  : pkF_;
    const float* cw = conv_w + m * 192 + lane * 3;
    const float cw0 = cw[0], cw1 = cw[1], cw2 = cw[2];
    const float cb  = conv_b[m * 64 + lane];
    const float dtb = dt_b[m * 64 + lane];
    const float* dwp = dt_w + m * 256;
    const float dw0 = dwp[lane], dw1 = dwp[64 + lane], dw2 = dwp[128 + lane], dw3 = dwp[192 + lane];
    // conv + silu for the wave's 4 rows
    float uu[4];
#pragma unroll
    for (int it = 0; it < 4; ++it) {
        const int row = r0 + wv * 4 + it;
        const int l = row & 511;
        const int l1 = dir ? l + 1 : l - 1;
        const int l2 = dir ? l + 2 : l - 2;
        float acc = cb;
        const float x0 = xz[(size_t)row * 128 + lane];
        const float x1 = (l1 >= 0 && l1 < 512) ? xz[(size_t)(b * 512 + l1) * 128 + lane] : 0.f;
        const float x2 = (l2 >= 0 && l2 < 512) ? xz[(size_t)(b * 512 + l2) * 128 + lane] : 0.f;
        acc += cw0 * x2 + cw1 * x1 + cw2 * x0;
        const float u = acc * sigf(acc);   // silu
        xp[row * 64 + lane] = u;
        uu[it] = u;
    }
    *(float4*)&sxp4[wv][lane][0] = float4{uu[0], uu[1], uu[2], uu[3]};
    __syncthreads();   // sW ready
    // xproj: read each weight once, fma into 4 row-accumulators
    const int jdt = lane & 3;
    float aB[4] = {0.f, 0.f, 0.f, 0.f};
    float aC[4] = {0.f, 0.f, 0.f, 0.f};
    float adt[4] = {0.f, 0.f, 0.f, 0.f};
#pragma unroll 4
    for (int k = 0; k < 64; ++k) {
        const float wB = sW[k * 132 + 4 + lane];
        const float wC = sW[k * 132 + 68 + lane];
        const float wd = sW[k * 132 + jdt];
        const float4 xv = *(const float4*)&sxp4[wv][k][0];
        aB[0] = fmaf(xv.x, wB, aB[0]); aC[0] = fmaf(xv.x, wC, aC[0]); adt[0] = fmaf(xv.x, wd, adt[0]);
        aB[1] = fmaf(xv.y, wB, aB[1]); aC[1] = fmaf(xv.y, wC, aC[1]); adt[1] = fmaf(xv.y, wd, adt[1]);
        aB[2] = fmaf(xv.z, wB, aB[2]); aC[2] = fmaf(xv.z, wC, aC[2]); adt[2] = fmaf(xv.z, wd, adt[2]);
        aB[3] = fmaf(xv.w, wB, aB[3]); aC[3] = fmaf(xv.w, wC, aC[3]); adt[3] = fmaf(xv.w, wd, adt[3]);
    }
#pragma unroll
    for (int it = 0; it < 4; ++it) {
        const int row = r0 + wv * 4 + it;
        xbc[row * 64 + lane] = (bf16r(aC[it]) << 16) | bf16r(aB[it]);
        if (lane < 4) sdl4[wv][it][lane] = adt[it];   // lane == jdt here
    }
    // sdl4 is wave-private; compiler-inserted lgkmcnt orders the RAW within the wave
#pragma unroll
    for (int it = 0; it < 4; ++it) {
        const int row = r0 + wv * 4 + it;
        float dpre = fmaf(sdl4[wv][it][0], dw0, dtb);
        dpre = fmaf(sdl4[wv][it][1], dw1, dpre);
        dpre = fmaf(sdl4[wv][it][2], dw2, dpre);
        dpre = fmaf(sdl4[wv][it][3], dw3, dpre);
        const float dlt = (dpre > 20.f) ? dpre : log1pf(__expf(dpre));
        ((float2*)pkx)[row * 64 + lane] = float2{dlt, dlt * uu[it]};
    }
}

// ------------- selective scan v7. grid 1024, block 256, packed bf16 B/C -------------
__global__ __launch_bounds__(256, 4) void scan7_kernel(
    const unsigned int* __restrict__ xbcF, const unsigned int* __restrict__ xbcB,
    const float* __restrict__ pkF, const float* __restrict__ pkB,
    const float* __restrict__ AlogF, const float* __restrict__ AlogB,
    float* __restrict__ ysF, float* __restrict__ ysB)
{
    __shared__ unsigned int sbc[2][1024]; // 8 KB: 16 slots x 64 packed (C<<16|B)
    __shared__ float spk[2][4][16][2];    // 1 KB
    __shared__ float ytile[4][16][68];    // 17.4 KB
    const int tid = threadIdx.x, wv = tid >> 6, lane = tid & 63;
    const int bx = blockIdx.x;
    const int db = bx & 63;               // (dir,b) in low bits -> same XCD for all e-quads
    const int dir = db >> 5;
    const int b   = db & 31;
    const int e0  = (bx >> 6) * 4;
    const int e   = e0 + wv;
    const unsigned int* xbc = dir ? xbcB : xbcF;
    const float* pk  = dir ? pkB  : pkF;
    const float* Aw  = dir ? AlogB : AlogF;
    float* ys = dir ? ysB : ysF;
    const float a = -__expf(Aw[e * 64 + lane]);
    float s = 0.f;
    float* yrow = ys + (size_t)(b * 64 + e) * 512;

    const int psl = tid & 15, pw_ = tid >> 4;   // tid<64: pk staging coords

#define STG_LOAD(RS)                                                              \
    {                                                                             \
        nb = *(const uint4*)(xbc + (size_t)(RS) * 64 + tid * 4);                  \
        if (tid < 64)                                                             \
            npp = *(const float2*)(pk + (size_t)((RS) + psl) * 128 + (e0 + pw_) * 2); \
    }
#define STG_WRITE(BUF)                                                            \
    {                                                                             \
        *(uint4*)(&sbc[BUF][tid * 4]) = nb;                                       \
        if (tid < 64) *(float2*)(&spk[BUF][pw_][psl][0]) = npp;                   \
    }

#define SCAN16(REV)                                                               \
    {                                                                             \
        const unsigned int* bc = &sbc[cur][0];                                    \
        const float* pq = &spk[cur][wv][0][0];                                    \
        _Pragma("unroll")                                                         \
        for (int j = 0; j < 8; ++j) {                                             \
            const int pj = (REV) ? 7 - j : j;                                     \
            const float4 pk4 = *(const float4*)(pq + pj * 4);                     \
            const int sA = (REV) ? 15 - 2 * j : 2 * j;                            \
            const int sB = (REV) ? 14 - 2 * j : 2 * j + 1;                        \
            const float dlA = (REV) ? pk4.z : pk4.x;                              \
            const float duA = (REV) ? pk4.w : pk4.y;                              \
            const float dlB = (REV) ? pk4.x : pk4.z;                              \
            const float duB = (REV) ? pk4.y : pk4.w;                              \
            const unsigned int bA = bc[sA * 64 + lane];                           \
            const float BnA = __uint_as_float(bA << 16);                          \
            const float CnA = __uint_as_float(bA & 0xffff0000u);                  \
            s = fmaf(__expf(dlA * a), s, duA * BnA);                              \
            ytile[wv][2 * j][lane] = s * CnA;                                     \
            const unsigned int bB = bc[sB * 64 + lane];                           \
            const float BnB = __uint_as_float(bB << 16);                          \
            const float CnB = __uint_as_float(bB & 0xffff0000u);                  \
            s = fmaf(__expf(dlB * a), s, duB * BnB);                              \
            ytile[wv][2 * j + 1][lane] = s * CnB;                                 \
        }                                                                         \
    }

    // prologue: stage tile 0
    {
        uint4 nb; float2 npp;
        const int rs0 = b * 512 + (dir ? 496 : 0);
        STG_LOAD(rs0);
        STG_WRITE(0);
    }
    __syncthreads();

    int cur = 0;
    const int rr = lane & 15, sg = lane >> 4;
    for (int t = 0; t < 32; ++t) {
        uint4 nb; float2 npp;
        const bool more = (t + 1) < 32;
        if (more) {
            const int rs = b * 512 + (dir ? (496 - (t + 1) * 16) : ((t + 1) * 16));
            STG_LOAD(rs);
        }
        if (dir == 0) { SCAN16(0) } else { SCAN16(1) }
        // per-wave reduce of own ytile (wave-private)
        {
            const float* yt = &ytile[wv][rr][sg * 16];
            const float4 A0 = *(const float4*)yt;
            const float4 A1 = *(const float4*)(yt + 4);
            const float4 A2 = *(const float4*)(yt + 8);
            const float4 A3 = *(const float4*)(yt + 12);
            float p = ((A0.x + A0.y) + (A0.z + A0.w)) + ((A1.x + A1.y) + (A1.z + A1.w))
                    + ((A2.x + A2.y) + (A2.z + A2.w)) + ((A3.x + A3.y) + (A3.z + A3.w));
            p += __shfl_xor(p, 16);
            p += __shfl_xor(p, 32);
            if (lane < 16) {
                const int lg = dir ? (511 - (t * 16 + rr)) : (t * 16 + rr);
                yrow[lg] = p;
            }
        }
        if (more) STG_WRITE(cur ^ 1);
        __syncthreads();
        cur ^= 1;
    }
#undef STG_LOAD
#undef STG_WRITE
#undef SCAN16
}

// ------------- opfn: gate + out-proj + LN1 + FFN + LN2 fused. grid 1024 (16 rows), block 256 --
__global__ __launch_bounds__(256) void opfn_kernel(
    const float* __restrict__ ysF, const float* __restrict__ ysB,
    const float* __restrict__ xpF, const float* __restrict__ xpB,
    const float* __restrict__ xzF, const float* __restrict__ xzB,
    const float* __restrict__ Dp, int layer,
    const float* __restrict__ Xc, const float* __restrict__ out_w,
    const float* __restrict__ W1, const float* __restrict__ b1,
    const float* __restrict__ W2, const float* __restrict__ b2,
    const float* __restrict__ g1, const float* __restrict__ bb1,
    const float* __restrict__ g2, const float* __restrict__ bb2,
    float* __restrict__ xout)
{
    __shared__ float smem[8832];
    float* syt = smem;            // [2][64][17] = 2176 (dead after phase1)
    float* y3  = smem;            // [16][128] = 2048 (over syt)
    float* sy  = smem + 2176;     // [16][128] = 2048
    float* sw  = smem + 4224;     // [32][128] = 4096 (GEMM W; later W1, then W2)
    float* sh  = smem + 8320;     // [16][32]  = 512
    const int tid = threadIdx.x;
    const int r0 = blockIdx.x * 16;
    const int b = r0 >> 9, l0 = r0 & 511;

    // phase 0: load ys (both dirs) transposed into syt (float4 reads)
    for (int q = tid; q < 512; q += 256) {
        const int d = q >> 8, ee = (q >> 2) & 63, rq = q & 3;
        const float* ysp = d ? ysB : ysF;
        const float4 v = *(const float4*)&ysp[(size_t)(b * 64 + ee) * 512 + l0 + rq * 4];
        float* dst = &syt[(d * 64 + ee) * 17 + rq * 4];
        dst[0] = v.x; dst[1] = v.y; dst[2] = v.z; dst[3] = v.w;
    }
    __syncthreads();
    // phase 1: gate -> sy[r][c]
    for (int q = tid; q < 2048; q += 256) {
        const int r = q >> 7, c = q & 127;
        const int d = c >> 6, ee = c & 63;
        const int row = r0 + r;
        const float dv  = Dp[(layer * 2 + d) * 64 + ee];
        const float u   = (d ? xpB : xpF)[(size_t)row * 64 + ee];
        const float res = (d ? xzB : xzF)[(size_t)row * 128 + 64 + ee];
        sy[r * 128 + c] = (syt[(d * 64 + ee) * 17 + r] + u * dv) * sigf(res);
    }
    // phase 2: out-proj GEMM (K=128) + residual + LN1 -> y3 (LDS)
    const int wv = tid >> 6, lane = tid & 63;
    const float* WFp = out_w + (layer * 2) * 8192;
    const float* WBp = out_w + (layer * 2 + 1) * 8192;
    float acc[4][2];
#pragma unroll
    for (int r = 0; r < 4; ++r) { acc[r][0] = 0.f; acc[r][1] = 0.f; }
    for (int ko = 0; ko < 128; ko += 32) {
        __syncthreads();   // first iter: also covers sy writes
        for (int q = tid; q < 1024; q += 256) {
            const int kk = q >> 5, c4 = q & 31;
            const int kg = ko + kk;
            *(float4*)&sw[kk * 128 + c4 * 4] = (kg < 64)
                ? *(const float4*)&WFp[kg * 128 + c4 * 4]
                : *(const float4*)&WBp[(kg - 64) * 128 + c4 * 4];
        }
        __syncthreads();
#define OPSTEP(COMP, J)                                                           \
        {                                                                         \
            const float w0 = sw[(kk + (J)) * 128 + lane];                         \
            const float w1 = sw[(kk + (J)) * 128 + lane + 64];                    \
            acc[0][0] = fmaf(y40.COMP, w0, acc[0][0]);                            \
            acc[0][1] = fmaf(y40.COMP, w1, acc[0][1]);                            \
            acc[1][0] = fmaf(y41.COMP, w0, acc[1][0]);                            \
            acc[1][1] = fmaf(y41.COMP, w1, acc[1][1]);                            \
            acc[2][0] = fmaf(y42.COMP, w0, acc[2][0]);                            \
            acc[2][1] = fmaf(y42.COMP, w1, acc[2][1]);                            \
            acc[3][0] = fmaf(y43.COMP, w0, acc[3][0]);                            \
            acc[3][1] = fmaf(y43.COMP, w1, acc[3][1]);                            \
        }
#pragma unroll
        for (int kk = 0; kk < 32; kk += 4) {
            const float4 y40 = *(const float4*)&sy[(wv * 4 + 0) * 128 + ko + kk];
            const float4 y41 = *(const float4*)&sy[(wv * 4 + 1) * 128 + ko + kk];
            const float4 y42 = *(const float4*)&sy[(wv * 4 + 2) * 128 + ko + kk];
            const float4 y43 = *(const float4*)&sy[(wv * 4 + 3) * 128 + ko + kk];
            OPSTEP(x, 0) OPSTEP(y, 1) OPSTEP(z, 2) OPSTEP(w, 3)
        }
#undef OPSTEP
    }
    __syncthreads();       // sy/syt dead; sw free
    // stage W1 into sw (float4) + write y3
    for (int q = tid; q < 1024; q += 256) ((float4*)sw)[q] = ((const float4*)W1)[q];
#pragma unroll
    for (int r = 0; r < 4; ++r) {
        const int rl = wv * 4 + r;
        const int row = r0 + rl;
        float v0 = acc[r][0] + Xc[(size_t)row * 128 + lane];
        float v1 = acc[r][1] + Xc[(size_t)row * 128 + lane + 64];
        float sum = v0 + v1, sq = v0 * v0 + v1 * v1;
#pragma unroll
        for (int o = 32; o >= 1; o >>= 1) { sum += __shfl_xor(sum, o); sq += __shfl_xor(sq, o); }
        const float mean = sum * (1.f / 128.f);
        const float var = sq * (1.f / 128.f) - mean * mean;
        const float rs = rsqrtf(var + 1e-5f);
        y3[rl * 128 + lane]      = (v0 - mean) * rs * g1[lane] + bb1[lane];
        y3[rl * 128 + lane + 64] = (v1 - mean) * rs * g1[lane + 64] + bb1[lane + 64];
    }
    __syncthreads();
    // phase 3: hid = relu(y3 @ W1 + b1) -> sh  (W1 from LDS)
    {
        const int r = tid >> 4, u = tid & 15;
        float h0 = b1[u], h1 = b1[u + 16];
#pragma unroll 8
        for (int k = 0; k < 128; ++k) {
            const float xv = y3[r * 128 + k];
            h0 = fmaf(xv, sw[k * 32 + u], h0);
            h1 = fmaf(xv, sw[k * 32 + u + 16], h1);
        }
        sh[r * 32 + u]      = fmaxf(h0, 0.f);
        sh[r * 32 + u + 16] = fmaxf(h1, 0.f);
    }
    __syncthreads();
    // stage W2 into sw (float4)
    for (int q = tid; q < 1024; q += 256) ((float4*)sw)[q] = ((const float4*)W2)[q];
    __syncthreads();
    // phase 4: FFN2 + residual(y3) + LN2 -> xout (W2 from LDS)
#pragma unroll
    for (int r = 0; r < 4; ++r) {
        const int rl = wv * 4 + r;
        float a0 = b2[lane], a1 = b2[lane + 64];
#pragma unroll 8
        for (int k = 0; k < 32; ++k) {
            const float hv = sh[rl * 32 + k];
            a0 = fmaf(hv, sw[k * 128 + lane], a0);
            a1 = fmaf(hv, sw[k * 128 + lane + 64], a1);
        }
        const float v0 = a0 + y3[rl * 128 + lane];
        const float v1 = a1 + y3[rl * 128 + lane + 64];
        float sum = v0 + v1, sq = v0 * v0 + v1 * v1;
#pragma unroll
        for (int o = 32; o >= 1; o >>= 1) { sum += __shfl_xor(sum, o); sq += __shfl_xor(sq, o); }
        const float mean = sum * (1.f / 128.f);
        const float var = sq * (1.f / 128.f) - mean * mean;
        const float rs = rsqrtf(var + 1e-5f);
        const int row = r0 + rl;
        xout[(size_t)row * 128 + lane]      = (v0 - mean) * rs * g2[lane] + bb2[lane];
        xout[(size_t)row * 128 + lane + 64] = (v1 - mean) * rs * g2[lane + 64] + bb2[lane + 64];
    }
}

// ================= head =================
__global__ __launch_bounds__(256) void head_prep_kernel(
    const float* __restrict__ psi, const float* __restrict__ W_q, const float* __restrict__ W_k,
    const float* __restrict__ f_b, const float* __restrict__ hmix, const float* __restrict__ attn_a,
    float* __restrict__ mixb, float* __restrict__ alphab, float* __restrict__ bft,
    float* __restrict__ Qb, float* __restrict__ Kb)
{
    const int tid = threadIdx.x;
    const float m0 = hmix[0], m1 = hmix[1], m2 = hmix[2], m3 = hmix[3];
    const float mx = fmaxf(fmaxf(m0, m1), fmaxf(m2, m3));
    const float e0 = __expf(m0 - mx), e1 = __expf(m1 - mx), e2 = __expf(m2 - mx), e3 = __expf(m3 - mx);
    const float inv = 1.f / (e0 + e1 + e2 + e3);
    float mixv[4] = {e0 * inv, e1 * inv, e2 * inv, e3 * inv};
    if (tid < 4) mixb[tid] = mixv[tid];
    if (tid == 4) alphab[0] = sigf(attn_a[0]);
    if (tid < 128) {
        float s = 0.f;
        for (int h = 0; h < 4; ++h) {
            float t = 0.f;
            for (int d = 0; d < 10; ++d) t = fmaf(psi[tid * 10 + d], f_b[h * 10 + d], t);
            s = fmaf(mixv[h], t, s);
        }
        bft[tid] = s;
    }
    for (int idx = tid; idx < 5120; idx += 256) {
        const int n = idx / 40, rem = idx - n * 40, h = rem / 10, d = rem - h * 10;
        float q = 0.f, kk = 0.f;
        for (int d0 = 0; d0 < 10; ++d0) {
            const float pv = psi[n * 10 + d0];
            q = fmaf(pv, W_q[(d0 * 4 + h) * 10 + d], q);
            kk = fmaf(pv, W_k[(d0 * 4 + h) * 10 + d], kk);
        }
        Qb[idx] = q; Kb[idx] = kk;
    }
}

// fused qk + aeff: grid 512 (h,n), block 128 (m)
__global__ __launch_bounds__(128) void head_qkaeff_kernel(
    const float* __restrict__ psi, const float* __restrict__ psis,
    const float* __restrict__ Qb, const float* __restrict__ Kb,
    const float* __restrict__ alphab,
    float* __restrict__ Aeff, float* __restrict__ StT)
{
    __shared__ float spn[10];
    __shared__ float red[128];
    const int h = blockIdx.x >> 7, n = blockIdx.x & 127, mcol = threadIdx.x;
    if (mcol < 10) spn[mcol] = psi[n * 10 + mcol];
    __syncthreads();
    float d2 = 0.f;
#pragma unroll
    for (int d = 0; d < 10; ++d) { const float df = spn[d] - psi[mcol * 10 + d]; d2 = fmaf(df, df, d2); }
    const float gv = __expf(-psis[0] * d2);
    float qv = 0.f;
#pragma unroll
    for (int d = 0; d < 10; ++d) qv = fmaf(Qb[n * 40 + h * 10 + d], Kb[mcol * 40 + h * 10 + d], qv);
    qv *= 0.3162277660168379332f;  // 1/sqrt(10)
    float r;
    red[mcol] = gv; __syncthreads();
    for (int s = 64; s >= 1; s >>= 1) { if (mcol < s) red[mcol] = fmaxf(red[mcol], red[mcol + s]); __syncthreads(); }
    r = red[0]; __syncthreads();
    const float eg = __expf(gv - r);
    red[mcol] = eg; __syncthreads();
    for (int s = 64; s >= 1; s >>= 1) { if (mcol < s) red[mcol] += red[mcol + s]; __syncthreads(); }
    const float gsum = red[0]; __syncthreads();
    red[mcol] = qv; __syncthreads();
    for (int s = 64; s >= 1; s >>= 1) { if (mcol < s) red[mcol] = fmaxf(red[mcol], red[mcol + s]); __syncthreads(); }
    r = red[0]; __syncthreads();
    const float eq = __expf(qv - r);
    red[mcol] = eq; __syncthreads();
    for (int s = 64; s >= 1; s >>= 1) { if (mcol < s) red[mcol] += red[mcol + s]; __syncthreads(); }
    const float qsum = red[0];
    const float al = alphab[0];
    const float aeff = al * (eg / gsum) + (1.f - al) * (eq / qsum);
    Aeff[h * 16384 + n * 128 + mcol] = aeff;
    StT[((h * 4 + 1) * 128 + mcol) * 128 + n] = aeff;
    StT[((h * 4 + 0) * 128 + mcol) * 128 + n] = (mcol == n) ? 1.f : 0.f;
}

__global__ __launch_bounds__(256) void head_cheb_kernel(
    const float* __restrict__ Aeff, float* __restrict__ StT, int kk)
{
    const int h = blockIdx.x >> 6;
    const int m0 = ((blockIdx.x & 63) << 1) + (threadIdx.x >> 7);
    const int n = threadIdx.x & 127;
    const float* Ar = Aeff + h * 16384 + n * 128;
    const float* Sp = StT + ((h * 4 + kk - 1) * 128 + m0) * 128;
    float acc = 0.f;
#pragma unroll 8
    for (int p = 0; p < 128; ++p) acc = fmaf(Ar[p], Sp[p], acc);
    const float s2 = StT[((h * 4 + kk - 2) * 128 + m0) * 128 + n];
    StT[((h * 4 + kk) * 128 + m0) * 128 + n] = 2.f * acc - s2;
}

__global__ __launch_bounds__(256) void head_wf_kernel(
    const float* __restrict__ psi, const float* __restrict__ F_w, float* __restrict__ WfT)
{
    const int idx = blockIdx.x * 256 + threadIdx.x;  // 2^20
    const int n = idx & 127, l = (idx >> 7) & 511, k = (idx >> 16) & 3, h = idx >> 18;
    float acc = 0.f;
#pragma unroll
    for (int d = 0; d < 10; ++d)
        acc = fmaf(psi[n * 10 + d], F_w[((h * 10 + d) * 4 + k) * 512 + l], acc);
    WfT[idx] = acc;
}

// head_v4: thread owns (m, n0..n0+3) x 8 l's; all loads/stores float4. grid 1024, block 256.
__global__ __launch_bounds__(256) void head_v4_kernel(
    const float* __restrict__ StT, const float* __restrict__ WfT, const float* __restrict__ mixb,
    float* __restrict__ V)
{
    const int tid = threadIdx.x;
    const int lt = blockIdx.x & 63, mm = blockIdx.x >> 6;   // lt 0..63, mm 0..15
    const int n4 = tid & 31, mh = tid >> 5;                 // mh 0..7
    const int m = mm * 8 + mh;
    const int l0 = lt * 8, n0 = n4 * 4;
    float4 sv[16];
#pragma unroll
    for (int h = 0; h < 4; ++h) {
        const float mx = mixb[h];
#pragma unroll
        for (int k = 0; k < 4; ++k) {
            const float4 v = *(const float4*)&StT[(size_t)((h * 4 + k) * 128 + m) * 128 + n0];
            sv[h * 4 + k] = float4{v.x * mx, v.y * mx, v.z * mx, v.w * mx};
        }
    }
#pragma unroll
    for (int j = 0; j < 8; ++j) {
        const int l = l0 + j;
        float4 acc = {0.f, 0.f, 0.f, 0.f};
#pragma unroll
        for (int hk = 0; hk < 16; ++hk) {
            const float4 w = *(const float4*)&WfT[(size_t)(hk * 512 + l) * 128 + n0];
            acc.x = fmaf(sv[hk].x, w.x, acc.x);
            acc.y = fmaf(sv[hk].y, w.y, acc.y);
            acc.z = fmaf(sv[hk].z, w.z, acc.z);
            acc.w = fmaf(sv[hk].w, w.w, acc.w);
        }
        *(float4*)&V[(size_t)(l * 128 + m) * 128 + n0] = acc;
    }
}

__global__ __launch_bounds__(256) void head_ctr_kernel(
    const float* __restrict__ Xf, const float* __restrict__ V, float* __restrict__ partial)
{
    __shared__ float sx[32][128];
    const int l = blockIdx.x, tid = threadIdx.x;
    const int n = tid & 127, mh = tid >> 7;
    for (int q = tid; q < 1024; q += 256) {
        const int b = q >> 5, m4 = q & 31;
        *(float4*)&sx[b][m4 * 4] = *(const float4*)&Xf[(size_t)(b * 512 + l) * 128 + m4 * 4];
    }
    __syncthreads();
    float acc[32];
#pragma unroll
    for (int b = 0; b < 32; ++b) acc[b] = 0.f;
    const float* vp = V + (size_t)(l * 128 + mh * 64) * 128 + n;
    for (int mm = 0; mm < 64; ++mm) {
        const float v = vp[(size_t)mm * 128];
        const int m = mh * 64 + mm;
#pragma unroll
        for (int b = 0; b < 32; ++b) acc[b] = fmaf(sx[b][m], v, acc[b]);
    }
#pragma unroll
    for (int b = 0; b < 32; ++b)
        partial[(size_t)((l * 2 + mh) * 32 + b) * 128 + n] = acc[b];
}

__global__ __launch_bounds__(128) void head_red_kernel(
    const float* __restrict__ partial, float* __restrict__ red1)
{
    const int b = blockIdx.x >> 5, cs = blockIdx.x & 31, n = threadIdx.x;
    const float* p = partial + ((size_t)(cs * 32) * 32 + b) * 128 + n;
    float s = 0.f;
#pragma unroll 8
    for (int c = 0; c < 32; ++c) s += p[(size_t)c * 4096];
    red1[(b * 32 + cs) * 128 + n] = s;
}

__global__ __launch_bounds__(128) void head_out_kernel(
    const float* __restrict__ red1, const float* __restrict__ bft,
    const float* __restrict__ head_w, const float* __restrict__ head_b, float* __restrict__ out)
{
    __shared__ float red[128];
    const int b = blockIdx.x, n = threadIdx.x;
    float s = bft[n];
#pragma unroll 8
    for (int cs = 0; cs < 32; ++cs) s += red1[(b * 32 + cs) * 128 + n];
    red[n] = s * head_w[n];
    __syncthreads();
    for (int st = 64; st >= 1; st >>= 1) { if (n < st) red[n] += red[n + st]; __syncthreads(); }
    if (n == 0) out[b] = red[0] + head_b[0];
    out[32 + b * 128 + n] = 0.f;   // log_var = zeros
}

extern "C" void kernel_launch(void* const* d_in, const int* in_sizes, int n_in,
                              void* d_out, int out_size, void* d_ws, size_t ws_size,
                              hipStream_t stream) {
    const float* x_in    = (const float*)d_in[0];
    const float* in_w    = (const float*)d_in[1];
    const float* conv_w  = (const float*)d_in[2];
    const float* conv_b  = (const float*)d_in[3];
    const float* xproj_w = (const float*)d_in[4];
    const float* dt_w    = (const float*)d_in[5];
    const float* dt_b    = (const float*)d_in[6];
    const float* Alog    = (const float*)d_in[7];
    const float* Dp      = (const float*)d_in[8];
    const float* out_w   = (const float*)d_in[9];
    const float* ln1_g   = (const float*)d_in[10];
    const float* ln1_b   = (const float*)d_in[11];
    const float* ln2_g   = (const float*)d_in[12];
    const float* ln2_b   = (const float*)d_in[13];
    const float* ffn_w1  = (const float*)d_in[14];
    const float* ffn_b1  = (const float*)d_in[15];
    const float* ffn_w2  = (const float*)d_in[16];
    const float* ffn_b2  = (const float*)d_in[17];
    const float* psi_emb = (const float*)d_in[18];
    const float* psi_s   = (const float*)d_in[19];
    const float* W_q     = (const float*)d_in[20];
    const float* W_k     = (const float*)d_in[21];
    const float* attn_a  = (const float*)d_in[22];
    const float* F_w     = (const float*)d_in[23];
    const float* f_b     = (const float*)d_in[24];
    const float* hmix    = (const float*)d_in[25];
    const float* head_w  = (const float*)d_in[26];
    const float* head_b  = (const float*)d_in[27];
    float* ws = (float*)d_ws;
    float* outp = (float*)d_out;

    for (int i = 0; i < 3; ++i) {
        const float* xcur = (i == 0) ? x_in : (ws + OFF_X);
        const int mF = 2 * i, mB = 2 * i + 1;
        gemm_in2_kernel<<<512, 256, 0, stream>>>(
            xcur, in_w + mF * 16384, in_w + mB * 16384, ws + OFF_XZF, ws + OFF_XZB);
        prep4_kernel<<<2048, 256, 0, stream>>>(
            ws + OFF_XZF, ws + OFF_XZB, conv_w, conv_b, xproj_w, dt_w, dt_b, i,
            ws + OFF_XPF, ws + OFF_XPB,
            (unsigned int*)(ws + OFF_XBCF), (unsigned int*)(ws + OFF_XBCB),
            ws + OFF_PKF, ws + OFF_PKB);
        scan7_kernel<<<1024, 256, 0, stream>>>(
            (const unsigned int*)(ws + OFF_XBCF), (const unsigned int*)(ws + OFF_XBCB),
            ws + OFF_PKF, ws + OFF_PKB,
            Alog + mF * 4096, Alog + mB * 4096, ws + OFF_YSF, ws + OFF_YSB);
        opfn_kernel<<<1024, 256, 0, stream>>>(
            ws + OFF_YSF, ws + OFF_YSB, ws + OFF_XPF, ws + OFF_XPB, ws + OFF_XZF, ws + OFF_XZB,
            Dp, i, xcur, out_w,
            ffn_w1 + i * 4096, ffn_b1 + i * 32, ffn_w2 + i * 4096, ffn_b2 + i * 128,
            ln1_g + i * 128, ln1_b + i * 128, ln2_g + i * 128, ln2_b + i * 128,
            ws + OFF_X);
    }
    // head
    head_prep_kernel<<<1, 256, 0, stream>>>(
        psi_emb, W_q, W_k, f_b, hmix, attn_a,
        ws + OFF_MIX, ws + OFF_ALPH, ws + OFF_BFT, ws + OFF_QB, ws + OFF_KB);
    head_qkaeff_kernel<<<512, 128, 0, stream>>>(
        psi_emb, psi_s, ws + OFF_QB, ws + OFF_KB, ws + OFF_ALPH, ws + OFF_AEFF, ws + OFF_STT);
    head_cheb_kernel<<<256, 256, 0, stream>>>(ws + OFF_AEFF, ws + OFF_STT, 2);
    head_cheb_kernel<<<256, 256, 0, stream>>>(ws + OFF_AEFF, ws + OFF_STT, 3);
    head_wf_kernel<<<4096, 256, 0, stream>>>(psi_emb, F_w, ws + OFF_WFT);
    head_v4_kernel<<<1024, 256, 0, stream>>>(ws + OFF_STT, ws + OFF_WFT, ws + OFF_MIX, ws + OFF_V);
    head_ctr_kernel<<<512, 256, 0, stream>>>(ws + OFF_X, ws + OFF_V, ws + OFF_PART);
    head_red_kernel<<<1024, 128, 0, stream>>>(ws + OFF_PART, ws + OFF_RED1);
    head_out_kernel<<<32, 128, 0, stream>>>(
        ws + OFF_RED1, ws + OFF_BFT, head_w, head_b, outp);
}

// Round 9
// 506.097 us; speedup vs baseline: 1.9186x; 1.0268x over previous
//
#include <hip/hip_runtime.h>
#include <hip/hip_bf16.h>

// MAMBA_BayesMAGAC: B=32, L=512, D=128, E=64, HS=64, DTR=4, U=32, R=3, K=3, DE=10, NH=4
// Round 9: opfn2 (fuses next-layer in-proj GEMM), head_wfqk (wf+qk+inline prep),
// scan with native v_exp (exp2f builtin, prescaled). 17 dispatches.

#define B_ 32
#define L_ 512
#define D_ 128
#define E_ 64
#define HS_ 64

// ---- workspace offsets (floats) ----
#define OFF_X     0u          // 2,097,152  x [b][l][128]
#define OFF_XZF   2097152u    // 2,097,152  xz fwd [b][l][128]
#define OFF_XZB   4194304u
#define OFF_XPF   6291456u    // 1,048,576  xp [b][l][64]
#define OFF_XPB   7340032u
#define OFF_PKF   8388608u    // 2,097,152  (dl,du) [b][l][64][2]
#define OFF_PKB   10485760u
#define OFF_XBCF  12582912u   // 1,048,576 u32: packed bf16 (C<<16|B) [b][l][64]
#define OFF_XBCB  14680064u
#define OFF_YSF   16777216u   // 1,048,576  scan y [b][e][l]
#define OFF_YSB   17825792u   // end 18,874,368 floats = 75.5 MB
// head phase (only OFF_X live):
#define OFF_V     2097152u    // 8,388,608  V [l][m][n]
#define OFF_WFT   10485760u   // 1,048,576  Wf [h][k][l][n]
#define OFF_STT   11534336u   // 262,144    S^T [h][k][m][n]
#define OFF_AEFF  11796480u   // 65,536
#define OFF_PART  12582912u   // 4,194,304  partial [1024][32][128]
#define OFF_RED1  16777216u   // 131,072    red1 [32][32][128]

__device__ __forceinline__ float sigf(float x) { return 1.f / (1.f + __expf(-x)); }
__device__ __forceinline__ unsigned int bf16r(float x) {
    unsigned int u = __float_as_uint(x);
    return (u + 0x7fffu + ((u >> 16) & 1u)) >> 16;   // RNE to bf16, return low 16
}

// ---------------- in-projection (layer 0 only): xz = x @ in_w, 32 rows/block ----------------
__global__ __launch_bounds__(256) void gemm_in2_kernel(
    const float* __restrict__ X, const float* __restrict__ WF, const float* __restrict__ WB,
    float* __restrict__ xzF, float* __restrict__ xzB)
{
    __shared__ float sxT[128][36];    // transposed x tile, padded
    __shared__ float sw[2][16][128];
    const int tid = threadIdx.x;
    const int r0 = blockIdx.x * 32;
    for (int q = tid; q < 1024; q += 256) {
        const int r = q >> 5, k4 = q & 31;
        const float4 v = *(const float4*)&X[(size_t)(r0 + r) * 128 + k4 * 4];
        sxT[k4 * 4 + 0][r] = v.x; sxT[k4 * 4 + 1][r] = v.y;
        sxT[k4 * 4 + 2][r] = v.z; sxT[k4 * 4 + 3][r] = v.w;
    }
    const int wv = tid >> 6, lane = tid & 63;
    const int d = wv >> 1, ch = wv & 1;
    const int r4 = lane >> 4, c16 = lane & 15;
    float4 acc[8];
#pragma unroll
    for (int j = 0; j < 8; ++j) acc[j] = float4{0.f, 0.f, 0.f, 0.f};
    for (int ko = 0; ko < 128; ko += 16) {
        __syncthreads();
        for (int q = tid; q < 1024; q += 256) {
            const int dd = q >> 9, kk = (q >> 5) & 15, c4 = q & 31;
            *(float4*)&sw[dd][kk][c4 * 4] =
                *(const float4*)&((dd ? WB : WF)[(ko + kk) * 128 + c4 * 4]);
        }
        __syncthreads();
#pragma unroll
        for (int kk = 0; kk < 16; ++kk) {
            const float4 w4 = *(const float4*)&sw[d][kk][ch * 64 + c16 * 4];
            const float4 xa = *(const float4*)&sxT[ko + kk][r4 * 8];
            const float4 xb = *(const float4*)&sxT[ko + kk][r4 * 8 + 4];
            const float xs[8] = {xa.x, xa.y, xa.z, xa.w, xb.x, xb.y, xb.z, xb.w};
#pragma unroll
            for (int j = 0; j < 8; ++j) {
                acc[j].x = fmaf(xs[j], w4.x, acc[j].x);
                acc[j].y = fmaf(xs[j], w4.y, acc[j].y);
                acc[j].z = fmaf(xs[j], w4.z, acc[j].z);
                acc[j].w = fmaf(xs[j], w4.w, acc[j].w);
            }
        }
    }
    float* xz = d ? xzB : xzF;
#pragma unroll
    for (int j = 0; j < 8; ++j) {
        *(float4*)&xz[(r0 + r4 * 8 + j) * 128 + ch * 64 + c16 * 4] = acc[j];
    }
}

// ------------- conv + silu + xproj + delta, 4-row amortized. grid 2048 (16 rows/block) -------
__global__ __launch_bounds__(256) void prep4_kernel(
    const float* __restrict__ xzF_, const float* __restrict__ xzB_,
    const float* __restrict__ conv_w, const float* __restrict__ conv_b,
    const float* __restrict__ xproj_w, const float* __restrict__ dt_w,
    const float* __restrict__ dt_b, int layer,
    float* __restrict__ xpF_, float* __restrict__ xpB_,
    unsigned int* __restrict__ xbcF_, unsigned int* __restrict__ xbcB_,
    float* __restrict__ pkF_, float* __restrict__ pkB_)
{
    __shared__ float sW[8448];
    __shared__ float sxp4[4][64][4];   // [wv][k][it]
    __shared__ float sdl4[4][4][4];    // [wv][it][r]
    const int tid = threadIdx.x, wv = tid >> 6, lane = tid & 63;
    const int dir = (int)(blockIdx.x >= 1024);        // block-uniform
    const int r0 = (blockIdx.x & 1023) * 16;          // 16 rows, same b
    const int b = r0 >> 9;
    const int m = layer * 2 + dir;
    const float* Wg = xproj_w + m * 8448;
    for (int q = tid; q < 2112; q += 256) ((float4*)sW)[q] = ((const float4*)Wg)[q];
    const float* xz = dir ? xzB_ : xzF_;
    float* xp  = dir ? xpB_  : xpF_;
    unsigned int* xbc = dir ? xbcB_ : xbcF_;
    float* pkx = dir ? pkB_  : pkF_;
    const float* cw = conv_w + m * 192 + lane * 3;
    const float cw0 = cw[0], cw1 = cw[1], cw2 = cw[2];
    const float cb  = conv_b[m * 64 + lane];
    const float dtb = dt_b[m * 64 + lane];
    const float* dwp = dt_w + m * 256;
    const float dw0 = dwp[lane], dw1 = dwp[64 + lane], dw2 = dwp[128 + lane], dw3 = dwp[192 + lane];
    // conv + silu for the wave's 4 rows
    float uu[4];
#pragma unroll
    for (int it = 0; it < 4; ++it) {
        const int row = r0 + wv * 4 + it;
        const int l = row & 511;
        const int l1 = dir ? l + 1 : l - 1;
        const int l2 = dir ? l + 2 : l - 2;
        float acc = cb;
        const float x0 = xz[(size_t)row * 128 + lane];
        const float x1 = (l1 >= 0 && l1 < 512) ? xz[(size_t)(b * 512 + l1) * 128 + lane] : 0.f;
        const float x2 = (l2 >= 0 && l2 < 512) ? xz[(size_t)(b * 512 + l2) * 128 + lane] : 0.f;
        acc += cw0 * x2 + cw1 * x1 + cw2 * x0;
        const float u = acc * sigf(acc);   // silu
        xp[row * 64 + lane] = u;
        uu[it] = u;
    }
    *(float4*)&sxp4[wv][lane][0] = float4{uu[0], uu[1], uu[2], uu[3]};
    __syncthreads();   // sW ready
    const int jdt = lane & 3;
    float aB[4] = {0.f, 0.f, 0.f, 0.f};
    float aC[4] = {0.f, 0.f, 0.f, 0.f};
    float adt[4] = {0.f, 0.f, 0.f, 0.f};
#pragma unroll 4
    for (int k = 0; k < 64; ++k) {
        const float wB = sW[k * 132 + 4 + lane];
        const float wC = sW[k * 132 + 68 + lane];
        const float wd = sW[k * 132 + jdt];
        const float4 xv = *(const float4*)&sxp4[wv][k][0];
        aB[0] = fmaf(xv.x, wB, aB[0]); aC[0] = fmaf(xv.x, wC, aC[0]); adt[0] = fmaf(xv.x, wd, adt[0]);
        aB[1] = fmaf(xv.y, wB, aB[1]); aC[1] = fmaf(xv.y, wC, aC[1]); adt[1] = fmaf(xv.y, wd, adt[1]);
        aB[2] = fmaf(xv.z, wB, aB[2]); aC[2] = fmaf(xv.z, wC, aC[2]); adt[2] = fmaf(xv.z, wd, adt[2]);
        aB[3] = fmaf(xv.w, wB, aB[3]); aC[3] = fmaf(xv.w, wC, aC[3]); adt[3] = fmaf(xv.w, wd, adt[3]);
    }
#pragma unroll
    for (int it = 0; it < 4; ++it) {
        const int row = r0 + wv * 4 + it;
        xbc[row * 64 + lane] = (bf16r(aC[it]) << 16) | bf16r(aB[it]);
        if (lane < 4) sdl4[wv][it][lane] = adt[it];
    }
#pragma unroll
    for (int it = 0; it < 4; ++it) {
        const int row = r0 + wv * 4 + it;
        float dpre = fmaf(sdl4[wv][it][0], dw0, dtb);
        dpre = fmaf(sdl4[wv][it][1], dw1, dpre);
        dpre = fmaf(sdl4[wv][it][2], dw2, dpre);
        dpre = fmaf(sdl4[wv][it][3], dw3, dpre);
        const float dlt = (dpre > 20.f) ? dpre : log1pf(__expf(dpre));
        ((float2*)pkx)[row * 64 + lane] = float2{dlt, dlt * uu[it]};
    }
}

// ------------- selective scan v8. grid 1024, block 256, packed bf16 B/C, native exp2 ---------
__global__ __launch_bounds__(256, 4) void scan8_kernel(
    const unsigned int* __restrict__ xbcF, const unsigned int* __restrict__ xbcB,
    const float* __restrict__ pkF, const float* __restrict__ pkB,
    const float* __restrict__ AlogF, const float* __restrict__ AlogB,
    float* __restrict__ ysF, float* __restrict__ ysB)
{
    __shared__ unsigned int sbc[2][1024]; // 8 KB
    __shared__ float spk[2][4][16][2];    // 1 KB
    __shared__ float ytile[4][16][68];    // 17.4 KB
    const int tid = threadIdx.x, wv = tid >> 6, lane = tid & 63;
    const int bx = blockIdx.x;
    const int db = bx & 63;               // (dir,b) in low bits -> same XCD for all e-quads
    const int dir = db >> 5;
    const int b   = db & 31;
    const int e0  = (bx >> 6) * 4;
    const int e   = e0 + wv;
    const unsigned int* xbc = dir ? xbcB : xbcF;
    const float* pk  = dir ? pkB  : pkF;
    const float* Aw  = dir ? AlogB : AlogF;
    float* ys = dir ? ysB : ysF;
    const float a2 = -__expf(Aw[e * 64 + lane]) * 1.4426950408889634f;  // prescaled log2e
    float s = 0.f;
    float* yrow = ys + (size_t)(b * 64 + e) * 512;

    const int psl = tid & 15, pw_ = tid >> 4;

#define STG_LOAD(RS)                                                              \
    {                                                                             \
        nb = *(const uint4*)(xbc + (size_t)(RS) * 64 + tid * 4);                  \
        if (tid < 64)                                                             \
            npp = *(const float2*)(pk + (size_t)((RS) + psl) * 128 + (e0 + pw_) * 2); \
    }
#define STG_WRITE(BUF)                                                            \
    {                                                                             \
        *(uint4*)(&sbc[BUF][tid * 4]) = nb;                                       \
        if (tid < 64) *(float2*)(&spk[BUF][pw_][psl][0]) = npp;                   \
    }

#define SCAN16(REV)                                                               \
    {                                                                             \
        const unsigned int* bc = &sbc[cur][0];                                    \
        const float* pq = &spk[cur][wv][0][0];                                    \
        _Pragma("unroll")                                                         \
        for (int j = 0; j < 8; ++j) {                                             \
            const int pj = (REV) ? 7 - j : j;                                     \
            const float4 pk4 = *(const float4*)(pq + pj * 4);                     \
            const int sA = (REV) ? 15 - 2 * j : 2 * j;                            \
            const int sB = (REV) ? 14 - 2 * j : 2 * j + 1;                        \
            const float dlA = (REV) ? pk4.z : pk4.x;                              \
            const float duA = (REV) ? pk4.w : pk4.y;                              \
            const float dlB = (REV) ? pk4.x : pk4.z;                              \
            const float duB = (REV) ? pk4.y : pk4.w;                              \
            const unsigned int bA = bc[sA * 64 + lane];                           \
            const float BnA = __uint_as_float(bA << 16);                          \
            const float CnA = __uint_as_float(bA & 0xffff0000u);                  \
            s = fmaf(__builtin_amdgcn_exp2f(dlA * a2), s, duA * BnA);             \
            ytile[wv][2 * j][lane] = s * CnA;                                     \
            const unsigned int bB = bc[sB * 64 + lane];                           \
            const float BnB = __uint_as_float(bB << 16);                          \
            const float CnB = __uint_as_float(bB & 0xffff0000u);                  \
            s = fmaf(__builtin_amdgcn_exp2f(dlB * a2), s, duB * BnB);             \
            ytile[wv][2 * j + 1][lane] = s * CnB;                                 \
        }                                                                         \
    }

    // prologue: stage tile 0
    {
        uint4 nb; float2 npp;
        const int rs0 = b * 512 + (dir ? 496 : 0);
        STG_LOAD(rs0);
        STG_WRITE(0);
    }
    __syncthreads();

    int cur = 0;
    const int rr = lane & 15, sg = lane >> 4;
    for (int t = 0; t < 32; ++t) {
        uint4 nb; float2 npp;
        const bool more = (t + 1) < 32;
        if (more) {
            const int rs = b * 512 + (dir ? (496 - (t + 1) * 16) : ((t + 1) * 16));
            STG_LOAD(rs);
        }
        if (dir == 0) { SCAN16(0) } else { SCAN16(1) }
        // per-wave reduce of own ytile (wave-private)
        {
            const float* yt = &ytile[wv][rr][sg * 16];
            const float4 A0 = *(const float4*)yt;
            const float4 A1 = *(const float4*)(yt + 4);
            const float4 A2 = *(const float4*)(yt + 8);
            const float4 A3 = *(const float4*)(yt + 12);
            float p = ((A0.x + A0.y) + (A0.z + A0.w)) + ((A1.x + A1.y) + (A1.z + A1.w))
                    + ((A2.x + A2.y) + (A2.z + A2.w)) + ((A3.x + A3.y) + (A3.z + A3.w));
            p += __shfl_xor(p, 16);
            p += __shfl_xor(p, 32);
            if (lane < 16) {
                const int lg = dir ? (511 - (t * 16 + rr)) : (t * 16 + rr);
                yrow[lg] = p;
            }
        }
        if (more) STG_WRITE(cur ^ 1);
        __syncthreads();
        cur ^= 1;
    }
#undef STG_LOAD
#undef STG_WRITE
#undef SCAN16
}

// ------------- opfn2: gate + out-proj + LN1 + FFN + LN2 + (next-layer in-proj GEMM) ----------
// grid 1024 (16 rows), block 256. WFn/WBn null => skip the fused in-proj.
__global__ __launch_bounds__(256) void opfn2_kernel(
    const float* __restrict__ ysF, const float* __restrict__ ysB,
    const float* __restrict__ xpF, const float* __restrict__ xpB,
    const float* __restrict__ xzF, const float* __restrict__ xzB,
    const float* __restrict__ Dp, int layer,
    const float* __restrict__ Xc, const float* __restrict__ out_w,
    const float* __restrict__ W1, const float* __restrict__ b1,
    const float* __restrict__ W2, const float* __restrict__ b2,
    const float* __restrict__ g1, const float* __restrict__ bb1,
    const float* __restrict__ g2, const float* __restrict__ bb2,
    float* __restrict__ xout,
    const float* __restrict__ WFn, const float* __restrict__ WBn,
    float* __restrict__ xzFo, float* __restrict__ xzBo)
{
    __shared__ float smem[8832];
    float* syt = smem;            // [2][64][17] = 2176 (dead after phase1)
    float* y3  = smem;            // [16][128] = 2048 (over syt; later = xout tile sxr)
    float* sy  = smem + 2176;     // [16][128] = 2048
    float* sw  = smem + 4224;     // [32][128] = 4096
    float* sh  = smem + 8320;     // [16][32]  = 512
    const int tid = threadIdx.x;
    const int r0 = blockIdx.x * 16;
    const int b = r0 >> 9, l0 = r0 & 511;

    // phase 0: ys transposed into syt
    for (int q = tid; q < 512; q += 256) {
        const int d = q >> 8, ee = (q >> 2) & 63, rq = q & 3;
        const float* ysp = d ? ysB : ysF;
        const float4 v = *(const float4*)&ysp[(size_t)(b * 64 + ee) * 512 + l0 + rq * 4];
        float* dst = &syt[(d * 64 + ee) * 17 + rq * 4];
        dst[0] = v.x; dst[1] = v.y; dst[2] = v.z; dst[3] = v.w;
    }
    __syncthreads();
    // phase 1: gate -> sy
    for (int q = tid; q < 2048; q += 256) {
        const int r = q >> 7, c = q & 127;
        const int d = c >> 6, ee = c & 63;
        const int row = r0 + r;
        const float dv  = Dp[(layer * 2 + d) * 64 + ee];
        const float u   = (d ? xpB : xpF)[(size_t)row * 64 + ee];
        const float res = (d ? xzB : xzF)[(size_t)row * 128 + 64 + ee];
        sy[r * 128 + c] = (syt[(d * 64 + ee) * 17 + r] + u * dv) * sigf(res);
    }
    // phase 2: out-proj GEMM + residual + LN1 -> y3
    const int wv = tid >> 6, lane = tid & 63;
    const float* WFp = out_w + (layer * 2) * 8192;
    const float* WBp = out_w + (layer * 2 + 1) * 8192;
    float acc[4][2];
#pragma unroll
    for (int r = 0; r < 4; ++r) { acc[r][0] = 0.f; acc[r][1] = 0.f; }
    for (int ko = 0; ko < 128; ko += 32) {
        __syncthreads();
        for (int q = tid; q < 1024; q += 256) {
            const int kk = q >> 5, c4 = q & 31;
            const int kg = ko + kk;
            *(float4*)&sw[kk * 128 + c4 * 4] = (kg < 64)
                ? *(const float4*)&WFp[kg * 128 + c4 * 4]
                : *(const float4*)&WBp[(kg - 64) * 128 + c4 * 4];
        }
        __syncthreads();
#define OPSTEP(SRC, COMP, J)                                                      \
        {                                                                         \
            const float w0 = sw[(kk + (J)) * 128 + lane];                         \
            const float w1 = sw[(kk + (J)) * 128 + lane + 64];                    \
            acc[0][0] = fmaf(y40.COMP, w0, acc[0][0]);                            \
            acc[0][1] = fmaf(y40.COMP, w1, acc[0][1]);                            \
            acc[1][0] = fmaf(y41.COMP, w0, acc[1][0]);                            \
            acc[1][1] = fmaf(y41.COMP, w1, acc[1][1]);                            \
            acc[2][0] = fmaf(y42.COMP, w0, acc[2][0]);                            \
            acc[2][1] = fmaf(y42.COMP, w1, acc[2][1]);                            \
            acc[3][0] = fmaf(y43.COMP, w0, acc[3][0]);                            \
            acc[3][1] = fmaf(y43.COMP, w1, acc[3][1]);                            \
        }
#pragma unroll
        for (int kk = 0; kk < 32; kk += 4) {
            const float4 y40 = *(const float4*)&sy[(wv * 4 + 0) * 128 + ko + kk];
            const float4 y41 = *(const float4*)&sy[(wv * 4 + 1) * 128 + ko + kk];
            const float4 y42 = *(const float4*)&sy[(wv * 4 + 2) * 128 + ko + kk];
            const float4 y43 = *(const float4*)&sy[(wv * 4 + 3) * 128 + ko + kk];
            OPSTEP(sy, x, 0) OPSTEP(sy, y, 1) OPSTEP(sy, z, 2) OPSTEP(sy, w, 3)
        }
    }
    __syncthreads();       // sy/syt dead
    for (int q = tid; q < 1024; q += 256) ((float4*)sw)[q] = ((const float4*)W1)[q];
#pragma unroll
    for (int r = 0; r < 4; ++r) {
        const int rl = wv * 4 + r;
        const int row = r0 + rl;
        float v0 = acc[r][0] + Xc[(size_t)row * 128 + lane];
        float v1 = acc[r][1] + Xc[(size_t)row * 128 + lane + 64];
        float sum = v0 + v1, sq = v0 * v0 + v1 * v1;
#pragma unroll
        for (int o = 32; o >= 1; o >>= 1) { sum += __shfl_xor(sum, o); sq += __shfl_xor(sq, o); }
        const float mean = sum * (1.f / 128.f);
        const float var = sq * (1.f / 128.f) - mean * mean;
        const float rs = rsqrtf(var + 1e-5f);
        y3[rl * 128 + lane]      = (v0 - mean) * rs * g1[lane] + bb1[lane];
        y3[rl * 128 + lane + 64] = (v1 - mean) * rs * g1[lane + 64] + bb1[lane + 64];
    }
    __syncthreads();
    // phase 3: hid = relu(y3 @ W1 + b1) -> sh
    {
        const int r = tid >> 4, u = tid & 15;
        float h0 = b1[u], h1 = b1[u + 16];
#pragma unroll 8
        for (int k = 0; k < 128; ++k) {
            const float xv = y3[r * 128 + k];
            h0 = fmaf(xv, sw[k * 32 + u], h0);
            h1 = fmaf(xv, sw[k * 32 + u + 16], h1);
        }
        sh[r * 32 + u]      = fmaxf(h0, 0.f);
        sh[r * 32 + u + 16] = fmaxf(h1, 0.f);
    }
    __syncthreads();
    for (int q = tid; q < 1024; q += 256) ((float4*)sw)[q] = ((const float4*)W2)[q];
    __syncthreads();
    // phase 4: FFN2 + residual(y3) + LN2 -> xout (keep values in regs)
    float xr[4][2];
#pragma unroll
    for (int r = 0; r < 4; ++r) {
        const int rl = wv * 4 + r;
        float a0 = b2[lane], a1 = b2[lane + 64];
#pragma unroll 8
        for (int k = 0; k < 32; ++k) {
            const float hv = sh[rl * 32 + k];
            a0 = fmaf(hv, sw[k * 128 + lane], a0);
            a1 = fmaf(hv, sw[k * 128 + lane + 64], a1);
        }
        const float v0 = a0 + y3[rl * 128 + lane];
        const float v1 = a1 + y3[rl * 128 + lane + 64];
        float sum = v0 + v1, sq = v0 * v0 + v1 * v1;
#pragma unroll
        for (int o = 32; o >= 1; o >>= 1) { sum += __shfl_xor(sum, o); sq += __shfl_xor(sq, o); }
        const float mean = sum * (1.f / 128.f);
        const float var = sq * (1.f / 128.f) - mean * mean;
        const float rs = rsqrtf(var + 1e-5f);
        const int row = r0 + rl;
        const float o0 = (v0 - mean) * rs * g2[lane] + bb2[lane];
        const float o1 = (v1 - mean) * rs * g2[lane + 64] + bb2[lane + 64];
        xout[(size_t)row * 128 + lane]      = o0;
        xout[(size_t)row * 128 + lane + 64] = o1;
        xr[r][0] = o0; xr[r][1] = o1;
    }
    if (WFn == nullptr) return;
    // ---- fused next-layer in-proj: xz_next = xout_tile @ in_w_next (both dirs) ----
    __syncthreads();      // all y3 reads done; reuse region as sxr [16][128]
    float* sxr = y3;
#pragma unroll
    for (int r = 0; r < 4; ++r) {
        sxr[(wv * 4 + r) * 128 + lane]      = xr[r][0];
        sxr[(wv * 4 + r) * 128 + lane + 64] = xr[r][1];
    }
    for (int d = 0; d < 2; ++d) {
        const float* Wn = d ? WBn : WFn;
        float* xzo = d ? xzBo : xzFo;
#pragma unroll
        for (int r = 0; r < 4; ++r) { acc[r][0] = 0.f; acc[r][1] = 0.f; }
        for (int ko = 0; ko < 128; ko += 32) {
            __syncthreads();   // first iter also covers sxr writes
            for (int q = tid; q < 1024; q += 256) {
                const int kk = q >> 5, c4 = q & 31;
                *(float4*)&sw[kk * 128 + c4 * 4] = *(const float4*)&Wn[(ko + kk) * 128 + c4 * 4];
            }
            __syncthreads();
#pragma unroll
            for (int kk = 0; kk < 32; kk += 4) {
                const float4 y40 = *(const float4*)&sxr[(wv * 4 + 0) * 128 + ko + kk];
                const float4 y41 = *(const float4*)&sxr[(wv * 4 + 1) * 128 + ko + kk];
                const float4 y42 = *(const float4*)&sxr[(wv * 4 + 2) * 128 + ko + kk];
                const float4 y43 = *(const float4*)&sxr[(wv * 4 + 3) * 128 + ko + kk];
                OPSTEP(sxr, x, 0) OPSTEP(sxr, y, 1) OPSTEP(sxr, z, 2) OPSTEP(sxr, w, 3)
            }
        }
#pragma unroll
        for (int r = 0; r < 4; ++r) {
            const int row = r0 + wv * 4 + r;
            xzo[(size_t)row * 128 + lane]      = acc[r][0];
            xzo[(size_t)row * 128 + lane + 64] = acc[r][1];
        }
    }
#undef OPSTEP
}

// ================= head =================
// wf (blocks 0..4095) + qk/aeff with inline Q/K/alpha (blocks 4096..4351, 2 units/block)
__global__ __launch_bounds__(256) void head_wfqk_kernel(
    const float* __restrict__ psi, const float* __restrict__ F_w, float* __restrict__ WfT,
    const float* __restrict__ psis, const float* __restrict__ W_q, const float* __restrict__ W_k,
    const float* __restrict__ attn_a,
    float* __restrict__ Aeff, float* __restrict__ StT)
{
    __shared__ float sQ[2][10];
    __shared__ float red[2][128];
    if (blockIdx.x < 4096) {
        const int idx = blockIdx.x * 256 + threadIdx.x;  // 2^20
        const int n = idx & 127, l = (idx >> 7) & 511, k = (idx >> 16) & 3, h = idx >> 18;
        float acc = 0.f;
#pragma unroll
        for (int d = 0; d < 10; ++d)
            acc = fmaf(psi[n * 10 + d], F_w[((h * 10 + d) * 4 + k) * 512 + l], acc);
        WfT[idx] = acc;
        return;
    }
    const int q = blockIdx.x - 4096;                 // 0..255
    const int half = threadIdx.x >> 7, mcol = threadIdx.x & 127;
    const int unit = q * 2 + half;                   // 0..511
    const int h = unit >> 7, n = unit & 127;
    // K[mcol, h, :] in regs
    float Kreg[10];
#pragma unroll
    for (int d = 0; d < 10; ++d) Kreg[d] = 0.f;
#pragma unroll
    for (int d0 = 0; d0 < 10; ++d0) {
        const float pv = psi[mcol * 10 + d0];
#pragma unroll
        for (int d = 0; d < 10; ++d) Kreg[d] = fmaf(pv, W_k[(d0 * 4 + h) * 10 + d], Kreg[d]);
    }
    if (mcol < 10) {
        float qd = 0.f;
        for (int d0 = 0; d0 < 10; ++d0)
            qd = fmaf(psi[n * 10 + d0], W_q[(d0 * 4 + h) * 10 + mcol], qd);
        sQ[half][mcol] = qd;
    }
    __syncthreads();
    float d2 = 0.f;
#pragma unroll
    for (int d = 0; d < 10; ++d) { const float df = psi[n * 10 + d] - psi[mcol * 10 + d]; d2 = fmaf(df, df, d2); }
    const float gv = __expf(-psis[0] * d2);
    float qv = 0.f;
#pragma unroll
    for (int d = 0; d < 10; ++d) qv = fmaf(sQ[half][d], Kreg[d], qv);
    qv *= 0.3162277660168379332f;  // 1/sqrt(10)
    float* rd = red[half];
    float r;
    rd[mcol] = gv; __syncthreads();
    for (int s = 64; s >= 1; s >>= 1) { if (mcol < s) rd[mcol] = fmaxf(rd[mcol], rd[mcol + s]); __syncthreads(); }
    r = rd[0]; __syncthreads();
    const float eg = __expf(gv - r);
    rd[mcol] = eg; __syncthreads();
    for (int s = 64; s >= 1; s >>= 1) { if (mcol < s) rd[mcol] += rd[mcol + s]; __syncthreads(); }
    const float gsum = rd[0]; __syncthreads();
    rd[mcol] = qv; __syncthreads();
    for (int s = 64; s >= 1; s >>= 1) { if (mcol < s) rd[mcol] = fmaxf(rd[mcol], rd[mcol + s]); __syncthreads(); }
    r = rd[0]; __syncthreads();
    const float eq = __expf(qv - r);
    rd[mcol] = eq; __syncthreads();
    for (int s = 64; s >= 1; s >>= 1) { if (mcol < s) rd[mcol] += rd[mcol + s]; __syncthreads(); }
    const float qsum = rd[0];
    const float al = sigf(attn_a[0]);
    const float aeff = al * (eg / gsum) + (1.f - al) * (eq / qsum);
    Aeff[h * 16384 + n * 128 + mcol] = aeff;
    StT[((h * 4 + 1) * 128 + mcol) * 128 + n] = aeff;
    StT[((h * 4 + 0) * 128 + mcol) * 128 + n] = (mcol == n) ? 1.f : 0.f;
}

__global__ __launch_bounds__(256) void head_cheb_kernel(
    const float* __restrict__ Aeff, float* __restrict__ StT, int kk)
{
    const int h = blockIdx.x >> 6;
    const int m0 = ((blockIdx.x & 63) << 1) + (threadIdx.x >> 7);
    const int n = threadIdx.x & 127;
    const float* Ar = Aeff + h * 16384 + n * 128;
    const float* Sp = StT + ((h * 4 + kk - 1) * 128 + m0) * 128;
    float acc = 0.f;
#pragma unroll 8
    for (int p = 0; p < 128; ++p) acc = fmaf(Ar[p], Sp[p], acc);
    const float s2 = StT[((h * 4 + kk - 2) * 128 + m0) * 128 + n];
    StT[((h * 4 + kk) * 128 + m0) * 128 + n] = 2.f * acc - s2;
}

// head_v4: thread owns (m, n0..n0+3) x 8 l's; mix computed inline. grid 1024, block 256.
__global__ __launch_bounds__(256) void head_v4_kernel(
    const float* __restrict__ StT, const float* __restrict__ WfT, const float* __restrict__ hmix,
    float* __restrict__ V)
{
    const float m0 = hmix[0], m1 = hmix[1], m2 = hmix[2], m3 = hmix[3];
    const float mxx = fmaxf(fmaxf(m0, m1), fmaxf(m2, m3));
    const float e0 = __expf(m0 - mxx), e1 = __expf(m1 - mxx), e2 = __expf(m2 - mxx), e3 = __expf(m3 - mxx);
    const float inv = 1.f / (e0 + e1 + e2 + e3);
    const float mixv[4] = {e0 * inv, e1 * inv, e2 * inv, e3 * inv};
    const int tid = threadIdx.x;
    const int lt = blockIdx.x & 63, mm = blockIdx.x >> 6;
    const int n4 = tid & 31, mh = tid >> 5;
    const int m = mm * 8 + mh;
    const int l0 = lt * 8, n0 = n4 * 4;
    float4 sv[16];
#pragma unroll
    for (int h = 0; h < 4; ++h) {
        const float mx = mixv[h];
#pragma unroll
        for (int k = 0; k < 4; ++k) {
            const float4 v = *(const float4*)&StT[(size_t)((h * 4 + k) * 128 + m) * 128 + n0];
            sv[h * 4 + k] = float4{v.x * mx, v.y * mx, v.z * mx, v.w * mx};
        }
    }
#pragma unroll
    for (int j = 0; j < 8; ++j) {
        const int l = l0 + j;
        float4 acc = {0.f, 0.f, 0.f, 0.f};
#pragma unroll
        for (int hk = 0; hk < 16; ++hk) {
            const float4 w = *(const float4*)&WfT[(size_t)(hk * 512 + l) * 128 + n0];
            acc.x = fmaf(sv[hk].x, w.x, acc.x);
            acc.y = fmaf(sv[hk].y, w.y, acc.y);
            acc.z = fmaf(sv[hk].z, w.z, acc.z);
            acc.w = fmaf(sv[hk].w, w.w, acc.w);
        }
        *(float4*)&V[(size_t)(l * 128 + m) * 128 + n0] = acc;
    }
}

__global__ __launch_bounds__(256) void head_ctr_kernel(
    const float* __restrict__ Xf, const float* __restrict__ V, float* __restrict__ partial)
{
    __shared__ float sx[32][128];
    const int l = blockIdx.x, tid = threadIdx.x;
    const int n = tid & 127, mh = tid >> 7;
    for (int q = tid; q < 1024; q += 256) {
        const int b = q >> 5, m4 = q & 31;
        *(float4*)&sx[b][m4 * 4] = *(const float4*)&Xf[(size_t)(b * 512 + l) * 128 + m4 * 4];
    }
    __syncthreads();
    float acc[32];
#pragma unroll
    for (int b = 0; b < 32; ++b) acc[b] = 0.f;
    const float* vp = V + (size_t)(l * 128 + mh * 64) * 128 + n;
    for (int mm = 0; mm < 64; ++mm) {
        const float v = vp[(size_t)mm * 128];
        const int m = mh * 64 + mm;
#pragma unroll
        for (int b = 0; b < 32; ++b) acc[b] = fmaf(sx[b][m], v, acc[b]);
    }
#pragma unroll
    for (int b = 0; b < 32; ++b)
        partial[(size_t)((l * 2 + mh) * 32 + b) * 128 + n] = acc[b];
}

__global__ __launch_bounds__(128) void head_red_kernel(
    const float* __restrict__ partial, float* __restrict__ red1)
{
    const int b = blockIdx.x >> 5, cs = blockIdx.x & 31, n = threadIdx.x;
    const float* p = partial + ((size_t)(cs * 32) * 32 + b) * 128 + n;
    float s = 0.f;
#pragma unroll 8
    for (int c = 0; c < 32; ++c) s += p[(size_t)c * 4096];
    red1[(b * 32 + cs) * 128 + n] = s;
}

// final reduce + inline bft + head_w dot + log_var. grid 32, block 128.
__global__ __launch_bounds__(128) void head_out_kernel(
    const float* __restrict__ red1, const float* __restrict__ psi,
    const float* __restrict__ f_b, const float* __restrict__ hmix,
    const float* __restrict__ head_w, const float* __restrict__ head_b, float* __restrict__ out)
{
    __shared__ float red[128];
    const int b = blockIdx.x, n = threadIdx.x;
    const float m0 = hmix[0], m1 = hmix[1], m2 = hmix[2], m3 = hmix[3];
    const float mxx = fmaxf(fmaxf(m0, m1), fmaxf(m2, m3));
    const float e0 = __expf(m0 - mxx), e1 = __expf(m1 - mxx), e2 = __expf(m2 - mxx), e3 = __expf(m3 - mxx);
    const float inv = 1.f / (e0 + e1 + e2 + e3);
    const float mixv[4] = {e0 * inv, e1 * inv, e2 * inv, e3 * inv};
    float s = 0.f;
#pragma unroll
    for (int h = 0; h < 4; ++h) {
        float t = 0.f;
#pragma unroll
        for (int d = 0; d < 10; ++d) t = fmaf(psi[n * 10 + d], f_b[h * 10 + d], t);
        s = fmaf(mixv[h], t, s);
    }
#pragma unroll 8
    for (int cs = 0; cs < 32; ++cs) s += red1[(b * 32 + cs) * 128 + n];
    red[n] = s * head_w[n];
    __syncthreads();
    for (int st = 64; st >= 1; st >>= 1) { if (n < st) red[n] += red[n + st]; __syncthreads(); }
    if (n == 0) out[b] = red[0] + head_b[0];
    out[32 + b * 128 + n] = 0.f;   // log_var = zeros
}

extern "C" void kernel_launch(void* const* d_in, const int* in_sizes, int n_in,
                              void* d_out, int out_size, void* d_ws, size_t ws_size,
                              hipStream_t stream) {
    const float* x_in    = (const float*)d_in[0];
    const float* in_w    = (const float*)d_in[1];
    const float* conv_w  = (const float*)d_in[2];
    const float* conv_b  = (const float*)d_in[3];
    const float* xproj_w = (const float*)d_in[4];
    const float* dt_w    = (const float*)d_in[5];
    const float* dt_b    = (const float*)d_in[6];
    const float* Alog    = (const float*)d_in[7];
    const float* Dp      = (const float*)d_in[8];
    const float* out_w   = (const float*)d_in[9];
    const float* ln1_g   = (const float*)d_in[10];
    const float* ln1_b   = (const float*)d_in[11];
    const float* ln2_g   = (const float*)d_in[12];
    const float* ln2_b   = (const float*)d_in[13];
    const float* ffn_w1  = (const float*)d_in[14];
    const float* ffn_b1  = (const float*)d_in[15];
    const float* ffn_w2  = (const float*)d_in[16];
    const float* ffn_b2  = (const float*)d_in[17];
    const float* psi_emb = (const float*)d_in[18];
    const float* psi_s   = (const float*)d_in[19];
    const float* W_q     = (const float*)d_in[20];
    const float* W_k     = (const float*)d_in[21];
    const float* attn_a  = (const float*)d_in[22];
    const float* F_w     = (const float*)d_in[23];
    const float* f_b     = (const float*)d_in[24];
    const float* hmix    = (const float*)d_in[25];
    const float* head_w  = (const float*)d_in[26];
    const float* head_b  = (const float*)d_in[27];
    float* ws = (float*)d_ws;
    float* outp = (float*)d_out;

    gemm_in2_kernel<<<512, 256, 0, stream>>>(
        x_in, in_w, in_w + 16384, ws + OFF_XZF, ws + OFF_XZB);
    for (int i = 0; i < 3; ++i) {
        const float* xcur = (i == 0) ? x_in : (ws + OFF_X);
        const int mF = 2 * i, mB = 2 * i + 1;
        prep4_kernel<<<2048, 256, 0, stream>>>(
            ws + OFF_XZF, ws + OFF_XZB, conv_w, conv_b, xproj_w, dt_w, dt_b, i,
            ws + OFF_XPF, ws + OFF_XPB,
            (unsigned int*)(ws + OFF_XBCF), (unsigned int*)(ws + OFF_XBCB),
            ws + OFF_PKF, ws + OFF_PKB);
        scan8_kernel<<<1024, 256, 0, stream>>>(
            (const unsigned int*)(ws + OFF_XBCF), (const unsigned int*)(ws + OFF_XBCB),
            ws + OFF_PKF, ws + OFF_PKB,
            Alog + mF * 4096, Alog + mB * 4096, ws + OFF_YSF, ws + OFF_YSB);
        const float* WFn = (i < 2) ? (in_w + (2 * i + 2) * 16384) : nullptr;
        const float* WBn = (i < 2) ? (in_w + (2 * i + 3) * 16384) : nullptr;
        opfn2_kernel<<<1024, 256, 0, stream>>>(
            ws + OFF_YSF, ws + OFF_YSB, ws + OFF_XPF, ws + OFF_XPB, ws + OFF_XZF, ws + OFF_XZB,
            Dp, i, xcur, out_w,
            ffn_w1 + i * 4096, ffn_b1 + i * 32, ffn_w2 + i * 4096, ffn_b2 + i * 128,
            ln1_g + i * 128, ln1_b + i * 128, ln2_g + i * 128, ln2_b + i * 128,
            ws + OFF_X, WFn, WBn, ws + OFF_XZF, ws + OFF_XZB);
    }
    // head
    head_wfqk_kernel<<<4352, 256, 0, stream>>>(
        psi_emb, F_w, ws + OFF_WFT, psi_s, W_q, W_k, attn_a,
        ws + OFF_AEFF, ws + OFF_STT);
    head_cheb_kernel<<<256, 256, 0, stream>>>(ws + OFF_AEFF, ws + OFF_STT, 2);
    head_cheb_kernel<<<256, 256, 0, stream>>>(ws + OFF_AEFF, ws + OFF_STT, 3);
    head_v4_kernel<<<1024, 256, 0, stream>>>(ws + OFF_STT, ws + OFF_WFT, hmix, ws + OFF_V);
    head_ctr_kernel<<<512, 256, 0, stream>>>(ws + OFF_X, ws + OFF_V, ws + OFF_PART);
    head_red_kernel<<<1024, 128, 0, stream>>>(ws + OFF_PART, ws + OFF_RED1);
    head_out_kernel<<<32, 128, 0, stream>>>(
        ws + OFF_RED1, psi_emb, f_b, hmix, head_w, head_b, outp);
}